// Round 12
// baseline (1079.016 us; speedup 1.0000x reference)
//
#include <hip/hip_runtime.h>

#define NN 100000
#define EE 1000000
#define ELL 500000
#define NF (NN*64)
#define NB_SCAN ((NN + 1023) / 1024)   // 98
#define NCPY 100352                    // padded per-copy histogram stride

// ws layouts (floats)
#define OFF_CNT    100352
#define OFF_BSUM   200704
#define OFF_RPA    200832
#define OFF_COLA   301184
#define OFF_RPB    1301184
#define OFF_COLB   1401536
#define WS_SINGLE  (1301184 + 3*NF)              // 82.0 MB
#define WS_DUAL    (2401536 + 3*NF)              // 86.4 MB

// ---------------- Threefry-2x32 ----------------
__device__ __forceinline__ void threefry2x32(unsigned k0, unsigned k1, unsigned &x0, unsigned &x1){
  unsigned ks2 = k0 ^ k1 ^ 0x1BD11BDAu;
#define TF_R(R) { x0 += x1; x1 = (x1<<(R))|(x1>>(32-(R))); x1 ^= x0; }
  x0 += k0; x1 += k1;
  TF_R(13) TF_R(15) TF_R(26) TF_R(6)
  x0 += k1;  x1 += ks2 + 1u;
  TF_R(17) TF_R(29) TF_R(16) TF_R(24)
  x0 += ks2; x1 += k0 + 2u;
  TF_R(13) TF_R(15) TF_R(26) TF_R(6)
  x0 += k0;  x1 += k1 + 3u;
  TF_R(17) TF_R(29) TF_R(16) TF_R(24)
  x0 += k1;  x1 += ks2 + 4u;
  TF_R(13) TF_R(15) TF_R(26) TF_R(6)
  x0 += ks2; x1 += k0 + 5u;
#undef TF_R
}

__device__ __forceinline__ float dropout_val(float v, unsigned i){
  unsigned x0 = 0u, x1 = i;
  threefry2x32(0u, 42u, x0, x1);
  unsigned bits = x0 ^ x1;
  float u = __uint_as_float((bits >> 9) | 0x3f800000u) - 1.0f;
  return (u < 0.6f) ? v * (1.0f/0.6f) : 0.0f;
}

__global__ void k_probe(const int* __restrict__ ei, unsigned hostbits, float* __restrict__ out){
  if (threadIdx.x != 0 || blockIdx.x != 0) return;
  unsigned bits = hostbits;
  { unsigned a=0u, b=0u; threefry2x32(0u, 0u, a, b);
    if (a != 0x6b200159u || b != 0x99ba4efeu) bits |= 1u; }
  if (bits) out[0] = 1.0e4f * (float)bits;
}

// ---------------- utility ----------------
__global__ void k_zero_int(int* __restrict__ p, int n){
  int i = blockIdx.x*256 + threadIdx.x;
  if (i < n) p[i] = 0;
}

__global__ void k_deg(const int* __restrict__ dst, int ne, int* __restrict__ cnt){
  int i = blockIdx.x*256 + threadIdx.x;
  if (i < ne) atomicAdd(&cnt[dst[i]], 1);
}

__global__ void k_dinv(const int* __restrict__ cnt, float* __restrict__ dinv, int n){
  int i = blockIdx.x*256 + threadIdx.x;
  if (i < n) dinv[i] = 1.0f / sqrtf((float)(cnt[i] + 1));
}

// ---------------- XCD-private histogram: copy = blockIdx&7 (round-robin ≈ XCD id) ----------------
__global__ void k_degrank8(const int* __restrict__ dst, int ne, int* __restrict__ cnt8,
                           int* __restrict__ rank){
  int i = blockIdx.x*256 + threadIdx.x;
  if (i >= ne) return;
  int copy = blockIdx.x & 7;
  int lr = atomicAdd(&cnt8[copy*NCPY + dst[i]], 1);
  rank[i] = (lr << 3) | copy;
}

// reduce 8 copies -> per-copy offsets + total count (+ optional dinv)
__global__ void k_hist8(const int* __restrict__ cnt8, int* __restrict__ off8,
                        int* __restrict__ cnt, float* __restrict__ dinv, int computeDinv){
  int d = blockIdx.x*256 + threadIdx.x;
  if (d >= NN) return;
  int running = 0;
  #pragma unroll
  for (int c = 0; c < 8; ++c){
    off8[c*NCPY + d] = running;
    running += cnt8[c*NCPY + d];
  }
  cnt[d] = running;
  if (computeDinv) dinv[d] = 1.0f / sqrtf((float)(running + 1));
}

// ---------------- multi-block exclusive scan ----------------
__global__ __launch_bounds__(1024) void k_scan1(const int* __restrict__ cnt, int* __restrict__ bsum, int n){
  __shared__ int lds[1024];
  int t = threadIdx.x, i = blockIdx.x*1024 + t;
  lds[t] = (i < n) ? cnt[i] : 0;
  __syncthreads();
  for (int off = 512; off > 0; off >>= 1){
    if (t < off) lds[t] += lds[t + off];
    __syncthreads();
  }
  if (t == 0) bsum[blockIdx.x] = lds[0];
}

__global__ __launch_bounds__(128) void k_scan2(int* __restrict__ bsum, int nb){
  __shared__ int lds[128];
  int t = threadIdx.x;
  int v = (t < nb) ? bsum[t] : 0;
  lds[t] = v;
  __syncthreads();
  for (int off = 1; off < 128; off <<= 1){
    int x = (t >= off) ? lds[t - off] : 0;
    __syncthreads();
    lds[t] += x;
    __syncthreads();
  }
  if (t < nb) bsum[t] = lds[t] - v;
}

__global__ __launch_bounds__(1024) void k_scan3(const int* __restrict__ cnt, const int* __restrict__ bsum,
                                                int* __restrict__ rowptr, int n){
  __shared__ int lds[1024];
  int t = threadIdx.x, i = blockIdx.x*1024 + t;
  int v = (i < n) ? cnt[i] : 0;
  lds[t] = v;
  __syncthreads();
  for (int off = 1; off < 1024; off <<= 1){
    int x = (t >= off) ? lds[t - off] : 0;
    __syncthreads();
    lds[t] += x;
    __syncthreads();
  }
  int excl = lds[t] - v + bsum[blockIdx.x];
  if (i < n)  rowptr[i] = excl;
  if (i == n-1) rowptr[n] = excl + v;
}

// ---------------- CSR fill, atomic-free (rank + per-copy offsets) ----------------
__global__ void k_fillr8(const int* __restrict__ src, const int* __restrict__ dst, int ne,
                         const int* __restrict__ rowptr, const int* __restrict__ rank,
                         const int* __restrict__ off8, int* __restrict__ col){
  int e = blockIdx.x*256 + threadIdx.x;
  if (e >= ne) return;
  int d = dst[e];
  unsigned r = (unsigned)rank[e];
  int c = (int)(r & 7u), lr = (int)(r >> 3);
  col[rowptr[d] + off8[c*NCPY + d] + lr] = src[e];
}

// ---------------- GEMM [nrows,64] @ [64,64]; RELU on input; SCALE: Y[row] *= dinv[row] ----------------
template<bool RELU, bool SCALE>
__global__ __launch_bounds__(256) void k_gemm64(const float* __restrict__ X, const float* __restrict__ W,
                                                const float* __restrict__ dinv,
                                                int nrows, float* __restrict__ Y){
  __shared__ float Ws[64][64];
  int t = threadIdx.x;
  {
    const float4* W4 = (const float4*)W;
    float4* S4 = (float4*)&Ws[0][0];
    #pragma unroll
    for (int i = 0; i < 4; ++i) S4[t + 256*i] = W4[t + 256*i];
  }
  __syncthreads();
  int row = blockIdx.x*16 + (t>>4);
  if (row >= nrows) return;
  int c0 = (t & 15) * 4;
  const float4* Xr = (const float4*)(X + (size_t)row*64);
  float4 acc = make_float4(0.f,0.f,0.f,0.f);
  #pragma unroll
  for (int kk = 0; kk < 16; ++kk){
    float4 xv = Xr[kk];
    if (RELU){
      xv.x = fmaxf(xv.x, 0.f); xv.y = fmaxf(xv.y, 0.f);
      xv.z = fmaxf(xv.z, 0.f); xv.w = fmaxf(xv.w, 0.f);
    }
    int k = kk*4;
    float4 w0 = *(const float4*)&Ws[k+0][c0];
    float4 w1 = *(const float4*)&Ws[k+1][c0];
    float4 w2 = *(const float4*)&Ws[k+2][c0];
    float4 w3 = *(const float4*)&Ws[k+3][c0];
    acc.x = fmaf(xv.x, w0.x, acc.x); acc.y = fmaf(xv.x, w0.y, acc.y);
    acc.z = fmaf(xv.x, w0.z, acc.z); acc.w = fmaf(xv.x, w0.w, acc.w);
    acc.x = fmaf(xv.y, w1.x, acc.x); acc.y = fmaf(xv.y, w1.y, acc.y);
    acc.z = fmaf(xv.y, w1.z, acc.z); acc.w = fmaf(xv.y, w1.w, acc.w);
    acc.x = fmaf(xv.z, w2.x, acc.x); acc.y = fmaf(xv.z, w2.y, acc.y);
    acc.z = fmaf(xv.z, w2.z, acc.z); acc.w = fmaf(xv.z, w2.w, acc.w);
    acc.x = fmaf(xv.w, w3.x, acc.x); acc.y = fmaf(xv.w, w3.y, acc.y);
    acc.z = fmaf(xv.w, w3.z, acc.z); acc.w = fmaf(xv.w, w3.w, acc.w);
  }
  if (SCALE){
    float dv = dinv[row];
    acc.x *= dv; acc.y *= dv; acc.z *= dv; acc.w *= dv;
  }
  *(float4*)(Y + (size_t)row*64 + c0) = acc;
}

// ---------------- GEMM [nrows,64] @ [64,2] ----------------
template<bool RELU, bool SCALE>
__global__ __launch_bounds__(256) void k_gemm2(const float* __restrict__ X, const float* __restrict__ W,
                                               const float* __restrict__ dinv,
                                               int nrows, float* __restrict__ Y){
  __shared__ float Ws[128];
  int t = threadIdx.x;
  if (t < 128) Ws[t] = W[t];
  __syncthreads();
  int row = blockIdx.x*256 + t;
  if (row >= nrows) return;
  const float4* Xr = (const float4*)(X + (size_t)row*64);
  float a0 = 0.f, a1 = 0.f;
  #pragma unroll
  for (int kk = 0; kk < 16; ++kk){
    float4 xv = Xr[kk];
    if (RELU){ xv.x=fmaxf(xv.x,0.f); xv.y=fmaxf(xv.y,0.f); xv.z=fmaxf(xv.z,0.f); xv.w=fmaxf(xv.w,0.f); }
    int k = kk*4;
    a0 = fmaf(xv.x, Ws[2*k+0], a0); a1 = fmaf(xv.x, Ws[2*k+1], a1);
    a0 = fmaf(xv.y, Ws[2*k+2], a0); a1 = fmaf(xv.y, Ws[2*k+3], a1);
    a0 = fmaf(xv.z, Ws[2*k+4], a0); a1 = fmaf(xv.z, Ws[2*k+5], a1);
    a0 = fmaf(xv.w, Ws[2*k+6], a0); a1 = fmaf(xv.w, Ws[2*k+7], a1);
  }
  if (SCALE){ float dv = dinv[row]; a0 *= dv; a1 *= dv; }
  Y[(size_t)row*2]   = a0;
  Y[(size_t)row*2+1] = a1;
}

// ---------------- CSR gather conv, 8-deep pipelined (col prefetch overlaps h loads) ----------------
__global__ __launch_bounds__(256) void k_gather64(const int* __restrict__ rowptr, const int* __restrict__ col,
                                                  const float* __restrict__ h, const float* __restrict__ dinv,
                                                  const float* __restrict__ b, float* __restrict__ out){
  int lane = threadIdx.x & 63;
  int node = (blockIdx.x*256 + threadIdx.x) >> 6;
  if (node >= NN) return;
  int beg = rowptr[node], end = rowptr[node+1];
  float acc = h[(size_t)node*64 + lane];
  int c[8];
  int j = beg;
  int n = end - j; if (n > 8) n = 8;
  #pragma unroll
  for (int k = 0; k < 8; ++k) if (k < n) c[k] = col[j + k];
  while (n > 0){
    float hv[8];
    #pragma unroll
    for (int k = 0; k < 8; ++k) if (k < n) hv[k] = h[(size_t)c[k]*64 + lane];
    j += n;
    int n2 = end - j; if (n2 > 8) n2 = 8;
    #pragma unroll
    for (int k = 0; k < 8; ++k) if (k < n2) c[k] = col[j + k];
    #pragma unroll
    for (int k = 0; k < 8; ++k) if (k < n) acc += hv[k];
    n = n2;
  }
  out[(size_t)node*64 + lane] = fmaf(acc, dinv[node], b[lane]);
}

// ---------------- CSR gather cross-layer agg, pipelined (+ optional fused dropout) ----------------
template<bool DROP>
__global__ __launch_bounds__(256) void k_agggather(const int* __restrict__ rowptr, const int* __restrict__ col,
                                                    const float* __restrict__ lf, const float* __restrict__ last,
                                                    const float* __restrict__ ds, int dsidx, float* __restrict__ out){
  int lane = threadIdx.x & 63;
  int node = (blockIdx.x*256 + threadIdx.x) >> 6;
  if (node >= NN) return;
  int beg = rowptr[node], end = rowptr[node+1];
  float acc = lf[(size_t)node*64 + lane];
  int c[8];
  int j = beg;
  int n = end - j; if (n > 8) n = 8;
  #pragma unroll
  for (int k = 0; k < 8; ++k) if (k < n) c[k] = col[j + k];
  while (n > 0){
    float hv[8];
    #pragma unroll
    for (int k = 0; k < 8; ++k) if (k < n) hv[k] = last[(size_t)c[k]*64 + lane];
    j += n;
    int n2 = end - j; if (n2 > 8) n2 = 8;
    #pragma unroll
    for (int k = 0; k < 8; ++k) if (k < n2) c[k] = col[j + k];
    #pragma unroll
    for (int k = 0; k < 8; ++k) if (k < n) acc += hv[k];
    n = n2;
  }
  float val = acc / ds[dsidx];
  unsigned i = (unsigned)node*64u + (unsigned)lane;
  if (DROP) val = dropout_val(val, i);
  out[i] = val;
}

// ---------------- CSR gather final conv (D_out=2) ----------------
__global__ void k_gather2(const int* __restrict__ rowptr, const int* __restrict__ col,
                          const float* __restrict__ h2, const float* __restrict__ dinv,
                          const float* __restrict__ b, float* __restrict__ out){
  int d = blockIdx.x*256 + threadIdx.x;
  if (d >= NN) return;
  int beg = rowptr[d], end = rowptr[d+1];
  float a0 = h2[(size_t)d*2];
  float a1 = h2[(size_t)d*2+1];
  for (int j = beg; j < end; ++j){
    int s = col[j];
    a0 += h2[(size_t)s*2];
    a1 += h2[(size_t)s*2+1];
  }
  float dv = dinv[d];
  out[(size_t)d*2]   = fmaf(a0, dv, b[0]);
  out[(size_t)d*2+1] = fmaf(a1, dv, b[1]);
}

// ---------------- standalone dropout (fallback path only) ----------------
__global__ void k_dropout(const float* __restrict__ last, float* __restrict__ xemb){
  unsigned i = blockIdx.x*256 + threadIdx.x;
  if (i >= NF) return;
  xemb[i] = dropout_val(last[i], i);
}

// ======== fallback (atomic scatter) kernels ========
__global__ void k_convinit(const float* __restrict__ h, const float* __restrict__ dinv,
                           const float* __restrict__ b, float* __restrict__ out){
  int i = blockIdx.x*256 + threadIdx.x;
  if (i >= NF) return;
  int v = i >> 6, c = i & 63;
  float dv = dinv[v];
  out[i] = h[i]*dv*dv + b[c];
}
__global__ void k_scatter64(const int* __restrict__ src, const int* __restrict__ dst, int ne,
                            const float* __restrict__ h, const float* __restrict__ dinv,
                            float* __restrict__ out){
  int lane = threadIdx.x & 63;
  int wid  = (blockIdx.x*256 + threadIdx.x) >> 6;
  int nw   = (gridDim.x*256) >> 6;
  for (int e = wid; e < ne; e += nw){
    int s = src[e], d = dst[e];
    float coef = dinv[s]*dinv[d];
    atomicAdd(&out[d*64 + lane], h[s*64 + lane]*coef);
  }
}
__global__ void k_layeragg(const int* __restrict__ recv, const int* __restrict__ srcn, int ne,
                           const float* __restrict__ last, float* __restrict__ acc){
  int lane = threadIdx.x & 63;
  int wid  = (blockIdx.x*256 + threadIdx.x) >> 6;
  int nw   = (gridDim.x*256) >> 6;
  for (int e = wid; e < ne; e += nw){
    int r = recv[e], s = srcn[e];
    atomicAdd(&acc[r*64 + lane], last[s*64 + lane]);
  }
}
__global__ void k_scale(const float* __restrict__ in, const float* __restrict__ ds, int dsidx,
                        float* __restrict__ out){
  int i = blockIdx.x*256 + threadIdx.x;
  if (i < NF) out[i] = in[i] / ds[dsidx];
}
__global__ void k_convinit2(const float* __restrict__ h2, const float* __restrict__ dinv,
                            const float* __restrict__ b, float* __restrict__ out){
  int i = blockIdx.x*256 + threadIdx.x;
  if (i >= NN*2) return;
  int v = i >> 1, c = i & 1;
  float dv = dinv[v];
  out[i] = h2[i]*dv*dv + b[c];
}
__global__ void k_scatter2(const int* __restrict__ src, const int* __restrict__ dst, int ne,
                           const float* __restrict__ h2, const float* __restrict__ dinv,
                           float* __restrict__ out){
  int e = blockIdx.x*256 + threadIdx.x;
  if (e >= ne) return;
  int s = src[e], d = dst[e];
  float coef = dinv[s]*dinv[d];
  atomicAdd(&out[d*2 + 0], h2[s*2 + 0]*coef);
  atomicAdd(&out[d*2 + 1], h2[s*2 + 1]*coef);
}

extern "C" void kernel_launch(void* const* d_in, const int* in_sizes, int n_in,
                              void* d_out, int out_size, void* d_ws, size_t ws_size,
                              hipStream_t stream) {
  const float* x    = (const float*)d_in[0];
  const int*   ei   = (const int*)  d_in[1];
  const int*   lei  = (const int*)  d_in[2];
  const float* degs = (const float*)d_in[3];
  const float* lW1  = (const float*)d_in[4];
  const float* lb1  = (const float*)d_in[5];
  const float* lW2  = (const float*)d_in[6];
  const float* lb2  = (const float*)d_in[7];
  const float* pW1  = (const float*)d_in[8];
  const float* pb1  = (const float*)d_in[9];
  const float* pW2  = (const float*)d_in[10];
  const float* pb2  = (const float*)d_in[11];
  float* out = (float*)d_out;

  const int gN  = (NN + 255)/256;
  const int gE  = (EE + 255)/256;
  const int gEL = (ELL + 255)/256;
  const int gNF = (NF + 255)/256;
  const int gG  = (NN*64 + 255)/256;
  const int gC8 = (8*NCPY + 255)/256;

  const bool dual   = ws_size >= (size_t)WS_DUAL * 4;
  const bool single = ws_size >= (size_t)WS_SINGLE * 4;

  if (single) {
    float* base   = (float*)d_ws;
    float* dinv   = base;
    int*   cnt    = (int*)(base + OFF_CNT);
    int*   bsum   = (int*)(base + OFF_BSUM);
    int*   rpA    = (int*)(base + OFF_RPA);
    int*   colA   = (int*)(base + OFF_COLA);
    int*   rpB    = dual ? (int*)(base + OFF_RPB)  : rpA;
    int*   colB   = dual ? (int*)(base + OFF_COLB) : colA;
    float* F0     = base + (dual ? OFF_COLB + 1000000 : OFF_RPB);
    float* F1     = F0 + NF;
    float* F2     = F1 + NF;

    // scratch (rank 1e6 | cnt8 8*NCPY | off8 8*NCPY = 10.4MB) aliases the dead F buffer per build
    auto build_csr = [&](const int* srcp, const int* dstp, int ne, int gEdges, int computeDinv,
                         int* rowptr, int* col, float* deadF){
      int* rank = (int*)deadF;
      int* cnt8 = rank + 1000000;
      int* off8 = cnt8 + 8*NCPY;
      k_zero_int<<<gC8, 256, 0, stream>>>(cnt8, 8*NCPY);
      k_degrank8<<<gEdges, 256, 0, stream>>>(dstp, ne, cnt8, rank);
      k_hist8<<<gN, 256, 0, stream>>>(cnt8, off8, cnt, dinv, computeDinv);
      k_scan1<<<NB_SCAN, 1024, 0, stream>>>(cnt, bsum, NN);
      k_scan2<<<1, 128, 0, stream>>>(bsum, NB_SCAN);
      k_scan3<<<NB_SCAN, 1024, 0, stream>>>(cnt, bsum, rowptr, NN);
      k_fillr8<<<gEdges, 256, 0, stream>>>(srcp, dstp, ne, rowptr, rank, off8, col);
    };

    const int* s0 = ei;                  const int* d0 = s0 + EE;
    const int* s1 = ei + 2*(size_t)EE;   const int* d1 = s1 + EE;
    const int* s2 = ei + 4*(size_t)EE;   const int* d2 = s2 + EE;
    const int* r0 = lei;                 const int* ls0 = r0 + ELL;
    const int* r1 = lei + 2*(size_t)ELL; const int* ls1 = r1 + ELL;

    // ---- surface 0 ----  (F0 dead during build)
    build_csr(s0, d0, EE, gE, 1, rpA, colA, F0);
    k_gemm64<false,true><<<6250, 256, 0, stream>>>(x, lW1, dinv, NN, F0);
    k_gather64<<<gG, 256, 0, stream>>>(rpA, colA, F0, dinv, lb1, F1);
    k_gemm64<true,true><<<6250, 256, 0, stream>>>(F1, lW2, dinv, NN, F0);
    k_gather64<<<gG, 256, 0, stream>>>(rpA, colA, F0, dinv, lb2, F2);            // last = F2
    // ---- surface 1 ----  (F0 dead during both builds)
    build_csr(s1, d1, EE, gE, 1, rpA, colA, F0);
    k_gemm64<false,true><<<6250, 256, 0, stream>>>(x + (size_t)NF, lW1 + 4096, dinv, NN, F0);
    k_gather64<<<gG, 256, 0, stream>>>(rpA, colA, F0, dinv, lb1 + 64, F1);
    k_gemm64<true,true><<<6250, 256, 0, stream>>>(F1, lW2 + 4096, dinv, NN, F0);
    k_gather64<<<gG, 256, 0, stream>>>(rpA, colA, F0, dinv, lb2 + 64, F1);       // lf = F1
    build_csr(ls0, r0, ELL, gEL, 0, rpB, colB, F0);
    k_agggather<false><<<gG, 256, 0, stream>>>(rpB, colB, F1, F2, degs, 0, F0);  // last = F0
    // ---- surface 2 ----  (F1 dead during both builds)
    build_csr(s2, d2, EE, gE, 1, rpA, colA, F1);
    k_gemm64<false,true><<<6250, 256, 0, stream>>>(x + 2*(size_t)NF, lW1 + 8192, dinv, NN, F1);
    k_gather64<<<gG, 256, 0, stream>>>(rpA, colA, F1, dinv, lb1 + 128, F2);
    k_gemm64<true,true><<<6250, 256, 0, stream>>>(F2, lW2 + 8192, dinv, NN, F1);
    k_gather64<<<gG, 256, 0, stream>>>(rpA, colA, F1, dinv, lb2 + 128, F2);      // lf = F2
    build_csr(ls1, r1, ELL, gEL, 0, rpB, colB, F1);
    k_agggather<true><<<gG, 256, 0, stream>>>(rpB, colB, F2, F0, degs, 1, F1);   // F1 = x_emb (dropout fused)
    // ---- predictor (edge set 2) ----  (F0 dead during build)
    if (!dual) build_csr(s2, d2, EE, gE, 0, rpA, colA, F0);
    k_gemm64<false,true><<<6250, 256, 0, stream>>>(F1, pW1, dinv, NN, F0);
    k_gather64<<<gG, 256, 0, stream>>>(rpA, colA, F0, dinv, pb1, F2);
    k_gemm2<true,true><<<gN, 256, 0, stream>>>(F2, pW2, dinv, NN, F1);
    k_gather2<<<gN, 256, 0, stream>>>(rpA, colA, F1, dinv, pb2, out);
    k_probe<<<1, 64, 0, stream>>>(ei, 0u, out);
    return;
  }

  // ================= fallback: verified atomic-scatter path =================
  float* base = (float*)d_ws;
  float* dinv = base;
  int*   cnt  = (int*)(base + 100352);
  float* A    = base + 262144;
  float* B    = A + NF;
  float* C    = B + NF;

  for (int i = 0; i < 3; ++i){
    const int* srcp = ei + (size_t)i*2*EE;
    const int* dstp = srcp + EE;
    k_zero_int<<<gN, 256, 0, stream>>>(cnt, NN);
    k_deg<<<gE, 256, 0, stream>>>(dstp, EE, cnt);
    k_dinv<<<gN, 256, 0, stream>>>(cnt, dinv, NN);
    k_gemm64<false,false><<<6250, 256, 0, stream>>>(x + (size_t)i*NF, lW1 + (size_t)i*64*64, dinv, NN, A);
    k_convinit<<<gNF, 256, 0, stream>>>(A, dinv, lb1 + (size_t)i*64, B);
    k_scatter64<<<8192, 256, 0, stream>>>(srcp, dstp, EE, A, dinv, B);
    k_gemm64<true,false><<<6250, 256, 0, stream>>>(B, lW2 + (size_t)i*64*64, dinv, NN, A);
    float* T = (i == 0) ? C : B;
    k_convinit<<<gNF, 256, 0, stream>>>(A, dinv, lb2 + (size_t)i*64, T);
    k_scatter64<<<8192, 256, 0, stream>>>(srcp, dstp, EE, A, dinv, T);
    if (i > 0){
      const int* recvp = lei + (size_t)(i-1)*2*ELL;
      const int* lsrcp = recvp + ELL;
      k_layeragg<<<4096, 256, 0, stream>>>(recvp, lsrcp, ELL, C, B);
      k_scale<<<gNF, 256, 0, stream>>>(B, degs, i-1, C);
    }
  }
  k_dropout<<<gNF, 256, 0, stream>>>(C, B);
  const int* srcp = ei + (size_t)2*2*EE;
  const int* dstp = srcp + EE;
  k_gemm64<false,false><<<6250, 256, 0, stream>>>(B, pW1, dinv, NN, A);
  k_convinit<<<gNF, 256, 0, stream>>>(A, dinv, pb1, C);
  k_scatter64<<<8192, 256, 0, stream>>>(srcp, dstp, EE, A, dinv, C);
  k_gemm2<true,false><<<gN, 256, 0, stream>>>(C, pW2, dinv, NN, B);
  k_convinit2<<<(NN*2 + 255)/256, 256, 0, stream>>>(B, dinv, pb2, out);
  k_scatter2<<<gE, 256, 0, stream>>>(srcp, dstp, EE, B, dinv, out);
  k_probe<<<1, 64, 0, stream>>>(ei, 0u, out);
}

// Round 13
// 859.560 us; speedup vs baseline: 1.2553x; 1.2553x over previous
//
#include <hip/hip_runtime.h>

#define NN 100000
#define EE 1000000
#define ELL 500000
#define NF (NN*64)
#define NB_SCAN ((NN + 1023) / 1024)   // 98

// ws layouts (floats)
#define OFF_CNT    100352
#define OFF_BSUM   200704
#define OFF_RPA    200832
#define OFF_COLA   301184
#define OFF_RPB    1301184
#define OFF_COLB   1401536
#define WS_SINGLE  (1301184 + 3*NF)              // 82.0 MB
#define WS_DUAL    (2401536 + 3*NF)              // 86.4 MB

// ---------------- Threefry-2x32 ----------------
__device__ __forceinline__ void threefry2x32(unsigned k0, unsigned k1, unsigned &x0, unsigned &x1){
  unsigned ks2 = k0 ^ k1 ^ 0x1BD11BDAu;
#define TF_R(R) { x0 += x1; x1 = (x1<<(R))|(x1>>(32-(R))); x1 ^= x0; }
  x0 += k0; x1 += k1;
  TF_R(13) TF_R(15) TF_R(26) TF_R(6)
  x0 += k1;  x1 += ks2 + 1u;
  TF_R(17) TF_R(29) TF_R(16) TF_R(24)
  x0 += ks2; x1 += k0 + 2u;
  TF_R(13) TF_R(15) TF_R(26) TF_R(6)
  x0 += k0;  x1 += k1 + 3u;
  TF_R(17) TF_R(29) TF_R(16) TF_R(24)
  x0 += k1;  x1 += ks2 + 4u;
  TF_R(13) TF_R(15) TF_R(26) TF_R(6)
  x0 += ks2; x1 += k0 + 5u;
#undef TF_R
}

__device__ __forceinline__ float dropout_val(float v, unsigned i){
  unsigned x0 = 0u, x1 = i;
  threefry2x32(0u, 42u, x0, x1);
  unsigned bits = x0 ^ x1;
  float u = __uint_as_float((bits >> 9) | 0x3f800000u) - 1.0f;
  return (u < 0.6f) ? v * (1.0f/0.6f) : 0.0f;
}

__global__ void k_probe(const int* __restrict__ ei, unsigned hostbits, float* __restrict__ out){
  if (threadIdx.x != 0 || blockIdx.x != 0) return;
  unsigned bits = hostbits;
  { unsigned a=0u, b=0u; threefry2x32(0u, 0u, a, b);
    if (a != 0x6b200159u || b != 0x99ba4efeu) bits |= 1u; }
  if (bits) out[0] = 1.0e4f * (float)bits;
}

// ---------------- utility ----------------
__global__ void k_zero_int(int* __restrict__ p, int n){
  int i = blockIdx.x*256 + threadIdx.x;
  if (i < n) p[i] = 0;
}

__global__ void k_deg(const int* __restrict__ dst, int ne, int* __restrict__ cnt){
  int i = blockIdx.x*256 + threadIdx.x;
  if (i < ne) atomicAdd(&cnt[dst[i]], 1);
}

// degree histogram + within-row rank (atomicAdd return) in ONE pass  [R11-proven]
__global__ void k_degrank(const int* __restrict__ dst, int ne, int* __restrict__ cnt,
                          int* __restrict__ rank){
  int i = blockIdx.x*256 + threadIdx.x;
  if (i >= ne) return;
  rank[i] = atomicAdd(&cnt[dst[i]], 1);
}

__global__ void k_dinv(const int* __restrict__ cnt, float* __restrict__ dinv, int n){
  int i = blockIdx.x*256 + threadIdx.x;
  if (i < n) dinv[i] = 1.0f / sqrtf((float)(cnt[i] + 1));
}

// ---------------- multi-block exclusive scan ----------------
__global__ __launch_bounds__(1024) void k_scan1(const int* __restrict__ cnt, int* __restrict__ bsum, int n){
  __shared__ int lds[1024];
  int t = threadIdx.x, i = blockIdx.x*1024 + t;
  lds[t] = (i < n) ? cnt[i] : 0;
  __syncthreads();
  for (int off = 512; off > 0; off >>= 1){
    if (t < off) lds[t] += lds[t + off];
    __syncthreads();
  }
  if (t == 0) bsum[blockIdx.x] = lds[0];
}

__global__ __launch_bounds__(128) void k_scan2(int* __restrict__ bsum, int nb){
  __shared__ int lds[128];
  int t = threadIdx.x;
  int v = (t < nb) ? bsum[t] : 0;
  lds[t] = v;
  __syncthreads();
  for (int off = 1; off < 128; off <<= 1){
    int x = (t >= off) ? lds[t - off] : 0;
    __syncthreads();
    lds[t] += x;
    __syncthreads();
  }
  if (t < nb) bsum[t] = lds[t] - v;
}

__global__ __launch_bounds__(1024) void k_scan3(const int* __restrict__ cnt, const int* __restrict__ bsum,
                                                int* __restrict__ rowptr, int n){
  __shared__ int lds[1024];
  int t = threadIdx.x, i = blockIdx.x*1024 + t;
  int v = (i < n) ? cnt[i] : 0;
  lds[t] = v;
  __syncthreads();
  for (int off = 1; off < 1024; off <<= 1){
    int x = (t >= off) ? lds[t - off] : 0;
    __syncthreads();
    lds[t] += x;
    __syncthreads();
  }
  int excl = lds[t] - v + bsum[blockIdx.x];
  if (i < n)  rowptr[i] = excl;
  if (i == n-1) rowptr[n] = excl + v;
}

// ---------------- CSR fill, atomic-free (uses precomputed rank)  [R11-proven] ----------------
__global__ void k_fillr(const int* __restrict__ src, const int* __restrict__ dst, int ne,
                        const int* __restrict__ rowptr, const int* __restrict__ rank,
                        int* __restrict__ col){
  int e = blockIdx.x*256 + threadIdx.x;
  if (e >= ne) return;
  col[rowptr[dst[e]] + rank[e]] = src[e];
}

// ---------------- legacy cursor fill (fallback path only) ----------------
__global__ void k_fill(const int* __restrict__ src, const int* __restrict__ dst, int ne,
                       const int* __restrict__ rowptr, int* __restrict__ cursor, int* __restrict__ col){
  int e = blockIdx.x*256 + threadIdx.x;
  if (e >= ne) return;
  int d = dst[e];
  int p = atomicAdd(&cursor[d], 1);
  col[rowptr[d] + p] = src[e];
}

// ---------------- GEMM [nrows,64] @ [64,64]; RELU on input; SCALE: Y[row] *= dinv[row] ----------------
template<bool RELU, bool SCALE>
__global__ __launch_bounds__(256) void k_gemm64(const float* __restrict__ X, const float* __restrict__ W,
                                                const float* __restrict__ dinv,
                                                int nrows, float* __restrict__ Y){
  __shared__ float Ws[64][64];
  int t = threadIdx.x;
  {
    const float4* W4 = (const float4*)W;
    float4* S4 = (float4*)&Ws[0][0];
    #pragma unroll
    for (int i = 0; i < 4; ++i) S4[t + 256*i] = W4[t + 256*i];
  }
  __syncthreads();
  int row = blockIdx.x*16 + (t>>4);
  if (row >= nrows) return;
  int c0 = (t & 15) * 4;
  const float4* Xr = (const float4*)(X + (size_t)row*64);
  float4 acc = make_float4(0.f,0.f,0.f,0.f);
  #pragma unroll
  for (int kk = 0; kk < 16; ++kk){
    float4 xv = Xr[kk];
    if (RELU){
      xv.x = fmaxf(xv.x, 0.f); xv.y = fmaxf(xv.y, 0.f);
      xv.z = fmaxf(xv.z, 0.f); xv.w = fmaxf(xv.w, 0.f);
    }
    int k = kk*4;
    float4 w0 = *(const float4*)&Ws[k+0][c0];
    float4 w1 = *(const float4*)&Ws[k+1][c0];
    float4 w2 = *(const float4*)&Ws[k+2][c0];
    float4 w3 = *(const float4*)&Ws[k+3][c0];
    acc.x = fmaf(xv.x, w0.x, acc.x); acc.y = fmaf(xv.x, w0.y, acc.y);
    acc.z = fmaf(xv.x, w0.z, acc.z); acc.w = fmaf(xv.x, w0.w, acc.w);
    acc.x = fmaf(xv.y, w1.x, acc.x); acc.y = fmaf(xv.y, w1.y, acc.y);
    acc.z = fmaf(xv.y, w1.z, acc.z); acc.w = fmaf(xv.y, w1.w, acc.w);
    acc.x = fmaf(xv.z, w2.x, acc.x); acc.y = fmaf(xv.z, w2.y, acc.y);
    acc.z = fmaf(xv.z, w2.z, acc.z); acc.w = fmaf(xv.z, w2.w, acc.w);
    acc.x = fmaf(xv.w, w3.x, acc.x); acc.y = fmaf(xv.w, w3.y, acc.y);
    acc.z = fmaf(xv.w, w3.z, acc.z); acc.w = fmaf(xv.w, w3.w, acc.w);
  }
  if (SCALE){
    float dv = dinv[row];
    acc.x *= dv; acc.y *= dv; acc.z *= dv; acc.w *= dv;
  }
  *(float4*)(Y + (size_t)row*64 + c0) = acc;
}

// ---------------- GEMM [nrows,64] @ [64,2] ----------------
template<bool RELU, bool SCALE>
__global__ __launch_bounds__(256) void k_gemm2(const float* __restrict__ X, const float* __restrict__ W,
                                               const float* __restrict__ dinv,
                                               int nrows, float* __restrict__ Y){
  __shared__ float Ws[128];
  int t = threadIdx.x;
  if (t < 128) Ws[t] = W[t];
  __syncthreads();
  int row = blockIdx.x*256 + t;
  if (row >= nrows) return;
  const float4* Xr = (const float4*)(X + (size_t)row*64);
  float a0 = 0.f, a1 = 0.f;
  #pragma unroll
  for (int kk = 0; kk < 16; ++kk){
    float4 xv = Xr[kk];
    if (RELU){ xv.x=fmaxf(xv.x,0.f); xv.y=fmaxf(xv.y,0.f); xv.z=fmaxf(xv.z,0.f); xv.w=fmaxf(xv.w,0.f); }
    int k = kk*4;
    a0 = fmaf(xv.x, Ws[2*k+0], a0); a1 = fmaf(xv.x, Ws[2*k+1], a1);
    a0 = fmaf(xv.y, Ws[2*k+2], a0); a1 = fmaf(xv.y, Ws[2*k+3], a1);
    a0 = fmaf(xv.z, Ws[2*k+4], a0); a1 = fmaf(xv.z, Ws[2*k+5], a1);
    a0 = fmaf(xv.w, Ws[2*k+6], a0); a1 = fmaf(xv.w, Ws[2*k+7], a1);
  }
  if (SCALE){ float dv = dinv[row]; a0 *= dv; a1 *= dv; }
  Y[(size_t)row*2]   = a0;
  Y[(size_t)row*2+1] = a1;
}

// ---------------- CSR gather conv: float4 lanes, 4 edges per wave-issue ----------------
// lane = (grp = edge slot 0..3) x (fq = feature quad 0..15); one node per wave.
__global__ __launch_bounds__(256) void k_gather64(const int* __restrict__ rowptr, const int* __restrict__ col,
                                                  const float* __restrict__ h, const float* __restrict__ dinv,
                                                  const float* __restrict__ b, float* __restrict__ out){
  int lane = threadIdx.x & 63;
  int node = (blockIdx.x*256 + threadIdx.x) >> 6;
  if (node >= NN) return;
  int grp = lane >> 4, fq = lane & 15;
  int beg = rowptr[node], end = rowptr[node+1];
  const float4* h4 = (const float4*)h;
  float4 acc = make_float4(0.f,0.f,0.f,0.f);
  if (grp == 0) acc = h4[(size_t)node*16 + fq];       // self-loop (h pre-scaled)
  // 2-slot software pipeline: col for the NEXT 8 edges prefetched before the adds
  int c0 = (beg + grp     < end) ? col[beg + grp]     : -1;
  int c1 = (beg + 4 + grp < end) ? col[beg + 4 + grp] : -1;
  for (int j = beg; j < end; j += 8){
    int cc0 = c0, cc1 = c1;
    int nj = j + 8;
    c0 = (nj + grp     < end) ? col[nj + grp]     : -1;
    c1 = (nj + 4 + grp < end) ? col[nj + 4 + grp] : -1;
    if (cc0 >= 0){
      float4 v = h4[(size_t)cc0*16 + fq];
      acc.x += v.x; acc.y += v.y; acc.z += v.z; acc.w += v.w;
    }
    if (cc1 >= 0){
      float4 v = h4[(size_t)cc1*16 + fq];
      acc.x += v.x; acc.y += v.y; acc.z += v.z; acc.w += v.w;
    }
  }
  // reduce the 4 edge groups (lanes stride 16)
  acc.x += __shfl_xor(acc.x, 16); acc.y += __shfl_xor(acc.y, 16);
  acc.z += __shfl_xor(acc.z, 16); acc.w += __shfl_xor(acc.w, 16);
  acc.x += __shfl_xor(acc.x, 32); acc.y += __shfl_xor(acc.y, 32);
  acc.z += __shfl_xor(acc.z, 32); acc.w += __shfl_xor(acc.w, 32);
  if (grp == 0){
    float dv = dinv[node];
    float4 bb = ((const float4*)b)[fq];
    float4 r;
    r.x = fmaf(acc.x, dv, bb.x); r.y = fmaf(acc.y, dv, bb.y);
    r.z = fmaf(acc.z, dv, bb.z); r.w = fmaf(acc.w, dv, bb.w);
    *(float4*)(out + (size_t)node*64 + fq*4) = r;
  }
}

// ---------------- CSR gather cross-layer agg, float4 (+ optional fused dropout) ----------------
template<bool DROP>
__global__ __launch_bounds__(256) void k_agggather(const int* __restrict__ rowptr, const int* __restrict__ col,
                                                    const float* __restrict__ lf, const float* __restrict__ last,
                                                    const float* __restrict__ ds, int dsidx, float* __restrict__ out){
  int lane = threadIdx.x & 63;
  int node = (blockIdx.x*256 + threadIdx.x) >> 6;
  if (node >= NN) return;
  int grp = lane >> 4, fq = lane & 15;
  int beg = rowptr[node], end = rowptr[node+1];
  const float4* l4 = (const float4*)last;
  float4 acc = make_float4(0.f,0.f,0.f,0.f);
  if (grp == 0) acc = ((const float4*)lf)[(size_t)node*16 + fq];
  int c0 = (beg + grp     < end) ? col[beg + grp]     : -1;
  int c1 = (beg + 4 + grp < end) ? col[beg + 4 + grp] : -1;
  for (int j = beg; j < end; j += 8){
    int cc0 = c0, cc1 = c1;
    int nj = j + 8;
    c0 = (nj + grp     < end) ? col[nj + grp]     : -1;
    c1 = (nj + 4 + grp < end) ? col[nj + 4 + grp] : -1;
    if (cc0 >= 0){
      float4 v = l4[(size_t)cc0*16 + fq];
      acc.x += v.x; acc.y += v.y; acc.z += v.z; acc.w += v.w;
    }
    if (cc1 >= 0){
      float4 v = l4[(size_t)cc1*16 + fq];
      acc.x += v.x; acc.y += v.y; acc.z += v.z; acc.w += v.w;
    }
  }
  acc.x += __shfl_xor(acc.x, 16); acc.y += __shfl_xor(acc.y, 16);
  acc.z += __shfl_xor(acc.z, 16); acc.w += __shfl_xor(acc.w, 16);
  acc.x += __shfl_xor(acc.x, 32); acc.y += __shfl_xor(acc.y, 32);
  acc.z += __shfl_xor(acc.z, 32); acc.w += __shfl_xor(acc.w, 32);
  float dsv = ds[dsidx];
  if (DROP){
    // all 64 lanes: lane handles feature fq*4 + grp (one component of its quad)
    float val = (grp == 0) ? acc.x : (grp == 1) ? acc.y : (grp == 2) ? acc.z : acc.w;
    val /= dsv;
    unsigned i = (unsigned)node*64u + (unsigned)(fq*4 + grp);
    out[i] = dropout_val(val, i);
  } else if (grp == 0){
    float4 r;
    r.x = acc.x / dsv; r.y = acc.y / dsv; r.z = acc.z / dsv; r.w = acc.w / dsv;
    *(float4*)(out + (size_t)node*64 + fq*4) = r;
  }
}

// ---------------- CSR gather final conv (D_out=2) ----------------
__global__ void k_gather2(const int* __restrict__ rowptr, const int* __restrict__ col,
                          const float* __restrict__ h2, const float* __restrict__ dinv,
                          const float* __restrict__ b, float* __restrict__ out){
  int d = blockIdx.x*256 + threadIdx.x;
  if (d >= NN) return;
  int beg = rowptr[d], end = rowptr[d+1];
  float a0 = h2[(size_t)d*2];
  float a1 = h2[(size_t)d*2+1];
  for (int j = beg; j < end; ++j){
    int s = col[j];
    a0 += h2[(size_t)s*2];
    a1 += h2[(size_t)s*2+1];
  }
  float dv = dinv[d];
  out[(size_t)d*2]   = fmaf(a0, dv, b[0]);
  out[(size_t)d*2+1] = fmaf(a1, dv, b[1]);
}

// ---------------- standalone dropout (fallback path only) ----------------
__global__ void k_dropout(const float* __restrict__ last, float* __restrict__ xemb){
  unsigned i = blockIdx.x*256 + threadIdx.x;
  if (i >= NF) return;
  xemb[i] = dropout_val(last[i], i);
}

// ======== fallback (atomic scatter) kernels ========
__global__ void k_convinit(const float* __restrict__ h, const float* __restrict__ dinv,
                           const float* __restrict__ b, float* __restrict__ out){
  int i = blockIdx.x*256 + threadIdx.x;
  if (i >= NF) return;
  int v = i >> 6, c = i & 63;
  float dv = dinv[v];
  out[i] = h[i]*dv*dv + b[c];
}
__global__ void k_scatter64(const int* __restrict__ src, const int* __restrict__ dst, int ne,
                            const float* __restrict__ h, const float* __restrict__ dinv,
                            float* __restrict__ out){
  int lane = threadIdx.x & 63;
  int wid  = (blockIdx.x*256 + threadIdx.x) >> 6;
  int nw   = (gridDim.x*256) >> 6;
  for (int e = wid; e < ne; e += nw){
    int s = src[e], d = dst[e];
    float coef = dinv[s]*dinv[d];
    atomicAdd(&out[d*64 + lane], h[s*64 + lane]*coef);
  }
}
__global__ void k_layeragg(const int* __restrict__ recv, const int* __restrict__ srcn, int ne,
                           const float* __restrict__ last, float* __restrict__ acc){
  int lane = threadIdx.x & 63;
  int wid  = (blockIdx.x*256 + threadIdx.x) >> 6;
  int nw   = (gridDim.x*256) >> 6;
  for (int e = wid; e < ne; e += nw){
    int r = recv[e], s = srcn[e];
    atomicAdd(&acc[r*64 + lane], last[s*64 + lane]);
  }
}
__global__ void k_scale(const float* __restrict__ in, const float* __restrict__ ds, int dsidx,
                        float* __restrict__ out){
  int i = blockIdx.x*256 + threadIdx.x;
  if (i < NF) out[i] = in[i] / ds[dsidx];
}
__global__ void k_convinit2(const float* __restrict__ h2, const float* __restrict__ dinv,
                            const float* __restrict__ b, float* __restrict__ out){
  int i = blockIdx.x*256 + threadIdx.x;
  if (i >= NN*2) return;
  int v = i >> 1, c = i & 1;
  float dv = dinv[v];
  out[i] = h2[i]*dv*dv + b[c];
}
__global__ void k_scatter2(const int* __restrict__ src, const int* __restrict__ dst, int ne,
                           const float* __restrict__ h2, const float* __restrict__ dinv,
                           float* __restrict__ out){
  int e = blockIdx.x*256 + threadIdx.x;
  if (e >= ne) return;
  int s = src[e], d = dst[e];
  float coef = dinv[s]*dinv[d];
  atomicAdd(&out[d*2 + 0], h2[s*2 + 0]*coef);
  atomicAdd(&out[d*2 + 1], h2[s*2 + 1]*coef);
}

extern "C" void kernel_launch(void* const* d_in, const int* in_sizes, int n_in,
                              void* d_out, int out_size, void* d_ws, size_t ws_size,
                              hipStream_t stream) {
  const float* x    = (const float*)d_in[0];
  const int*   ei   = (const int*)  d_in[1];
  const int*   lei  = (const int*)  d_in[2];
  const float* degs = (const float*)d_in[3];
  const float* lW1  = (const float*)d_in[4];
  const float* lb1  = (const float*)d_in[5];
  const float* lW2  = (const float*)d_in[6];
  const float* lb2  = (const float*)d_in[7];
  const float* pW1  = (const float*)d_in[8];
  const float* pb1  = (const float*)d_in[9];
  const float* pW2  = (const float*)d_in[10];
  const float* pb2  = (const float*)d_in[11];
  float* out = (float*)d_out;

  const int gN  = (NN + 255)/256;
  const int gE  = (EE + 255)/256;
  const int gEL = (ELL + 255)/256;
  const int gNF = (NF + 255)/256;
  const int gG  = (NN*64 + 255)/256;

  const bool dual   = ws_size >= (size_t)WS_DUAL * 4;
  const bool single = ws_size >= (size_t)WS_SINGLE * 4;

  if (single) {
    float* base   = (float*)d_ws;
    float* dinv   = base;
    int*   cnt    = (int*)(base + OFF_CNT);
    int*   bsum   = (int*)(base + OFF_BSUM);
    int*   rpA    = (int*)(base + OFF_RPA);
    int*   colA   = (int*)(base + OFF_COLA);
    int*   rpB    = dual ? (int*)(base + OFF_RPB)  : rpA;
    int*   colB   = dual ? (int*)(base + OFF_COLB) : colA;
    float* F0     = base + (dual ? OFF_COLB + 1000000 : OFF_RPB);
    float* F1     = F0 + NF;
    float* F2     = F1 + NF;

    // rank buffer aliases a provably-dead F buffer per build (consumed within the build)
    auto build_csr = [&](const int* srcp, const int* dstp, int ne, int gEdges, bool computeDinv,
                         int* rowptr, int* col, int* rank){
      k_zero_int<<<gN, 256, 0, stream>>>(cnt, NN);
      k_degrank<<<gEdges, 256, 0, stream>>>(dstp, ne, cnt, rank);
      if (computeDinv) k_dinv<<<gN, 256, 0, stream>>>(cnt, dinv, NN);
      k_scan1<<<NB_SCAN, 1024, 0, stream>>>(cnt, bsum, NN);
      k_scan2<<<1, 128, 0, stream>>>(bsum, NB_SCAN);
      k_scan3<<<NB_SCAN, 1024, 0, stream>>>(cnt, bsum, rowptr, NN);
      k_fillr<<<gEdges, 256, 0, stream>>>(srcp, dstp, ne, rowptr, rank, col);
    };

    const int* s0 = ei;                  const int* d0 = s0 + EE;
    const int* s1 = ei + 2*(size_t)EE;   const int* d1 = s1 + EE;
    const int* s2 = ei + 4*(size_t)EE;   const int* d2 = s2 + EE;
    const int* r0 = lei;                 const int* ls0 = r0 + ELL;
    const int* r1 = lei + 2*(size_t)ELL; const int* ls1 = r1 + ELL;

    // ---- surface 0 ----  (F0 dead during build)
    build_csr(s0, d0, EE, gE, true, rpA, colA, (int*)F0);
    k_gemm64<false,true><<<6250, 256, 0, stream>>>(x, lW1, dinv, NN, F0);
    k_gather64<<<gG, 256, 0, stream>>>(rpA, colA, F0, dinv, lb1, F1);
    k_gemm64<true,true><<<6250, 256, 0, stream>>>(F1, lW2, dinv, NN, F0);
    k_gather64<<<gG, 256, 0, stream>>>(rpA, colA, F0, dinv, lb2, F2);            // last = F2
    // ---- surface 1 ----  (F0 dead during both builds)
    build_csr(s1, d1, EE, gE, true, rpA, colA, (int*)F0);
    k_gemm64<false,true><<<6250, 256, 0, stream>>>(x + (size_t)NF, lW1 + 4096, dinv, NN, F0);
    k_gather64<<<gG, 256, 0, stream>>>(rpA, colA, F0, dinv, lb1 + 64, F1);
    k_gemm64<true,true><<<6250, 256, 0, stream>>>(F1, lW2 + 4096, dinv, NN, F0);
    k_gather64<<<gG, 256, 0, stream>>>(rpA, colA, F0, dinv, lb2 + 64, F1);       // lf = F1
    build_csr(ls0, r0, ELL, gEL, false, rpB, colB, (int*)F0);
    k_agggather<false><<<gG, 256, 0, stream>>>(rpB, colB, F1, F2, degs, 0, F0);  // last = F0
    // ---- surface 2 ----  (F1 dead during both builds)
    build_csr(s2, d2, EE, gE, true, rpA, colA, (int*)F1);
    k_gemm64<false,true><<<6250, 256, 0, stream>>>(x + 2*(size_t)NF, lW1 + 8192, dinv, NN, F1);
    k_gather64<<<gG, 256, 0, stream>>>(rpA, colA, F1, dinv, lb1 + 128, F2);
    k_gemm64<true,true><<<6250, 256, 0, stream>>>(F2, lW2 + 8192, dinv, NN, F1);
    k_gather64<<<gG, 256, 0, stream>>>(rpA, colA, F1, dinv, lb2 + 128, F2);      // lf = F2
    build_csr(ls1, r1, ELL, gEL, false, rpB, colB, (int*)F1);
    k_agggather<true><<<gG, 256, 0, stream>>>(rpB, colB, F2, F0, degs, 1, F1);   // F1 = x_emb (dropout fused)
    // ---- predictor (edge set 2) ----  (F0 dead during build)
    if (!dual) build_csr(s2, d2, EE, gE, false, rpA, colA, (int*)F0);
    k_gemm64<false,true><<<6250, 256, 0, stream>>>(F1, pW1, dinv, NN, F0);
    k_gather64<<<gG, 256, 0, stream>>>(rpA, colA, F0, dinv, pb1, F2);
    k_gemm2<true,true><<<gN, 256, 0, stream>>>(F2, pW2, dinv, NN, F1);
    k_gather2<<<gN, 256, 0, stream>>>(rpA, colA, F1, dinv, pb2, out);
    k_probe<<<1, 64, 0, stream>>>(ei, 0u, out);
    return;
  }

  // ================= fallback: verified atomic-scatter path =================
  float* base = (float*)d_ws;
  float* dinv = base;
  int*   cnt  = (int*)(base + 100352);
  float* A    = base + 262144;
  float* B    = A + NF;
  float* C    = B + NF;

  for (int i = 0; i < 3; ++i){
    const int* srcp = ei + (size_t)i*2*EE;
    const int* dstp = srcp + EE;
    k_zero_int<<<gN, 256, 0, stream>>>(cnt, NN);
    k_deg<<<gE, 256, 0, stream>>>(dstp, EE, cnt);
    k_dinv<<<gN, 256, 0, stream>>>(cnt, dinv, NN);
    k_gemm64<false,false><<<6250, 256, 0, stream>>>(x + (size_t)i*NF, lW1 + (size_t)i*64*64, dinv, NN, A);
    k_convinit<<<gNF, 256, 0, stream>>>(A, dinv, lb1 + (size_t)i*64, B);
    k_scatter64<<<8192, 256, 0, stream>>>(srcp, dstp, EE, A, dinv, B);
    k_gemm64<true,false><<<6250, 256, 0, stream>>>(B, lW2 + (size_t)i*64*64, dinv, NN, A);
    float* T = (i == 0) ? C : B;
    k_convinit<<<gNF, 256, 0, stream>>>(A, dinv, lb2 + (size_t)i*64, T);
    k_scatter64<<<8192, 256, 0, stream>>>(srcp, dstp, EE, A, dinv, T);
    if (i > 0){
      const int* recvp = lei + (size_t)(i-1)*2*ELL;
      const int* lsrcp = recvp + ELL;
      k_layeragg<<<4096, 256, 0, stream>>>(recvp, lsrcp, ELL, C, B);
      k_scale<<<gNF, 256, 0, stream>>>(B, degs, i-1, C);
    }
  }
  k_dropout<<<gNF, 256, 0, stream>>>(C, B);
  const int* srcp = ei + (size_t)2*2*EE;
  const int* dstp = srcp + EE;
  k_gemm64<false,false><<<6250, 256, 0, stream>>>(B, pW1, dinv, NN, A);
  k_convinit<<<gNF, 256, 0, stream>>>(A, dinv, pb1, C);
  k_scatter64<<<8192, 256, 0, stream>>>(srcp, dstp, EE, A, dinv, C);
  k_gemm2<true,false><<<gN, 256, 0, stream>>>(C, pW2, dinv, NN, B);
  k_convinit2<<<(NN*2 + 255)/256, 256, 0, stream>>>(B, dinv, pb2, out);
  k_scatter2<<<gE, 256, 0, stream>>>(srcp, dstp, EE, B, dinv, out);
  k_probe<<<1, 64, 0, stream>>>(ei, 0u, out);
}

// Round 14
// 818.640 us; speedup vs baseline: 1.3181x; 1.0500x over previous
//
#include <hip/hip_runtime.h>

#define NN 100000
#define EE 1000000
#define ELL 500000
#define NF (NN*64)
#define NB_SCAN ((NN + 1023) / 1024)   // 98

// ws layouts (floats)
#define OFF_CNT    100352
#define OFF_BSUM   200704
#define OFF_RPA    200832
#define OFF_COLA   301184
#define OFF_RPB    1301184
#define OFF_COLB   1401536
#define WS_SINGLE  (1301184 + 3*NF)              // 82.0 MB
#define WS_DUAL    (2401536 + 3*NF)              // 86.4 MB

// ---------------- Threefry-2x32 ----------------
__device__ __forceinline__ void threefry2x32(unsigned k0, unsigned k1, unsigned &x0, unsigned &x1){
  unsigned ks2 = k0 ^ k1 ^ 0x1BD11BDAu;
#define TF_R(R) { x0 += x1; x1 = (x1<<(R))|(x1>>(32-(R))); x1 ^= x0; }
  x0 += k0; x1 += k1;
  TF_R(13) TF_R(15) TF_R(26) TF_R(6)
  x0 += k1;  x1 += ks2 + 1u;
  TF_R(17) TF_R(29) TF_R(16) TF_R(24)
  x0 += ks2; x1 += k0 + 2u;
  TF_R(13) TF_R(15) TF_R(26) TF_R(6)
  x0 += k0;  x1 += k1 + 3u;
  TF_R(17) TF_R(29) TF_R(16) TF_R(24)
  x0 += k1;  x1 += ks2 + 4u;
  TF_R(13) TF_R(15) TF_R(26) TF_R(6)
  x0 += ks2; x1 += k0 + 5u;
#undef TF_R
}

__device__ __forceinline__ float dropout_val(float v, unsigned i){
  unsigned x0 = 0u, x1 = i;
  threefry2x32(0u, 42u, x0, x1);
  unsigned bits = x0 ^ x1;
  float u = __uint_as_float((bits >> 9) | 0x3f800000u) - 1.0f;
  return (u < 0.6f) ? v * (1.0f/0.6f) : 0.0f;
}

__global__ void k_probe(const int* __restrict__ ei, unsigned hostbits, float* __restrict__ out){
  if (threadIdx.x != 0 || blockIdx.x != 0) return;
  unsigned bits = hostbits;
  { unsigned a=0u, b=0u; threefry2x32(0u, 0u, a, b);
    if (a != 0x6b200159u || b != 0x99ba4efeu) bits |= 1u; }
  if (bits) out[0] = 1.0e4f * (float)bits;
}

// ---------------- utility ----------------
__global__ void k_zero_int(int* __restrict__ p, int n){
  int i = blockIdx.x*256 + threadIdx.x;
  if (i < n) p[i] = 0;
}

// zero cnt + the scan barrier flag in one launch
__global__ void k_zerof(int* __restrict__ cnt, int n, int* __restrict__ flag){
  int i = blockIdx.x*256 + threadIdx.x;
  if (i < n) cnt[i] = 0;
  if (i == 0) *flag = 0;
}

__global__ void k_deg(const int* __restrict__ dst, int ne, int* __restrict__ cnt){
  int i = blockIdx.x*256 + threadIdx.x;
  if (i < ne) atomicAdd(&cnt[dst[i]], 1);
}

// degree histogram + within-row rank (atomicAdd return) in ONE pass
__global__ void k_degrank(const int* __restrict__ dst, int ne, int* __restrict__ cnt,
                          int* __restrict__ rank){
  int i = blockIdx.x*256 + threadIdx.x;
  if (i >= ne) return;
  rank[i] = atomicAdd(&cnt[dst[i]], 1);
}

__global__ void k_dinv(const int* __restrict__ cnt, float* __restrict__ dinv, int n){
  int i = blockIdx.x*256 + threadIdx.x;
  if (i < n) dinv[i] = 1.0f / sqrtf((float)(cnt[i] + 1));
}

// ---------------- fused single-launch scan (98 blocks, device spin barrier) + dinv ----------------
__global__ __launch_bounds__(1024) void k_scanfused(const int* __restrict__ cnt, int* __restrict__ bsum,
                                                    int* __restrict__ flag, int* __restrict__ rowptr,
                                                    float* __restrict__ dinv, int computeDinv, int n){
  __shared__ int lds[1024];
  __shared__ int ps[128];
  int t = threadIdx.x;
  int i = blockIdx.x*1024 + t;
  int v = (i < n) ? cnt[i] : 0;
  if (computeDinv && i < n) dinv[i] = 1.0f / sqrtf((float)(v + 1));
  lds[t] = v;
  __syncthreads();
  for (int off = 1; off < 1024; off <<= 1){
    int x = (t >= off) ? lds[t - off] : 0;
    __syncthreads();
    lds[t] += x;
    __syncthreads();
  }
  int incl = lds[t];
  // post block total (release), then barrier-spin until all posted
  if (t == 1023){
    bsum[blockIdx.x] = lds[1023];
    __threadfence();
    atomicAdd(flag, 1);
  }
  if (t == 0){
    while (atomicAdd(flag, 0) < NB_SCAN) { }
  }
  __syncthreads();
  // parallel prefix of preceding block totals
  if (t < 128) ps[t] = (t < blockIdx.x) ? bsum[t] : 0;
  __syncthreads();
  if (t < 64) ps[t] += ps[t + 64];
  __syncthreads();
  if (t < 32) ps[t] += ps[t + 32];
  __syncthreads();
  if (t < 16) ps[t] += ps[t + 16];
  __syncthreads();
  if (t < 8)  ps[t] += ps[t + 8];
  __syncthreads();
  if (t < 4)  ps[t] += ps[t + 4];
  __syncthreads();
  if (t < 2)  ps[t] += ps[t + 2];
  __syncthreads();
  if (t < 1)  ps[t] += ps[t + 1];
  __syncthreads();
  int excl = incl - v + ps[0];
  if (i < n)  rowptr[i] = excl;
  if (i == n-1) rowptr[n] = excl + v;
}

// ---------------- CSR fill, atomic-free ----------------
__global__ void k_fillr(const int* __restrict__ src, const int* __restrict__ dst, int ne,
                        const int* __restrict__ rowptr, const int* __restrict__ rank,
                        int* __restrict__ col){
  int e = blockIdx.x*256 + threadIdx.x;
  if (e >= ne) return;
  col[rowptr[dst[e]] + rank[e]] = src[e];
}

// ---------------- GEMM [nrows,64] @ [64,64]; RELU on input; SCALE: Y[row] *= dinv[row] ----------------
template<bool RELU, bool SCALE>
__global__ __launch_bounds__(256) void k_gemm64(const float* __restrict__ X, const float* __restrict__ W,
                                                const float* __restrict__ dinv,
                                                int nrows, float* __restrict__ Y){
  __shared__ float Ws[64][64];
  int t = threadIdx.x;
  {
    const float4* W4 = (const float4*)W;
    float4* S4 = (float4*)&Ws[0][0];
    #pragma unroll
    for (int i = 0; i < 4; ++i) S4[t + 256*i] = W4[t + 256*i];
  }
  __syncthreads();
  int row = blockIdx.x*16 + (t>>4);
  if (row >= nrows) return;
  int c0 = (t & 15) * 4;
  const float4* Xr = (const float4*)(X + (size_t)row*64);
  float4 acc = make_float4(0.f,0.f,0.f,0.f);
  #pragma unroll
  for (int kk = 0; kk < 16; ++kk){
    float4 xv = Xr[kk];
    if (RELU){
      xv.x = fmaxf(xv.x, 0.f); xv.y = fmaxf(xv.y, 0.f);
      xv.z = fmaxf(xv.z, 0.f); xv.w = fmaxf(xv.w, 0.f);
    }
    int k = kk*4;
    float4 w0 = *(const float4*)&Ws[k+0][c0];
    float4 w1 = *(const float4*)&Ws[k+1][c0];
    float4 w2 = *(const float4*)&Ws[k+2][c0];
    float4 w3 = *(const float4*)&Ws[k+3][c0];
    acc.x = fmaf(xv.x, w0.x, acc.x); acc.y = fmaf(xv.x, w0.y, acc.y);
    acc.z = fmaf(xv.x, w0.z, acc.z); acc.w = fmaf(xv.x, w0.w, acc.w);
    acc.x = fmaf(xv.y, w1.x, acc.x); acc.y = fmaf(xv.y, w1.y, acc.y);
    acc.z = fmaf(xv.y, w1.z, acc.z); acc.w = fmaf(xv.y, w1.w, acc.w);
    acc.x = fmaf(xv.z, w2.x, acc.x); acc.y = fmaf(xv.z, w2.y, acc.y);
    acc.z = fmaf(xv.z, w2.z, acc.z); acc.w = fmaf(xv.z, w2.w, acc.w);
    acc.x = fmaf(xv.w, w3.x, acc.x); acc.y = fmaf(xv.w, w3.y, acc.y);
    acc.z = fmaf(xv.w, w3.z, acc.z); acc.w = fmaf(xv.w, w3.w, acc.w);
  }
  if (SCALE){
    float dv = dinv[row];
    acc.x *= dv; acc.y *= dv; acc.z *= dv; acc.w *= dv;
  }
  *(float4*)(Y + (size_t)row*64 + c0) = acc;
}

// ---------------- GEMM [nrows,64] @ [64,2] ----------------
template<bool RELU, bool SCALE>
__global__ __launch_bounds__(256) void k_gemm2(const float* __restrict__ X, const float* __restrict__ W,
                                               const float* __restrict__ dinv,
                                               int nrows, float* __restrict__ Y){
  __shared__ float Ws[128];
  int t = threadIdx.x;
  if (t < 128) Ws[t] = W[t];
  __syncthreads();
  int row = blockIdx.x*256 + t;
  if (row >= nrows) return;
  const float4* Xr = (const float4*)(X + (size_t)row*64);
  float a0 = 0.f, a1 = 0.f;
  #pragma unroll
  for (int kk = 0; kk < 16; ++kk){
    float4 xv = Xr[kk];
    if (RELU){ xv.x=fmaxf(xv.x,0.f); xv.y=fmaxf(xv.y,0.f); xv.z=fmaxf(xv.z,0.f); xv.w=fmaxf(xv.w,0.f); }
    int k = kk*4;
    a0 = fmaf(xv.x, Ws[2*k+0], a0); a1 = fmaf(xv.x, Ws[2*k+1], a1);
    a0 = fmaf(xv.y, Ws[2*k+2], a0); a1 = fmaf(xv.y, Ws[2*k+3], a1);
    a0 = fmaf(xv.z, Ws[2*k+4], a0); a1 = fmaf(xv.z, Ws[2*k+5], a1);
    a0 = fmaf(xv.w, Ws[2*k+6], a0); a1 = fmaf(xv.w, Ws[2*k+7], a1);
  }
  if (SCALE){ float dv = dinv[row]; a0 *= dv; a1 *= dv; }
  Y[(size_t)row*2]   = a0;
  Y[(size_t)row*2+1] = a1;
}

// ---------------- CSR gather conv: 16-lane group per node, float4 lanes, 4-deep pipeline ----------------
__global__ __launch_bounds__(256) void k_gather64(const int* __restrict__ rowptr, const int* __restrict__ col,
                                                  const float* __restrict__ h, const float* __restrict__ dinv,
                                                  const float* __restrict__ b, float* __restrict__ out){
  int gt = blockIdx.x*256 + threadIdx.x;
  int fq = gt & 15;
  int node = gt >> 4;
  if (node >= NN) return;
  int beg = rowptr[node], end = rowptr[node+1];
  const float4* __restrict__ h4 = (const float4*)h;
  float4 acc = h4[(size_t)node*16 + fq];          // self-loop (h pre-scaled by dinv)
  int j = beg;
  bool p0 = j   < end; int c0 = p0 ? col[j]   : 0;
  bool p1 = j+1 < end; int c1 = p1 ? col[j+1] : 0;
  bool p2 = j+2 < end; int c2 = p2 ? col[j+2] : 0;
  bool p3 = j+3 < end; int c3 = p3 ? col[j+3] : 0;
  while (p0){
    float4 v0 = h4[(size_t)c0*16 + fq];
    float4 v1 = p1 ? h4[(size_t)c1*16 + fq] : make_float4(0.f,0.f,0.f,0.f);
    float4 v2 = p2 ? h4[(size_t)c2*16 + fq] : make_float4(0.f,0.f,0.f,0.f);
    float4 v3 = p3 ? h4[(size_t)c3*16 + fq] : make_float4(0.f,0.f,0.f,0.f);
    j += 4;
    bool q0 = j < end, q1 = j+1 < end, q2 = j+2 < end, q3 = j+3 < end;
    int n0 = q0 ? col[j]   : 0;
    int n1 = q1 ? col[j+1] : 0;
    int n2 = q2 ? col[j+2] : 0;
    int n3 = q3 ? col[j+3] : 0;
    acc.x += v0.x + v1.x + v2.x + v3.x;
    acc.y += v0.y + v1.y + v2.y + v3.y;
    acc.z += v0.z + v1.z + v2.z + v3.z;
    acc.w += v0.w + v1.w + v2.w + v3.w;
    p0=q0; p1=q1; p2=q2; p3=q3; c0=n0; c1=n1; c2=n2; c3=n3;
  }
  float dv = dinv[node];
  float4 bb = ((const float4*)b)[fq];
  float4 r;
  r.x = fmaf(acc.x, dv, bb.x); r.y = fmaf(acc.y, dv, bb.y);
  r.z = fmaf(acc.z, dv, bb.z); r.w = fmaf(acc.w, dv, bb.w);
  *(float4*)(out + (size_t)node*64 + fq*4) = r;
}

// ---------------- CSR gather cross-layer agg, 16-lane group (+ optional fused dropout) ----------------
template<bool DROP>
__global__ __launch_bounds__(256) void k_agggather(const int* __restrict__ rowptr, const int* __restrict__ col,
                                                    const float* __restrict__ lf, const float* __restrict__ last,
                                                    const float* __restrict__ ds, int dsidx, float* __restrict__ out){
  int gt = blockIdx.x*256 + threadIdx.x;
  int fq = gt & 15;
  int node = gt >> 4;
  if (node >= NN) return;
  int beg = rowptr[node], end = rowptr[node+1];
  const float4* __restrict__ l4 = (const float4*)last;
  float4 acc = ((const float4*)lf)[(size_t)node*16 + fq];
  int j = beg;
  bool p0 = j   < end; int c0 = p0 ? col[j]   : 0;
  bool p1 = j+1 < end; int c1 = p1 ? col[j+1] : 0;
  bool p2 = j+2 < end; int c2 = p2 ? col[j+2] : 0;
  bool p3 = j+3 < end; int c3 = p3 ? col[j+3] : 0;
  while (p0){
    float4 v0 = l4[(size_t)c0*16 + fq];
    float4 v1 = p1 ? l4[(size_t)c1*16 + fq] : make_float4(0.f,0.f,0.f,0.f);
    float4 v2 = p2 ? l4[(size_t)c2*16 + fq] : make_float4(0.f,0.f,0.f,0.f);
    float4 v3 = p3 ? l4[(size_t)c3*16 + fq] : make_float4(0.f,0.f,0.f,0.f);
    j += 4;
    bool q0 = j < end, q1 = j+1 < end, q2 = j+2 < end, q3 = j+3 < end;
    int n0 = q0 ? col[j]   : 0;
    int n1 = q1 ? col[j+1] : 0;
    int n2 = q2 ? col[j+2] : 0;
    int n3 = q3 ? col[j+3] : 0;
    acc.x += v0.x + v1.x + v2.x + v3.x;
    acc.y += v0.y + v1.y + v2.y + v3.y;
    acc.z += v0.z + v1.z + v2.z + v3.z;
    acc.w += v0.w + v1.w + v2.w + v3.w;
    p0=q0; p1=q1; p2=q2; p3=q3; c0=n0; c1=n1; c2=n2; c3=n3;
  }
  float inv = 1.0f / ds[dsidx];
  float4 r;
  r.x = acc.x * inv; r.y = acc.y * inv; r.z = acc.z * inv; r.w = acc.w * inv;
  if (DROP){
    unsigned base_i = (unsigned)node*64u + (unsigned)fq*4u;
    r.x = dropout_val(r.x, base_i + 0);
    r.y = dropout_val(r.y, base_i + 1);
    r.z = dropout_val(r.z, base_i + 2);
    r.w = dropout_val(r.w, base_i + 3);
  }
  *(float4*)(out + (size_t)node*64 + fq*4) = r;
}

// ---------------- CSR gather final conv (D_out=2) ----------------
__global__ void k_gather2(const int* __restrict__ rowptr, const int* __restrict__ col,
                          const float* __restrict__ h2, const float* __restrict__ dinv,
                          const float* __restrict__ b, float* __restrict__ out){
  int d = blockIdx.x*256 + threadIdx.x;
  if (d >= NN) return;
  int beg = rowptr[d], end = rowptr[d+1];
  float a0 = h2[(size_t)d*2];
  float a1 = h2[(size_t)d*2+1];
  for (int j = beg; j < end; ++j){
    int s = col[j];
    a0 += h2[(size_t)s*2];
    a1 += h2[(size_t)s*2+1];
  }
  float dv = dinv[d];
  out[(size_t)d*2]   = fmaf(a0, dv, b[0]);
  out[(size_t)d*2+1] = fmaf(a1, dv, b[1]);
}

// ---------------- standalone dropout (fallback path only) ----------------
__global__ void k_dropout(const float* __restrict__ last, float* __restrict__ xemb){
  unsigned i = blockIdx.x*256 + threadIdx.x;
  if (i >= NF) return;
  xemb[i] = dropout_val(last[i], i);
}

// ======== fallback (atomic scatter) kernels ========
__global__ void k_convinit(const float* __restrict__ h, const float* __restrict__ dinv,
                           const float* __restrict__ b, float* __restrict__ out){
  int i = blockIdx.x*256 + threadIdx.x;
  if (i >= NF) return;
  int v = i >> 6, c = i & 63;
  float dv = dinv[v];
  out[i] = h[i]*dv*dv + b[c];
}
__global__ void k_scatter64(const int* __restrict__ src, const int* __restrict__ dst, int ne,
                            const float* __restrict__ h, const float* __restrict__ dinv,
                            float* __restrict__ out){
  int lane = threadIdx.x & 63;
  int wid  = (blockIdx.x*256 + threadIdx.x) >> 6;
  int nw   = (gridDim.x*256) >> 6;
  for (int e = wid; e < ne; e += nw){
    int s = src[e], d = dst[e];
    float coef = dinv[s]*dinv[d];
    atomicAdd(&out[d*64 + lane], h[s*64 + lane]*coef);
  }
}
__global__ void k_layeragg(const int* __restrict__ recv, const int* __restrict__ srcn, int ne,
                           const float* __restrict__ last, float* __restrict__ acc){
  int lane = threadIdx.x & 63;
  int wid  = (blockIdx.x*256 + threadIdx.x) >> 6;
  int nw   = (gridDim.x*256) >> 6;
  for (int e = wid; e < ne; e += nw){
    int r = recv[e], s = srcn[e];
    atomicAdd(&acc[r*64 + lane], last[s*64 + lane]);
  }
}
__global__ void k_scale(const float* __restrict__ in, const float* __restrict__ ds, int dsidx,
                        float* __restrict__ out){
  int i = blockIdx.x*256 + threadIdx.x;
  if (i < NF) out[i] = in[i] / ds[dsidx];
}
__global__ void k_convinit2(const float* __restrict__ h2, const float* __restrict__ dinv,
                            const float* __restrict__ b, float* __restrict__ out){
  int i = blockIdx.x*256 + threadIdx.x;
  if (i >= NN*2) return;
  int v = i >> 1, c = i & 1;
  float dv = dinv[v];
  out[i] = h2[i]*dv*dv + b[c];
}
__global__ void k_scatter2(const int* __restrict__ src, const int* __restrict__ dst, int ne,
                           const float* __restrict__ h2, const float* __restrict__ dinv,
                           float* __restrict__ out){
  int e = blockIdx.x*256 + threadIdx.x;
  if (e >= ne) return;
  int s = src[e], d = dst[e];
  float coef = dinv[s]*dinv[d];
  atomicAdd(&out[d*2 + 0], h2[s*2 + 0]*coef);
  atomicAdd(&out[d*2 + 1], h2[s*2 + 1]*coef);
}

extern "C" void kernel_launch(void* const* d_in, const int* in_sizes, int n_in,
                              void* d_out, int out_size, void* d_ws, size_t ws_size,
                              hipStream_t stream) {
  const float* x    = (const float*)d_in[0];
  const int*   ei   = (const int*)  d_in[1];
  const int*   lei  = (const int*)  d_in[2];
  const float* degs = (const float*)d_in[3];
  const float* lW1  = (const float*)d_in[4];
  const float* lb1  = (const float*)d_in[5];
  const float* lW2  = (const float*)d_in[6];
  const float* lb2  = (const float*)d_in[7];
  const float* pW1  = (const float*)d_in[8];
  const float* pb1  = (const float*)d_in[9];
  const float* pW2  = (const float*)d_in[10];
  const float* pb2  = (const float*)d_in[11];
  float* out = (float*)d_out;

  const int gN  = (NN + 255)/256;
  const int gE  = (EE + 255)/256;
  const int gEL = (ELL + 255)/256;
  const int gNF = (NF + 255)/256;
  const int gG16 = (NN*16 + 255)/256;   // 16-lane-group gather grid

  const bool dual   = ws_size >= (size_t)WS_DUAL * 4;
  const bool single = ws_size >= (size_t)WS_SINGLE * 4;

  if (single) {
    float* base   = (float*)d_ws;
    float* dinv   = base;
    int*   cnt    = (int*)(base + OFF_CNT);
    int*   bsum   = (int*)(base + OFF_BSUM);      // 128 slots; [120] = barrier flag
    int*   flag   = bsum + 120;
    int*   rpA    = (int*)(base + OFF_RPA);
    int*   colA   = (int*)(base + OFF_COLA);
    int*   rpB    = dual ? (int*)(base + OFF_RPB)  : rpA;
    int*   colB   = dual ? (int*)(base + OFF_COLB) : colA;
    float* F0     = base + (dual ? OFF_COLB + 1000000 : OFF_RPB);
    float* F1     = F0 + NF;
    float* F2     = F1 + NF;

    // rank buffer aliases a provably-dead F buffer per build (consumed within the build)
    auto build_csr = [&](const int* srcp, const int* dstp, int ne, int gEdges, int computeDinv,
                         int* rowptr, int* col, int* rank){
      k_zerof<<<gN, 256, 0, stream>>>(cnt, NN, flag);
      k_degrank<<<gEdges, 256, 0, stream>>>(dstp, ne, cnt, rank);
      k_scanfused<<<NB_SCAN, 1024, 0, stream>>>(cnt, bsum, flag, rowptr, dinv, computeDinv, NN);
      k_fillr<<<gEdges, 256, 0, stream>>>(srcp, dstp, ne, rowptr, rank, col);
    };

    const int* s0 = ei;                  const int* d0 = s0 + EE;
    const int* s1 = ei + 2*(size_t)EE;   const int* d1 = s1 + EE;
    const int* s2 = ei + 4*(size_t)EE;   const int* d2 = s2 + EE;
    const int* r0 = lei;                 const int* ls0 = r0 + ELL;
    const int* r1 = lei + 2*(size_t)ELL; const int* ls1 = r1 + ELL;

    // ---- surface 0 ----  (F0 dead during build)
    build_csr(s0, d0, EE, gE, 1, rpA, colA, (int*)F0);
    k_gemm64<false,true><<<6250, 256, 0, stream>>>(x, lW1, dinv, NN, F0);
    k_gather64<<<gG16, 256, 0, stream>>>(rpA, colA, F0, dinv, lb1, F1);
    k_gemm64<true,true><<<6250, 256, 0, stream>>>(F1, lW2, dinv, NN, F0);
    k_gather64<<<gG16, 256, 0, stream>>>(rpA, colA, F0, dinv, lb2, F2);            // last = F2
    // ---- surface 1 ----  (F0 dead during both builds)
    build_csr(s1, d1, EE, gE, 1, rpA, colA, (int*)F0);
    k_gemm64<false,true><<<6250, 256, 0, stream>>>(x + (size_t)NF, lW1 + 4096, dinv, NN, F0);
    k_gather64<<<gG16, 256, 0, stream>>>(rpA, colA, F0, dinv, lb1 + 64, F1);
    k_gemm64<true,true><<<6250, 256, 0, stream>>>(F1, lW2 + 4096, dinv, NN, F0);
    k_gather64<<<gG16, 256, 0, stream>>>(rpA, colA, F0, dinv, lb2 + 64, F1);       // lf = F1
    build_csr(ls0, r0, ELL, gEL, 0, rpB, colB, (int*)F0);
    k_agggather<false><<<gG16, 256, 0, stream>>>(rpB, colB, F1, F2, degs, 0, F0);  // last = F0
    // ---- surface 2 ----  (F1 dead during both builds)
    build_csr(s2, d2, EE, gE, 1, rpA, colA, (int*)F1);
    k_gemm64<false,true><<<6250, 256, 0, stream>>>(x + 2*(size_t)NF, lW1 + 8192, dinv, NN, F1);
    k_gather64<<<gG16, 256, 0, stream>>>(rpA, colA, F1, dinv, lb1 + 128, F2);
    k_gemm64<true,true><<<6250, 256, 0, stream>>>(F2, lW2 + 8192, dinv, NN, F1);
    k_gather64<<<gG16, 256, 0, stream>>>(rpA, colA, F1, dinv, lb2 + 128, F2);      // lf = F2
    build_csr(ls1, r1, ELL, gEL, 0, rpB, colB, (int*)F1);
    k_agggather<true><<<gG16, 256, 0, stream>>>(rpB, colB, F2, F0, degs, 1, F1);   // F1 = x_emb (dropout fused)
    // ---- predictor (edge set 2) ----  (F0 dead during build)
    if (!dual) build_csr(s2, d2, EE, gE, 0, rpA, colA, (int*)F0);
    k_gemm64<false,true><<<6250, 256, 0, stream>>>(F1, pW1, dinv, NN, F0);
    k_gather64<<<gG16, 256, 0, stream>>>(rpA, colA, F0, dinv, pb1, F2);
    k_gemm2<true,true><<<gN, 256, 0, stream>>>(F2, pW2, dinv, NN, F1);
    k_gather2<<<gN, 256, 0, stream>>>(rpA, colA, F1, dinv, pb2, out);
    k_probe<<<1, 64, 0, stream>>>(ei, 0u, out);
    return;
  }

  // ================= fallback: verified atomic-scatter path =================
  float* base = (float*)d_ws;
  float* dinv = base;
  int*   cnt  = (int*)(base + 100352);
  float* A    = base + 262144;
  float* B    = A + NF;
  float* C    = B + NF;

  for (int i = 0; i < 3; ++i){
    const int* srcp = ei + (size_t)i*2*EE;
    const int* dstp = srcp + EE;
    k_zero_int<<<gN, 256, 0, stream>>>(cnt, NN);
    k_deg<<<gE, 256, 0, stream>>>(dstp, EE, cnt);
    k_dinv<<<gN, 256, 0, stream>>>(cnt, dinv, NN);
    k_gemm64<false,false><<<6250, 256, 0, stream>>>(x + (size_t)i*NF, lW1 + (size_t)i*64*64, dinv, NN, A);
    k_convinit<<<gNF, 256, 0, stream>>>(A, dinv, lb1 + (size_t)i*64, B);
    k_scatter64<<<8192, 256, 0, stream>>>(srcp, dstp, EE, A, dinv, B);
    k_gemm64<true,false><<<6250, 256, 0, stream>>>(B, lW2 + (size_t)i*64*64, dinv, NN, A);
    float* T = (i == 0) ? C : B;
    k_convinit<<<gNF, 256, 0, stream>>>(A, dinv, lb2 + (size_t)i*64, T);
    k_scatter64<<<8192, 256, 0, stream>>>(srcp, dstp, EE, A, dinv, T);
    if (i > 0){
      const int* recvp = lei + (size_t)(i-1)*2*ELL;
      const int* lsrcp = recvp + ELL;
      k_layeragg<<<4096, 256, 0, stream>>>(recvp, lsrcp, ELL, C, B);
      k_scale<<<gNF, 256, 0, stream>>>(B, degs, i-1, C);
    }
  }
  k_dropout<<<gNF, 256, 0, stream>>>(C, B);
  const int* srcp = ei + (size_t)2*2*EE;
  const int* dstp = srcp + EE;
  k_gemm64<false,false><<<6250, 256, 0, stream>>>(B, pW1, dinv, NN, A);
  k_convinit<<<gNF, 256, 0, stream>>>(A, dinv, pb1, C);
  k_scatter64<<<8192, 256, 0, stream>>>(srcp, dstp, EE, A, dinv, C);
  k_gemm2<true,false><<<gN, 256, 0, stream>>>(C, pW2, dinv, NN, B);
  k_convinit2<<<(NN*2 + 255)/256, 256, 0, stream>>>(B, dinv, pb2, out);
  k_scatter2<<<gE, 256, 0, stream>>>(srcp, dstp, EE, B, dinv, out);
  k_probe<<<1, 64, 0, stream>>>(ei, 0u, out);
}

// Round 15
// 744.909 us; speedup vs baseline: 1.4485x; 1.0990x over previous
//
#include <hip/hip_runtime.h>

#define NN 100000
#define EE 1000000
#define ELL 500000
#define NF (NN*64)
#define NB_SCAN ((NN + 1023) / 1024)   // 98

// ws layouts (floats)
#define OFF_CNT    100352
#define OFF_BSUM   200704
#define OFF_RPA    200832
#define OFF_COLA   301184
#define OFF_RPB    1301184
#define OFF_COLB   1401536
#define WS_SINGLE  (1301184 + 3*NF)              // 82.0 MB
#define WS_DUAL    (2401536 + 3*NF)              // 86.4 MB

// ---------------- Threefry-2x32 ----------------
__device__ __forceinline__ void threefry2x32(unsigned k0, unsigned k1, unsigned &x0, unsigned &x1){
  unsigned ks2 = k0 ^ k1 ^ 0x1BD11BDAu;
#define TF_R(R) { x0 += x1; x1 = (x1<<(R))|(x1>>(32-(R))); x1 ^= x0; }
  x0 += k0; x1 += k1;
  TF_R(13) TF_R(15) TF_R(26) TF_R(6)
  x0 += k1;  x1 += ks2 + 1u;
  TF_R(17) TF_R(29) TF_R(16) TF_R(24)
  x0 += ks2; x1 += k0 + 2u;
  TF_R(13) TF_R(15) TF_R(26) TF_R(6)
  x0 += k0;  x1 += k1 + 3u;
  TF_R(17) TF_R(29) TF_R(16) TF_R(24)
  x0 += k1;  x1 += ks2 + 4u;
  TF_R(13) TF_R(15) TF_R(26) TF_R(6)
  x0 += ks2; x1 += k0 + 5u;
#undef TF_R
}

__device__ __forceinline__ float dropout_val(float v, unsigned i){
  unsigned x0 = 0u, x1 = i;
  threefry2x32(0u, 42u, x0, x1);
  unsigned bits = x0 ^ x1;
  float u = __uint_as_float((bits >> 9) | 0x3f800000u) - 1.0f;
  return (u < 0.6f) ? v * (1.0f/0.6f) : 0.0f;
}

__global__ void k_probe(const int* __restrict__ ei, unsigned hostbits, float* __restrict__ out){
  if (threadIdx.x != 0 || blockIdx.x != 0) return;
  unsigned bits = hostbits;
  { unsigned a=0u, b=0u; threefry2x32(0u, 0u, a, b);
    if (a != 0x6b200159u || b != 0x99ba4efeu) bits |= 1u; }
  if (bits) out[0] = 1.0e4f * (float)bits;
}

// ---------------- utility ----------------
__global__ void k_zero_int(int* __restrict__ p, int n){
  int i = blockIdx.x*256 + threadIdx.x;
  if (i < n) p[i] = 0;
}

__global__ void k_zerof(int* __restrict__ cnt, int n, int* __restrict__ flag){
  int i = blockIdx.x*256 + threadIdx.x;
  if (i < n) cnt[i] = 0;
  if (i == 0) *flag = 0;
}

__global__ void k_deg(const int* __restrict__ dst, int ne, int* __restrict__ cnt){
  int i = blockIdx.x*256 + threadIdx.x;
  if (i < ne) atomicAdd(&cnt[dst[i]], 1);
}

__global__ void k_degrank(const int* __restrict__ dst, int ne, int* __restrict__ cnt,
                          int* __restrict__ rank){
  int i = blockIdx.x*256 + threadIdx.x;
  if (i >= ne) return;
  rank[i] = atomicAdd(&cnt[dst[i]], 1);
}

__global__ void k_dinv(const int* __restrict__ cnt, float* __restrict__ dinv, int n){
  int i = blockIdx.x*256 + threadIdx.x;
  if (i < n) dinv[i] = 1.0f / sqrtf((float)(cnt[i] + 1));
}

// ---------------- fused single-launch scan (98 blocks, device spin barrier) + dinv ----------------
__global__ __launch_bounds__(1024) void k_scanfused(const int* __restrict__ cnt, int* __restrict__ bsum,
                                                    int* __restrict__ flag, int* __restrict__ rowptr,
                                                    float* __restrict__ dinv, int computeDinv, int n){
  __shared__ int lds[1024];
  __shared__ int ps[128];
  int t = threadIdx.x;
  int i = blockIdx.x*1024 + t;
  int v = (i < n) ? cnt[i] : 0;
  if (computeDinv && i < n) dinv[i] = 1.0f / sqrtf((float)(v + 1));
  lds[t] = v;
  __syncthreads();
  for (int off = 1; off < 1024; off <<= 1){
    int x = (t >= off) ? lds[t - off] : 0;
    __syncthreads();
    lds[t] += x;
    __syncthreads();
  }
  int incl = lds[t];
  if (t == 1023){
    bsum[blockIdx.x] = lds[1023];
    __threadfence();
    atomicAdd(flag, 1);
  }
  if (t == 0){
    while (atomicAdd(flag, 0) < NB_SCAN) { }
  }
  __syncthreads();
  if (t < 128) ps[t] = (t < blockIdx.x) ? bsum[t] : 0;
  __syncthreads();
  if (t < 64) ps[t] += ps[t + 64];
  __syncthreads();
  if (t < 32) ps[t] += ps[t + 32];
  __syncthreads();
  if (t < 16) ps[t] += ps[t + 16];
  __syncthreads();
  if (t < 8)  ps[t] += ps[t + 8];
  __syncthreads();
  if (t < 4)  ps[t] += ps[t + 4];
  __syncthreads();
  if (t < 2)  ps[t] += ps[t + 2];
  __syncthreads();
  if (t < 1)  ps[t] += ps[t + 1];
  __syncthreads();
  int excl = incl - v + ps[0];
  if (i < n)  rowptr[i] = excl;
  if (i == n-1) rowptr[n] = excl + v;
}

// ---------------- CSR fill, atomic-free; also re-zeroes cnt+flag for the NEXT build ----------------
__global__ void k_fillrz(const int* __restrict__ src, const int* __restrict__ dst, int ne,
                         const int* __restrict__ rowptr, const int* __restrict__ rank,
                         int* __restrict__ col, int* __restrict__ cnt, int* __restrict__ flag){
  int e = blockIdx.x*256 + threadIdx.x;
  if (e < NN) cnt[e] = 0;
  if (e == 0) *flag = 0;
  if (e >= ne) return;
  col[rowptr[dst[e]] + rank[e]] = src[e];
}

// plain fill (single tier)
__global__ void k_fillr(const int* __restrict__ src, const int* __restrict__ dst, int ne,
                        const int* __restrict__ rowptr, const int* __restrict__ rank,
                        int* __restrict__ col){
  int e = blockIdx.x*256 + threadIdx.x;
  if (e >= ne) return;
  col[rowptr[dst[e]] + rank[e]] = src[e];
}

// ---------------- GEMM [nrows,64] @ [64,64]; RELU on input; SCALE: Y[row] *= dinv[row] ----------------
template<bool RELU, bool SCALE>
__global__ __launch_bounds__(256) void k_gemm64(const float* __restrict__ X, const float* __restrict__ W,
                                                const float* __restrict__ dinv,
                                                int nrows, float* __restrict__ Y){
  __shared__ float Ws[64][64];
  int t = threadIdx.x;
  {
    const float4* W4 = (const float4*)W;
    float4* S4 = (float4*)&Ws[0][0];
    #pragma unroll
    for (int i = 0; i < 4; ++i) S4[t + 256*i] = W4[t + 256*i];
  }
  __syncthreads();
  int row = blockIdx.x*16 + (t>>4);
  if (row >= nrows) return;
  int c0 = (t & 15) * 4;
  const float4* Xr = (const float4*)(X + (size_t)row*64);
  float4 acc = make_float4(0.f,0.f,0.f,0.f);
  #pragma unroll
  for (int kk = 0; kk < 16; ++kk){
    float4 xv = Xr[kk];
    if (RELU){
      xv.x = fmaxf(xv.x, 0.f); xv.y = fmaxf(xv.y, 0.f);
      xv.z = fmaxf(xv.z, 0.f); xv.w = fmaxf(xv.w, 0.f);
    }
    int k = kk*4;
    float4 w0 = *(const float4*)&Ws[k+0][c0];
    float4 w1 = *(const float4*)&Ws[k+1][c0];
    float4 w2 = *(const float4*)&Ws[k+2][c0];
    float4 w3 = *(const float4*)&Ws[k+3][c0];
    acc.x = fmaf(xv.x, w0.x, acc.x); acc.y = fmaf(xv.x, w0.y, acc.y);
    acc.z = fmaf(xv.x, w0.z, acc.z); acc.w = fmaf(xv.x, w0.w, acc.w);
    acc.x = fmaf(xv.y, w1.x, acc.x); acc.y = fmaf(xv.y, w1.y, acc.y);
    acc.z = fmaf(xv.y, w1.z, acc.z); acc.w = fmaf(xv.y, w1.w, acc.w);
    acc.x = fmaf(xv.z, w2.x, acc.x); acc.y = fmaf(xv.z, w2.y, acc.y);
    acc.z = fmaf(xv.z, w2.z, acc.z); acc.w = fmaf(xv.z, w2.w, acc.w);
    acc.x = fmaf(xv.w, w3.x, acc.x); acc.y = fmaf(xv.w, w3.y, acc.y);
    acc.z = fmaf(xv.w, w3.z, acc.z); acc.w = fmaf(xv.w, w3.w, acc.w);
  }
  if (SCALE){
    float dv = dinv[row];
    acc.x *= dv; acc.y *= dv; acc.z *= dv; acc.w *= dv;
  }
  *(float4*)(Y + (size_t)row*64 + c0) = acc;
}

// ---------------- GEMM [nrows,64] @ [64,2] ----------------
template<bool RELU, bool SCALE>
__global__ __launch_bounds__(256) void k_gemm2(const float* __restrict__ X, const float* __restrict__ W,
                                               const float* __restrict__ dinv,
                                               int nrows, float* __restrict__ Y){
  __shared__ float Ws[128];
  int t = threadIdx.x;
  if (t < 128) Ws[t] = W[t];
  __syncthreads();
  int row = blockIdx.x*256 + t;
  if (row >= nrows) return;
  const float4* Xr = (const float4*)(X + (size_t)row*64);
  float a0 = 0.f, a1 = 0.f;
  #pragma unroll
  for (int kk = 0; kk < 16; ++kk){
    float4 xv = Xr[kk];
    if (RELU){ xv.x=fmaxf(xv.x,0.f); xv.y=fmaxf(xv.y,0.f); xv.z=fmaxf(xv.z,0.f); xv.w=fmaxf(xv.w,0.f); }
    int k = kk*4;
    a0 = fmaf(xv.x, Ws[2*k+0], a0); a1 = fmaf(xv.x, Ws[2*k+1], a1);
    a0 = fmaf(xv.y, Ws[2*k+2], a0); a1 = fmaf(xv.y, Ws[2*k+3], a1);
    a0 = fmaf(xv.z, Ws[2*k+4], a0); a1 = fmaf(xv.z, Ws[2*k+5], a1);
    a0 = fmaf(xv.w, Ws[2*k+6], a0); a1 = fmaf(xv.w, Ws[2*k+7], a1);
  }
  if (SCALE){ float dv = dinv[row]; a0 *= dv; a1 *= dv; }
  Y[(size_t)row*2]   = a0;
  Y[(size_t)row*2+1] = a1;
}

// ---------------- shared 4-deep pipelined row-gather helper ----------------
__device__ __forceinline__ float4 gather_rows4(const int* __restrict__ col, int beg, int end,
                                               const float4* __restrict__ h4, int fq, float4 acc){
  int j = beg;
  bool p0 = j   < end; int c0 = p0 ? col[j]   : 0;
  bool p1 = j+1 < end; int c1 = p1 ? col[j+1] : 0;
  bool p2 = j+2 < end; int c2 = p2 ? col[j+2] : 0;
  bool p3 = j+3 < end; int c3 = p3 ? col[j+3] : 0;
  while (p0){
    float4 v0 = h4[(size_t)c0*16 + fq];
    float4 v1 = p1 ? h4[(size_t)c1*16 + fq] : make_float4(0.f,0.f,0.f,0.f);
    float4 v2 = p2 ? h4[(size_t)c2*16 + fq] : make_float4(0.f,0.f,0.f,0.f);
    float4 v3 = p3 ? h4[(size_t)c3*16 + fq] : make_float4(0.f,0.f,0.f,0.f);
    j += 4;
    bool q0 = j < end, q1 = j+1 < end, q2 = j+2 < end, q3 = j+3 < end;
    int n0 = q0 ? col[j]   : 0;
    int n1 = q1 ? col[j+1] : 0;
    int n2 = q2 ? col[j+2] : 0;
    int n3 = q3 ? col[j+3] : 0;
    acc.x += v0.x + v1.x + v2.x + v3.x;
    acc.y += v0.y + v1.y + v2.y + v3.y;
    acc.z += v0.z + v1.z + v2.z + v3.z;
    acc.w += v0.w + v1.w + v2.w + v3.w;
    p0=q0; p1=q1; p2=q2; p3=q3; c0=n0; c1=n1; c2=n2; c3=n3;
  }
  return acc;
}

// ---------------- CSR gather conv (standalone) ----------------
__global__ __launch_bounds__(256) void k_gather64(const int* __restrict__ rowptr, const int* __restrict__ col,
                                                  const float* __restrict__ h, const float* __restrict__ dinv,
                                                  const float* __restrict__ b, float* __restrict__ out){
  int gt = blockIdx.x*256 + threadIdx.x;
  int fq = gt & 15;
  int node = gt >> 4;
  if (node >= NN) return;
  const float4* __restrict__ h4 = (const float4*)h;
  float4 acc = h4[(size_t)node*16 + fq];
  acc = gather_rows4(col, rowptr[node], rowptr[node+1], h4, fq, acc);
  float dv = dinv[node];
  float4 bb = ((const float4*)b)[fq];
  float4 r;
  r.x = fmaf(acc.x, dv, bb.x); r.y = fmaf(acc.y, dv, bb.y);
  r.z = fmaf(acc.z, dv, bb.z); r.w = fmaf(acc.w, dv, bb.w);
  *(float4*)(out + (size_t)node*64 + fq*4) = r;
}

// ---------------- FUSED: gather conv1 + ReLU + @W2 + scale-by-dinv ----------------
// out_row = relu(gatherA(h1')·dv + b1) @ W2 · dv   (h1' pre-scaled by dinv)
__global__ __launch_bounds__(256) void k_gathergemm(const int* __restrict__ rowptr, const int* __restrict__ col,
                                                    const float* __restrict__ h, const float* __restrict__ dinv,
                                                    const float* __restrict__ b1, const float* __restrict__ W2,
                                                    float* __restrict__ Y){
  __shared__ float Ws[64][64];
  __shared__ float rows[16][68];
  int t = threadIdx.x;
  {
    const float4* W4 = (const float4*)W2;
    float4* S4 = (float4*)&Ws[0][0];
    #pragma unroll
    for (int i = 0; i < 4; ++i) S4[t + 256*i] = W4[t + 256*i];
  }
  __syncthreads();
  int fq = t & 15, grp = t >> 4;
  int node = blockIdx.x*16 + grp;
  bool alive = node < NN;
  float dv = 0.f;
  if (alive){
    const float4* __restrict__ h4 = (const float4*)h;
    float4 acc = h4[(size_t)node*16 + fq];
    acc = gather_rows4(col, rowptr[node], rowptr[node+1], h4, fq, acc);
    dv = dinv[node];
    float4 bb = ((const float4*)b1)[fq];
    float4 r;
    r.x = fmaxf(fmaf(acc.x, dv, bb.x), 0.f);
    r.y = fmaxf(fmaf(acc.y, dv, bb.y), 0.f);
    r.z = fmaxf(fmaf(acc.z, dv, bb.z), 0.f);
    r.w = fmaxf(fmaf(acc.w, dv, bb.w), 0.f);
    *(float4*)&rows[grp][fq*4] = r;
  }
  __syncthreads();
  if (alive){
    const float* __restrict__ row = &rows[grp][0];
    float4 o = make_float4(0.f,0.f,0.f,0.f);
    int c0 = fq*4;
    #pragma unroll 8
    for (int k = 0; k < 64; ++k){
      float rv = row[k];
      float4 w = *(const float4*)&Ws[k][c0];
      o.x = fmaf(rv, w.x, o.x); o.y = fmaf(rv, w.y, o.y);
      o.z = fmaf(rv, w.z, o.z); o.w = fmaf(rv, w.w, o.w);
    }
    o.x *= dv; o.y *= dv; o.z *= dv; o.w *= dv;
    *(float4*)(Y + (size_t)node*64 + fq*4) = o;
  }
}

// ---------------- FUSED: lf-gather (CSR-A) + cross-layer agg (CSR-B) + scale (+dropout) ----------------
template<bool DROP>
__global__ __launch_bounds__(256) void k_gatherlfagg(const int* __restrict__ rpA, const int* __restrict__ colA,
                                                     const float* __restrict__ h, const float* __restrict__ dinv,
                                                     const float* __restrict__ b,
                                                     const int* __restrict__ rpB, const int* __restrict__ colB,
                                                     const float* __restrict__ last,
                                                     const float* __restrict__ ds, int dsidx,
                                                     float* __restrict__ out){
  int gt = blockIdx.x*256 + threadIdx.x;
  int fq = gt & 15;
  int node = gt >> 4;
  if (node >= NN) return;
  const float4* __restrict__ h4 = (const float4*)h;
  float4 acc = h4[(size_t)node*16 + fq];
  acc = gather_rows4(colA, rpA[node], rpA[node+1], h4, fq, acc);
  float dv = dinv[node];
  float4 bb = ((const float4*)b)[fq];
  float4 lf;
  lf.x = fmaf(acc.x, dv, bb.x); lf.y = fmaf(acc.y, dv, bb.y);
  lf.z = fmaf(acc.z, dv, bb.z); lf.w = fmaf(acc.w, dv, bb.w);
  float4 agg = gather_rows4(colB, rpB[node], rpB[node+1], (const float4*)last, fq,
                            make_float4(0.f,0.f,0.f,0.f));
  float inv = 1.0f / ds[dsidx];
  float4 r;
  r.x = (lf.x + agg.x) * inv; r.y = (lf.y + agg.y) * inv;
  r.z = (lf.z + agg.z) * inv; r.w = (lf.w + agg.w) * inv;
  if (DROP){
    unsigned base_i = (unsigned)node*64u + (unsigned)fq*4u;
    r.x = dropout_val(r.x, base_i + 0);
    r.y = dropout_val(r.y, base_i + 1);
    r.z = dropout_val(r.z, base_i + 2);
    r.w = dropout_val(r.w, base_i + 3);
  }
  *(float4*)(out + (size_t)node*64 + fq*4) = r;
}

// ---------------- CSR gather cross-layer agg (single tier) ----------------
template<bool DROP>
__global__ __launch_bounds__(256) void k_agggather(const int* __restrict__ rowptr, const int* __restrict__ col,
                                                    const float* __restrict__ lf, const float* __restrict__ last,
                                                    const float* __restrict__ ds, int dsidx, float* __restrict__ out){
  int gt = blockIdx.x*256 + threadIdx.x;
  int fq = gt & 15;
  int node = gt >> 4;
  if (node >= NN) return;
  float4 acc = ((const float4*)lf)[(size_t)node*16 + fq];
  acc = gather_rows4(col, rowptr[node], rowptr[node+1], (const float4*)last, fq, acc);
  float inv = 1.0f / ds[dsidx];
  float4 r;
  r.x = acc.x * inv; r.y = acc.y * inv; r.z = acc.z * inv; r.w = acc.w * inv;
  if (DROP){
    unsigned base_i = (unsigned)node*64u + (unsigned)fq*4u;
    r.x = dropout_val(r.x, base_i + 0);
    r.y = dropout_val(r.y, base_i + 1);
    r.z = dropout_val(r.z, base_i + 2);
    r.w = dropout_val(r.w, base_i + 3);
  }
  *(float4*)(out + (size_t)node*64 + fq*4) = r;
}

// ---------------- CSR gather final conv (D_out=2) ----------------
__global__ void k_gather2(const int* __restrict__ rowptr, const int* __restrict__ col,
                          const float* __restrict__ h2, const float* __restrict__ dinv,
                          const float* __restrict__ b, float* __restrict__ out){
  int d = blockIdx.x*256 + threadIdx.x;
  if (d >= NN) return;
  int beg = rowptr[d], end = rowptr[d+1];
  float a0 = h2[(size_t)d*2];
  float a1 = h2[(size_t)d*2+1];
  for (int j = beg; j < end; ++j){
    int s = col[j];
    a0 += h2[(size_t)s*2];
    a1 += h2[(size_t)s*2+1];
  }
  float dv = dinv[d];
  out[(size_t)d*2]   = fmaf(a0, dv, b[0]);
  out[(size_t)d*2+1] = fmaf(a1, dv, b[1]);
}

// ---------------- standalone dropout (fallback path only) ----------------
__global__ void k_dropout(const float* __restrict__ last, float* __restrict__ xemb){
  unsigned i = blockIdx.x*256 + threadIdx.x;
  if (i >= NF) return;
  xemb[i] = dropout_val(last[i], i);
}

// ======== fallback (atomic scatter) kernels ========
__global__ void k_convinit(const float* __restrict__ h, const float* __restrict__ dinv,
                           const float* __restrict__ b, float* __restrict__ out){
  int i = blockIdx.x*256 + threadIdx.x;
  if (i >= NF) return;
  int v = i >> 6, c = i & 63;
  float dv = dinv[v];
  out[i] = h[i]*dv*dv + b[c];
}
__global__ void k_scatter64(const int* __restrict__ src, const int* __restrict__ dst, int ne,
                            const float* __restrict__ h, const float* __restrict__ dinv,
                            float* __restrict__ out){
  int lane = threadIdx.x & 63;
  int wid  = (blockIdx.x*256 + threadIdx.x) >> 6;
  int nw   = (gridDim.x*256) >> 6;
  for (int e = wid; e < ne; e += nw){
    int s = src[e], d = dst[e];
    float coef = dinv[s]*dinv[d];
    atomicAdd(&out[d*64 + lane], h[s*64 + lane]*coef);
  }
}
__global__ void k_layeragg(const int* __restrict__ recv, const int* __restrict__ srcn, int ne,
                           const float* __restrict__ last, float* __restrict__ acc){
  int lane = threadIdx.x & 63;
  int wid  = (blockIdx.x*256 + threadIdx.x) >> 6;
  int nw   = (gridDim.x*256) >> 6;
  for (int e = wid; e < ne; e += nw){
    int r = recv[e], s = srcn[e];
    atomicAdd(&acc[r*64 + lane], last[s*64 + lane]);
  }
}
__global__ void k_scale(const float* __restrict__ in, const float* __restrict__ ds, int dsidx,
                        float* __restrict__ out){
  int i = blockIdx.x*256 + threadIdx.x;
  if (i < NF) out[i] = in[i] / ds[dsidx];
}
__global__ void k_convinit2(const float* __restrict__ h2, const float* __restrict__ dinv,
                            const float* __restrict__ b, float* __restrict__ out){
  int i = blockIdx.x*256 + threadIdx.x;
  if (i >= NN*2) return;
  int v = i >> 1, c = i & 1;
  float dv = dinv[v];
  out[i] = h2[i]*dv*dv + b[c];
}
__global__ void k_scatter2(const int* __restrict__ src, const int* __restrict__ dst, int ne,
                           const float* __restrict__ h2, const float* __restrict__ dinv,
                           float* __restrict__ out){
  int e = blockIdx.x*256 + threadIdx.x;
  if (e >= ne) return;
  int s = src[e], d = dst[e];
  float coef = dinv[s]*dinv[d];
  atomicAdd(&out[d*2 + 0], h2[s*2 + 0]*coef);
  atomicAdd(&out[d*2 + 1], h2[s*2 + 1]*coef);
}

extern "C" void kernel_launch(void* const* d_in, const int* in_sizes, int n_in,
                              void* d_out, int out_size, void* d_ws, size_t ws_size,
                              hipStream_t stream) {
  const float* x    = (const float*)d_in[0];
  const int*   ei   = (const int*)  d_in[1];
  const int*   lei  = (const int*)  d_in[2];
  const float* degs = (const float*)d_in[3];
  const float* lW1  = (const float*)d_in[4];
  const float* lb1  = (const float*)d_in[5];
  const float* lW2  = (const float*)d_in[6];
  const float* lb2  = (const float*)d_in[7];
  const float* pW1  = (const float*)d_in[8];
  const float* pb1  = (const float*)d_in[9];
  const float* pW2  = (const float*)d_in[10];
  const float* pb2  = (const float*)d_in[11];
  float* out = (float*)d_out;

  const int gN  = (NN + 255)/256;
  const int gE  = (EE + 255)/256;
  const int gEL = (ELL + 255)/256;
  const int gNF = (NF + 255)/256;
  const int gG16 = (NN*16 + 255)/256;   // 6250

  const bool dual   = ws_size >= (size_t)WS_DUAL * 4;
  const bool single = ws_size >= (size_t)WS_SINGLE * 4;

  if (dual) {
    float* base   = (float*)d_ws;
    float* dinv   = base;
    int*   cnt    = (int*)(base + OFF_CNT);
    int*   bsum   = (int*)(base + OFF_BSUM);
    int*   flag   = bsum + 120;
    int*   rpA    = (int*)(base + OFF_RPA);
    int*   colA   = (int*)(base + OFF_COLA);
    int*   rpB    = (int*)(base + OFF_RPB);
    int*   colB   = (int*)(base + OFF_COLB);
    float* F0     = base + OFF_COLB + 1000000;
    float* F1     = F0 + NF;
    float* F2     = F1 + NF;

    auto build_csr = [&](const int* srcp, const int* dstp, int ne, int gEdges, int computeDinv,
                         int* rowptr, int* col, int* rank){
      k_degrank<<<gEdges, 256, 0, stream>>>(dstp, ne, cnt, rank);
      k_scanfused<<<NB_SCAN, 1024, 0, stream>>>(cnt, bsum, flag, rowptr, dinv, computeDinv, NN);
      k_fillrz<<<gEdges, 256, 0, stream>>>(srcp, dstp, ne, rowptr, rank, col, cnt, flag);
    };

    const int* s0 = ei;                  const int* d0 = s0 + EE;
    const int* s1 = ei + 2*(size_t)EE;   const int* d1 = s1 + EE;
    const int* s2 = ei + 4*(size_t)EE;   const int* d2 = s2 + EE;
    const int* r0 = lei;                 const int* ls0 = r0 + ELL;
    const int* r1 = lei + 2*(size_t)ELL; const int* ls1 = r1 + ELL;

    k_zerof<<<gN, 256, 0, stream>>>(cnt, NN, flag);

    // ---- surface 0 ----  (rank scratch in F0: dead)
    build_csr(s0, d0, EE, gE, 1, rpA, colA, (int*)F0);
    k_gemm64<false,true><<<6250, 256, 0, stream>>>(x, lW1, dinv, NN, F0);
    k_gathergemm<<<6250, 256, 0, stream>>>(rpA, colA, F0, dinv, lb1, lW2, F1);       // F1 = h2'
    k_gather64<<<gG16, 256, 0, stream>>>(rpA, colA, F1, dinv, lb2, F2);              // last = F2
    // ---- surface 1 ----  (rank in F0: dead after gathergemm consumed it... F0 consumed by S0 gathergemm)
    build_csr(s1, d1, EE, gE, 1, rpA, colA, (int*)F0);
    build_csr(ls0, r0, ELL, gEL, 0, rpB, colB, (int*)F0);
    k_gemm64<false,true><<<6250, 256, 0, stream>>>(x + (size_t)NF, lW1 + 4096, dinv, NN, F0);
    k_gathergemm<<<6250, 256, 0, stream>>>(rpA, colA, F0, dinv, lb1 + 64, lW2 + 4096, F1);  // F1 = h2'
    k_gatherlfagg<false><<<gG16, 256, 0, stream>>>(rpA, colA, F1, dinv, lb2 + 64,
                                                   rpB, colB, F2, degs, 0, F0);      // last = F0
    // ---- surface 2 ----  (rank in F1: dead — S1's h2' consumed by gatherlfagg)
    build_csr(s2, d2, EE, gE, 1, rpA, colA, (int*)F1);
    build_csr(ls1, r1, ELL, gEL, 0, rpB, colB, (int*)F1);
    k_gemm64<false,true><<<6250, 256, 0, stream>>>(x + 2*(size_t)NF, lW1 + 8192, dinv, NN, F1);
    k_gathergemm<<<6250, 256, 0, stream>>>(rpA, colA, F1, dinv, lb1 + 128, lW2 + 8192, F2); // F2 = h2'
    k_gatherlfagg<true><<<gG16, 256, 0, stream>>>(rpA, colA, F2, dinv, lb2 + 128,
                                                  rpB, colB, F0, degs, 1, F1);       // F1 = x_emb
    // ---- predictor (CSR-A still = surface-2 edges; dinv = surface-2 degrees) ----
    k_gemm64<false,true><<<6250, 256, 0, stream>>>(F1, pW1, dinv, NN, F0);
    k_gather64<<<gG16, 256, 0, stream>>>(rpA, colA, F0, dinv, pb1, F2);
    k_gemm2<true,true><<<gN, 256, 0, stream>>>(F2, pW2, dinv, NN, F1);
    k_gather2<<<gN, 256, 0, stream>>>(rpA, colA, F1, dinv, pb2, out);
    k_probe<<<1, 64, 0, stream>>>(ei, 0u, out);
    return;
  }

  if (single) {
    // ======= R14-proven single-slot path =======
    float* base   = (float*)d_ws;
    float* dinv   = base;
    int*   cnt    = (int*)(base + OFF_CNT);
    int*   bsum   = (int*)(base + OFF_BSUM);
    int*   flag   = bsum + 120;
    int*   rpA    = (int*)(base + OFF_RPA);
    int*   colA   = (int*)(base + OFF_COLA);
    float* F0     = base + OFF_RPB;
    float* F1     = F0 + NF;
    float* F2     = F1 + NF;

    auto build_csr = [&](const int* srcp, const int* dstp, int ne, int gEdges, int computeDinv,
                         int* rowptr, int* col, int* rank){
      k_zerof<<<gN, 256, 0, stream>>>(cnt, NN, flag);
      k_degrank<<<gEdges, 256, 0, stream>>>(dstp, ne, cnt, rank);
      k_scanfused<<<NB_SCAN, 1024, 0, stream>>>(cnt, bsum, flag, rowptr, dinv, computeDinv, NN);
      k_fillr<<<gEdges, 256, 0, stream>>>(srcp, dstp, ne, rowptr, rank, col);
    };

    const int* s0 = ei;                  const int* d0 = s0 + EE;
    const int* s1 = ei + 2*(size_t)EE;   const int* d1 = s1 + EE;
    const int* s2 = ei + 4*(size_t)EE;   const int* d2 = s2 + EE;
    const int* r0 = lei;                 const int* ls0 = r0 + ELL;
    const int* r1 = lei + 2*(size_t)ELL; const int* ls1 = r1 + ELL;

    build_csr(s0, d0, EE, gE, 1, rpA, colA, (int*)F0);
    k_gemm64<false,true><<<6250, 256, 0, stream>>>(x, lW1, dinv, NN, F0);
    k_gather64<<<gG16, 256, 0, stream>>>(rpA, colA, F0, dinv, lb1, F1);
    k_gemm64<true,true><<<6250, 256, 0, stream>>>(F1, lW2, dinv, NN, F0);
    k_gather64<<<gG16, 256, 0, stream>>>(rpA, colA, F0, dinv, lb2, F2);
    build_csr(s1, d1, EE, gE, 1, rpA, colA, (int*)F0);
    k_gemm64<false,true><<<6250, 256, 0, stream>>>(x + (size_t)NF, lW1 + 4096, dinv, NN, F0);
    k_gather64<<<gG16, 256, 0, stream>>>(rpA, colA, F0, dinv, lb1 + 64, F1);
    k_gemm64<true,true><<<6250, 256, 0, stream>>>(F1, lW2 + 4096, dinv, NN, F0);
    k_gather64<<<gG16, 256, 0, stream>>>(rpA, colA, F0, dinv, lb2 + 64, F1);
    build_csr(ls0, r0, ELL, gEL, 0, rpA, colA, (int*)F0);
    k_agggather<false><<<gG16, 256, 0, stream>>>(rpA, colA, F1, F2, degs, 0, F0);
    build_csr(s2, d2, EE, gE, 1, rpA, colA, (int*)F1);
    k_gemm64<false,true><<<6250, 256, 0, stream>>>(x + 2*(size_t)NF, lW1 + 8192, dinv, NN, F1);
    k_gather64<<<gG16, 256, 0, stream>>>(rpA, colA, F1, dinv, lb1 + 128, F2);
    k_gemm64<true,true><<<6250, 256, 0, stream>>>(F2, lW2 + 8192, dinv, NN, F1);
    k_gather64<<<gG16, 256, 0, stream>>>(rpA, colA, F1, dinv, lb2 + 128, F2);
    build_csr(ls1, r1, ELL, gEL, 0, rpA, colA, (int*)F1);
    k_agggather<true><<<gG16, 256, 0, stream>>>(rpA, colA, F2, F0, degs, 1, F1);
    build_csr(s2, d2, EE, gE, 0, rpA, colA, (int*)F0);
    k_gemm64<false,true><<<6250, 256, 0, stream>>>(F1, pW1, dinv, NN, F0);
    k_gather64<<<gG16, 256, 0, stream>>>(rpA, colA, F0, dinv, pb1, F2);
    k_gemm2<true,true><<<gN, 256, 0, stream>>>(F2, pW2, dinv, NN, F1);
    k_gather2<<<gN, 256, 0, stream>>>(rpA, colA, F1, dinv, pb2, out);
    k_probe<<<1, 64, 0, stream>>>(ei, 0u, out);
    return;
  }

  // ================= fallback: verified atomic-scatter path =================
  float* base = (float*)d_ws;
  float* dinv = base;
  int*   cnt  = (int*)(base + 100352);
  float* A    = base + 262144;
  float* B    = A + NF;
  float* C    = B + NF;

  for (int i = 0; i < 3; ++i){
    const int* srcp = ei + (size_t)i*2*EE;
    const int* dstp = srcp + EE;
    k_zero_int<<<gN, 256, 0, stream>>>(cnt, NN);
    k_deg<<<gE, 256, 0, stream>>>(dstp, EE, cnt);
    k_dinv<<<gN, 256, 0, stream>>>(cnt, dinv, NN);
    k_gemm64<false,false><<<6250, 256, 0, stream>>>(x + (size_t)i*NF, lW1 + (size_t)i*64*64, dinv, NN, A);
    k_convinit<<<gNF, 256, 0, stream>>>(A, dinv, lb1 + (size_t)i*64, B);
    k_scatter64<<<8192, 256, 0, stream>>>(srcp, dstp, EE, A, dinv, B);
    k_gemm64<true,false><<<6250, 256, 0, stream>>>(B, lW2 + (size_t)i*64*64, dinv, NN, A);
    float* T = (i == 0) ? C : B;
    k_convinit<<<gNF, 256, 0, stream>>>(A, dinv, lb2 + (size_t)i*64, T);
    k_scatter64<<<8192, 256, 0, stream>>>(srcp, dstp, EE, A, dinv, T);
    if (i > 0){
      const int* recvp = lei + (size_t)(i-1)*2*ELL;
      const int* lsrcp = recvp + ELL;
      k_layeragg<<<4096, 256, 0, stream>>>(recvp, lsrcp, ELL, C, B);
      k_scale<<<gNF, 256, 0, stream>>>(B, degs, i-1, C);
    }
  }
  k_dropout<<<gNF, 256, 0, stream>>>(C, B);
  const int* srcp = ei + (size_t)2*2*EE;
  const int* dstp = srcp + EE;
  k_gemm64<false,false><<<6250, 256, 0, stream>>>(B, pW1, dinv, NN, A);
  k_convinit<<<gNF, 256, 0, stream>>>(A, dinv, pb1, C);
  k_scatter64<<<8192, 256, 0, stream>>>(srcp, dstp, EE, A, dinv, C);
  k_gemm2<true,false><<<gN, 256, 0, stream>>>(C, pW2, dinv, NN, B);
  k_convinit2<<<(NN*2 + 255)/256, 256, 0, stream>>>(B, dinv, pb2, out);
  k_scatter2<<<gE, 256, 0, stream>>>(srcp, dstp, EE, B, dinv, out);
  k_probe<<<1, 64, 0, stream>>>(ei, 0u, out);
}

// Round 16
// 645.736 us; speedup vs baseline: 1.6710x; 1.1536x over previous
//
#include <hip/hip_runtime.h>
#include <hip/hip_fp16.h>

#define NN 100000
#define EE 1000000
#define ELL 500000
#define NF (NN*64)
#define NB_SCAN ((NN + 1023) / 1024)   // 98

// ws layouts (floats)
#define OFF_CNT    100352
#define OFF_BSUM   200704
#define OFF_RPA    200832
#define OFF_COLA   301184
#define OFF_RPB    1301184
#define OFF_COLB   1401536
#define WS_SINGLE  (1301184 + 3*NF)              // 82.0 MB
#define WS_DUAL    (2401536 + 4*NF)              // dual + 2 fp16 tables (each NF/2 floats)

// ---------------- Threefry-2x32 ----------------
__device__ __forceinline__ void threefry2x32(unsigned k0, unsigned k1, unsigned &x0, unsigned &x1){
  unsigned ks2 = k0 ^ k1 ^ 0x1BD11BDAu;
#define TF_R(R) { x0 += x1; x1 = (x1<<(R))|(x1>>(32-(R))); x1 ^= x0; }
  x0 += k0; x1 += k1;
  TF_R(13) TF_R(15) TF_R(26) TF_R(6)
  x0 += k1;  x1 += ks2 + 1u;
  TF_R(17) TF_R(29) TF_R(16) TF_R(24)
  x0 += ks2; x1 += k0 + 2u;
  TF_R(13) TF_R(15) TF_R(26) TF_R(6)
  x0 += k0;  x1 += k1 + 3u;
  TF_R(17) TF_R(29) TF_R(16) TF_R(24)
  x0 += k1;  x1 += ks2 + 4u;
  TF_R(13) TF_R(15) TF_R(26) TF_R(6)
  x0 += ks2; x1 += k0 + 5u;
#undef TF_R
}

__device__ __forceinline__ float dropout_val(float v, unsigned i){
  unsigned x0 = 0u, x1 = i;
  threefry2x32(0u, 42u, x0, x1);
  unsigned bits = x0 ^ x1;
  float u = __uint_as_float((bits >> 9) | 0x3f800000u) - 1.0f;
  return (u < 0.6f) ? v * (1.0f/0.6f) : 0.0f;
}

__global__ void k_probe(const int* __restrict__ ei, unsigned hostbits, float* __restrict__ out){
  if (threadIdx.x != 0 || blockIdx.x != 0) return;
  unsigned bits = hostbits;
  { unsigned a=0u, b=0u; threefry2x32(0u, 0u, a, b);
    if (a != 0x6b200159u || b != 0x99ba4efeu) bits |= 1u; }
  if (bits) out[0] = 1.0e4f * (float)bits;
}

// ---------------- fp16 pack/unpack ----------------
__device__ __forceinline__ uint2 f4_to_h4(float4 v){
  __half2 lo = __floats2half2_rn(v.x, v.y);
  __half2 hi = __floats2half2_rn(v.z, v.w);
  uint2 r; r.x = *(unsigned*)&lo; r.y = *(unsigned*)&hi; return r;
}
__device__ __forceinline__ float4 h4_to_f4(uint2 u){
  __half2 lo = *(__half2*)&u.x;
  __half2 hi = *(__half2*)&u.y;
  float2 a = __half22float2(lo), b = __half22float2(hi);
  return make_float4(a.x, a.y, b.x, b.y);
}

// ---------------- utility ----------------
__global__ void k_zero_int(int* __restrict__ p, int n){
  int i = blockIdx.x*256 + threadIdx.x;
  if (i < n) p[i] = 0;
}

__global__ void k_zerof(int* __restrict__ cnt, int n, int* __restrict__ flag){
  int i = blockIdx.x*256 + threadIdx.x;
  if (i < n) cnt[i] = 0;
  if (i == 0) *flag = 0;
}

__global__ void k_deg(const int* __restrict__ dst, int ne, int* __restrict__ cnt){
  int i = blockIdx.x*256 + threadIdx.x;
  if (i < ne) atomicAdd(&cnt[dst[i]], 1);
}

__global__ void k_degrank(const int* __restrict__ dst, int ne, int* __restrict__ cnt,
                          int* __restrict__ rank){
  int i = blockIdx.x*256 + threadIdx.x;
  if (i >= ne) return;
  rank[i] = atomicAdd(&cnt[dst[i]], 1);
}

__global__ void k_dinv(const int* __restrict__ cnt, float* __restrict__ dinv, int n){
  int i = blockIdx.x*256 + threadIdx.x;
  if (i < n) dinv[i] = 1.0f / sqrtf((float)(cnt[i] + 1));
}

// ---------------- fused single-launch scan (98 blocks, device spin barrier) + dinv ----------------
__global__ __launch_bounds__(1024) void k_scanfused(const int* __restrict__ cnt, int* __restrict__ bsum,
                                                    int* __restrict__ flag, int* __restrict__ rowptr,
                                                    float* __restrict__ dinv, int computeDinv, int n){
  __shared__ int lds[1024];
  __shared__ int ps[128];
  int t = threadIdx.x;
  int i = blockIdx.x*1024 + t;
  int v = (i < n) ? cnt[i] : 0;
  if (computeDinv && i < n) dinv[i] = 1.0f / sqrtf((float)(v + 1));
  lds[t] = v;
  __syncthreads();
  for (int off = 1; off < 1024; off <<= 1){
    int x = (t >= off) ? lds[t - off] : 0;
    __syncthreads();
    lds[t] += x;
    __syncthreads();
  }
  int incl = lds[t];
  if (t == 1023){
    bsum[blockIdx.x] = lds[1023];
    __threadfence();
    atomicAdd(flag, 1);
  }
  if (t == 0){
    while (atomicAdd(flag, 0) < NB_SCAN) { }
  }
  __syncthreads();
  if (t < 128) ps[t] = (t < blockIdx.x) ? bsum[t] : 0;
  __syncthreads();
  if (t < 64) ps[t] += ps[t + 64];
  __syncthreads();
  if (t < 32) ps[t] += ps[t + 32];
  __syncthreads();
  if (t < 16) ps[t] += ps[t + 16];
  __syncthreads();
  if (t < 8)  ps[t] += ps[t + 8];
  __syncthreads();
  if (t < 4)  ps[t] += ps[t + 4];
  __syncthreads();
  if (t < 2)  ps[t] += ps[t + 2];
  __syncthreads();
  if (t < 1)  ps[t] += ps[t + 1];
  __syncthreads();
  int excl = incl - v + ps[0];
  if (i < n)  rowptr[i] = excl;
  if (i == n-1) rowptr[n] = excl + v;
}

// ---------------- CSR fill, atomic-free; also re-zeroes cnt+flag for the NEXT build ----------------
__global__ void k_fillrz(const int* __restrict__ src, const int* __restrict__ dst, int ne,
                         const int* __restrict__ rowptr, const int* __restrict__ rank,
                         int* __restrict__ col, int* __restrict__ cnt, int* __restrict__ flag){
  int e = blockIdx.x*256 + threadIdx.x;
  if (e < NN) cnt[e] = 0;
  if (e == 0) *flag = 0;
  if (e >= ne) return;
  col[rowptr[dst[e]] + rank[e]] = src[e];
}

__global__ void k_fillr(const int* __restrict__ src, const int* __restrict__ dst, int ne,
                        const int* __restrict__ rowptr, const int* __restrict__ rank,
                        int* __restrict__ col){
  int e = blockIdx.x*256 + threadIdx.x;
  if (e >= ne) return;
  col[rowptr[dst[e]] + rank[e]] = src[e];
}

// ---------------- GEMM [nrows,64] @ [64,64]; RELU on input; SCALE: row *= dinv[row]; f32 out ----------------
template<bool RELU, bool SCALE>
__global__ __launch_bounds__(256) void k_gemm64(const float* __restrict__ X, const float* __restrict__ W,
                                                const float* __restrict__ dinv,
                                                int nrows, float* __restrict__ Y){
  __shared__ float Ws[64][64];
  int t = threadIdx.x;
  {
    const float4* W4 = (const float4*)W;
    float4* S4 = (float4*)&Ws[0][0];
    #pragma unroll
    for (int i = 0; i < 4; ++i) S4[t + 256*i] = W4[t + 256*i];
  }
  __syncthreads();
  int row = blockIdx.x*16 + (t>>4);
  if (row >= nrows) return;
  int c0 = (t & 15) * 4;
  const float4* Xr = (const float4*)(X + (size_t)row*64);
  float4 acc = make_float4(0.f,0.f,0.f,0.f);
  #pragma unroll
  for (int kk = 0; kk < 16; ++kk){
    float4 xv = Xr[kk];
    if (RELU){
      xv.x = fmaxf(xv.x, 0.f); xv.y = fmaxf(xv.y, 0.f);
      xv.z = fmaxf(xv.z, 0.f); xv.w = fmaxf(xv.w, 0.f);
    }
    int k = kk*4;
    float4 w0 = *(const float4*)&Ws[k+0][c0];
    float4 w1 = *(const float4*)&Ws[k+1][c0];
    float4 w2 = *(const float4*)&Ws[k+2][c0];
    float4 w3 = *(const float4*)&Ws[k+3][c0];
    acc.x = fmaf(xv.x, w0.x, acc.x); acc.y = fmaf(xv.x, w0.y, acc.y);
    acc.z = fmaf(xv.x, w0.z, acc.z); acc.w = fmaf(xv.x, w0.w, acc.w);
    acc.x = fmaf(xv.y, w1.x, acc.x); acc.y = fmaf(xv.y, w1.y, acc.y);
    acc.z = fmaf(xv.y, w1.z, acc.z); acc.w = fmaf(xv.y, w1.w, acc.w);
    acc.x = fmaf(xv.z, w2.x, acc.x); acc.y = fmaf(xv.z, w2.y, acc.y);
    acc.z = fmaf(xv.z, w2.z, acc.z); acc.w = fmaf(xv.z, w2.w, acc.w);
    acc.x = fmaf(xv.w, w3.x, acc.x); acc.y = fmaf(xv.w, w3.y, acc.y);
    acc.z = fmaf(xv.w, w3.z, acc.z); acc.w = fmaf(xv.w, w3.w, acc.w);
  }
  if (SCALE){
    float dv = dinv[row];
    acc.x *= dv; acc.y *= dv; acc.z *= dv; acc.w *= dv;
  }
  *(float4*)(Y + (size_t)row*64 + c0) = acc;
}

// ---------------- GEMM f32-in -> fp16 table out (row = 16 x uint2) ----------------
template<bool RELU>
__global__ __launch_bounds__(256) void k_gemm64h(const float* __restrict__ X, const float* __restrict__ W,
                                                 const float* __restrict__ dinv,
                                                 int nrows, uint2* __restrict__ Y16){
  __shared__ float Ws[64][64];
  int t = threadIdx.x;
  {
    const float4* W4 = (const float4*)W;
    float4* S4 = (float4*)&Ws[0][0];
    #pragma unroll
    for (int i = 0; i < 4; ++i) S4[t + 256*i] = W4[t + 256*i];
  }
  __syncthreads();
  int row = blockIdx.x*16 + (t>>4);
  if (row >= nrows) return;
  int c0 = (t & 15) * 4;
  const float4* Xr = (const float4*)(X + (size_t)row*64);
  float4 acc = make_float4(0.f,0.f,0.f,0.f);
  #pragma unroll
  for (int kk = 0; kk < 16; ++kk){
    float4 xv = Xr[kk];
    if (RELU){
      xv.x = fmaxf(xv.x, 0.f); xv.y = fmaxf(xv.y, 0.f);
      xv.z = fmaxf(xv.z, 0.f); xv.w = fmaxf(xv.w, 0.f);
    }
    int k = kk*4;
    float4 w0 = *(const float4*)&Ws[k+0][c0];
    float4 w1 = *(const float4*)&Ws[k+1][c0];
    float4 w2 = *(const float4*)&Ws[k+2][c0];
    float4 w3 = *(const float4*)&Ws[k+3][c0];
    acc.x = fmaf(xv.x, w0.x, acc.x); acc.y = fmaf(xv.x, w0.y, acc.y);
    acc.z = fmaf(xv.x, w0.z, acc.z); acc.w = fmaf(xv.x, w0.w, acc.w);
    acc.x = fmaf(xv.y, w1.x, acc.x); acc.y = fmaf(xv.y, w1.y, acc.y);
    acc.z = fmaf(xv.y, w1.z, acc.z); acc.w = fmaf(xv.y, w1.w, acc.w);
    acc.x = fmaf(xv.z, w2.x, acc.x); acc.y = fmaf(xv.z, w2.y, acc.y);
    acc.z = fmaf(xv.z, w2.z, acc.z); acc.w = fmaf(xv.z, w2.w, acc.w);
    acc.x = fmaf(xv.w, w3.x, acc.x); acc.y = fmaf(xv.w, w3.y, acc.y);
    acc.z = fmaf(xv.w, w3.z, acc.z); acc.w = fmaf(xv.w, w3.w, acc.w);
  }
  float dv = dinv[row];
  acc.x *= dv; acc.y *= dv; acc.z *= dv; acc.w *= dv;
  Y16[(size_t)row*16 + (t & 15)] = f4_to_h4(acc);
}

// ---------------- GEMM [nrows,64] @ [64,2] ----------------
template<bool RELU, bool SCALE>
__global__ __launch_bounds__(256) void k_gemm2(const float* __restrict__ X, const float* __restrict__ W,
                                               const float* __restrict__ dinv,
                                               int nrows, float* __restrict__ Y){
  __shared__ float Ws[128];
  int t = threadIdx.x;
  if (t < 128) Ws[t] = W[t];
  __syncthreads();
  int row = blockIdx.x*256 + t;
  if (row >= nrows) return;
  const float4* Xr = (const float4*)(X + (size_t)row*64);
  float a0 = 0.f, a1 = 0.f;
  #pragma unroll
  for (int kk = 0; kk < 16; ++kk){
    float4 xv = Xr[kk];
    if (RELU){ xv.x=fmaxf(xv.x,0.f); xv.y=fmaxf(xv.y,0.f); xv.z=fmaxf(xv.z,0.f); xv.w=fmaxf(xv.w,0.f); }
    int k = kk*4;
    a0 = fmaf(xv.x, Ws[2*k+0], a0); a1 = fmaf(xv.x, Ws[2*k+1], a1);
    a0 = fmaf(xv.y, Ws[2*k+2], a0); a1 = fmaf(xv.y, Ws[2*k+3], a1);
    a0 = fmaf(xv.z, Ws[2*k+4], a0); a1 = fmaf(xv.z, Ws[2*k+5], a1);
    a0 = fmaf(xv.w, Ws[2*k+6], a0); a1 = fmaf(xv.w, Ws[2*k+7], a1);
  }
  if (SCALE){ float dv = dinv[row]; a0 *= dv; a1 *= dv; }
  Y[(size_t)row*2]   = a0;
  Y[(size_t)row*2+1] = a1;
}

// ---------------- pipelined row-gather helpers ----------------
__device__ __forceinline__ float4 gather_rows4(const int* __restrict__ col, int beg, int end,
                                               const float4* __restrict__ h4, int fq, float4 acc){
  int j = beg;
  bool p0 = j   < end; int c0 = p0 ? col[j]   : 0;
  bool p1 = j+1 < end; int c1 = p1 ? col[j+1] : 0;
  bool p2 = j+2 < end; int c2 = p2 ? col[j+2] : 0;
  bool p3 = j+3 < end; int c3 = p3 ? col[j+3] : 0;
  while (p0){
    float4 v0 = h4[(size_t)c0*16 + fq];
    float4 v1 = p1 ? h4[(size_t)c1*16 + fq] : make_float4(0.f,0.f,0.f,0.f);
    float4 v2 = p2 ? h4[(size_t)c2*16 + fq] : make_float4(0.f,0.f,0.f,0.f);
    float4 v3 = p3 ? h4[(size_t)c3*16 + fq] : make_float4(0.f,0.f,0.f,0.f);
    j += 4;
    bool q0 = j < end, q1 = j+1 < end, q2 = j+2 < end, q3 = j+3 < end;
    int n0 = q0 ? col[j]   : 0;
    int n1 = q1 ? col[j+1] : 0;
    int n2 = q2 ? col[j+2] : 0;
    int n3 = q3 ? col[j+3] : 0;
    acc.x += v0.x + v1.x + v2.x + v3.x;
    acc.y += v0.y + v1.y + v2.y + v3.y;
    acc.z += v0.z + v1.z + v2.z + v3.z;
    acc.w += v0.w + v1.w + v2.w + v3.w;
    p0=q0; p1=q1; p2=q2; p3=q3; c0=n0; c1=n1; c2=n2; c3=n3;
  }
  return acc;
}

__device__ __forceinline__ float4 gather_rows4_h16(const int* __restrict__ col, int beg, int end,
                                                   const uint2* __restrict__ h16, int fq, float4 acc){
  int j = beg;
  bool p0 = j   < end; int c0 = p0 ? col[j]   : 0;
  bool p1 = j+1 < end; int c1 = p1 ? col[j+1] : 0;
  bool p2 = j+2 < end; int c2 = p2 ? col[j+2] : 0;
  bool p3 = j+3 < end; int c3 = p3 ? col[j+3] : 0;
  const uint2 z = make_uint2(0u, 0u);   // fp16 +0
  while (p0){
    uint2 u0 = h16[(size_t)c0*16 + fq];
    uint2 u1 = p1 ? h16[(size_t)c1*16 + fq] : z;
    uint2 u2 = p2 ? h16[(size_t)c2*16 + fq] : z;
    uint2 u3 = p3 ? h16[(size_t)c3*16 + fq] : z;
    j += 4;
    bool q0 = j < end, q1 = j+1 < end, q2 = j+2 < end, q3 = j+3 < end;
    int n0 = q0 ? col[j]   : 0;
    int n1 = q1 ? col[j+1] : 0;
    int n2 = q2 ? col[j+2] : 0;
    int n3 = q3 ? col[j+3] : 0;
    float4 v0 = h4_to_f4(u0), v1 = h4_to_f4(u1), v2 = h4_to_f4(u2), v3 = h4_to_f4(u3);
    acc.x += v0.x + v1.x + v2.x + v3.x;
    acc.y += v0.y + v1.y + v2.y + v3.y;
    acc.z += v0.z + v1.z + v2.z + v3.z;
    acc.w += v0.w + v1.w + v2.w + v3.w;
    p0=q0; p1=q1; p2=q2; p3=q3; c0=n0; c1=n1; c2=n2; c3=n3;
  }
  return acc;
}

// ---------------- CSR gather conv, f32 table (single/fallback tiers) ----------------
__global__ __launch_bounds__(256) void k_gather64(const int* __restrict__ rowptr, const int* __restrict__ col,
                                                  const float* __restrict__ h, const float* __restrict__ dinv,
                                                  const float* __restrict__ b, float* __restrict__ out){
  int gt = blockIdx.x*256 + threadIdx.x;
  int fq = gt & 15;
  int node = gt >> 4;
  if (node >= NN) return;
  const float4* __restrict__ h4 = (const float4*)h;
  float4 acc = h4[(size_t)node*16 + fq];
  acc = gather_rows4(col, rowptr[node], rowptr[node+1], h4, fq, acc);
  float dv = dinv[node];
  float4 bb = ((const float4*)b)[fq];
  float4 r;
  r.x = fmaf(acc.x, dv, bb.x); r.y = fmaf(acc.y, dv, bb.y);
  r.z = fmaf(acc.z, dv, bb.z); r.w = fmaf(acc.w, dv, bb.w);
  *(float4*)(out + (size_t)node*64 + fq*4) = r;
}

// ---------------- CSR gather conv, fp16 table in, f32 out ----------------
__global__ __launch_bounds__(256) void k_gather64h(const int* __restrict__ rowptr, const int* __restrict__ col,
                                                   const uint2* __restrict__ h16, const float* __restrict__ dinv,
                                                   const float* __restrict__ b, float* __restrict__ out){
  int gt = blockIdx.x*256 + threadIdx.x;
  int fq = gt & 15;
  int node = gt >> 4;
  if (node >= NN) return;
  float4 acc = h4_to_f4(h16[(size_t)node*16 + fq]);
  acc = gather_rows4_h16(col, rowptr[node], rowptr[node+1], h16, fq, acc);
  float dv = dinv[node];
  float4 bb = ((const float4*)b)[fq];
  float4 r;
  r.x = fmaf(acc.x, dv, bb.x); r.y = fmaf(acc.y, dv, bb.y);
  r.z = fmaf(acc.z, dv, bb.z); r.w = fmaf(acc.w, dv, bb.w);
  *(float4*)(out + (size_t)node*64 + fq*4) = r;
}

// ---------------- FUSED: gather conv1(fp16) + ReLU + @W2 + scale -> fp16 table ----------------
__global__ __launch_bounds__(256) void k_gathergemmh(const int* __restrict__ rowptr, const int* __restrict__ col,
                                                     const uint2* __restrict__ h16, const float* __restrict__ dinv,
                                                     const float* __restrict__ b1, const float* __restrict__ W2,
                                                     uint2* __restrict__ Y16){
  __shared__ float Ws[64][64];
  __shared__ float rows[16][68];
  int t = threadIdx.x;
  {
    const float4* W4 = (const float4*)W2;
    float4* S4 = (float4*)&Ws[0][0];
    #pragma unroll
    for (int i = 0; i < 4; ++i) S4[t + 256*i] = W4[t + 256*i];
  }
  __syncthreads();
  int fq = t & 15, grp = t >> 4;
  int node = blockIdx.x*16 + grp;
  bool alive = node < NN;
  float dv = 0.f;
  if (alive){
    float4 acc = h4_to_f4(h16[(size_t)node*16 + fq]);
    acc = gather_rows4_h16(col, rowptr[node], rowptr[node+1], h16, fq, acc);
    dv = dinv[node];
    float4 bb = ((const float4*)b1)[fq];
    float4 r;
    r.x = fmaxf(fmaf(acc.x, dv, bb.x), 0.f);
    r.y = fmaxf(fmaf(acc.y, dv, bb.y), 0.f);
    r.z = fmaxf(fmaf(acc.z, dv, bb.z), 0.f);
    r.w = fmaxf(fmaf(acc.w, dv, bb.w), 0.f);
    *(float4*)&rows[grp][fq*4] = r;
  }
  __syncthreads();
  if (alive){
    const float* __restrict__ row = &rows[grp][0];
    float4 o = make_float4(0.f,0.f,0.f,0.f);
    int c0 = fq*4;
    #pragma unroll 8
    for (int k = 0; k < 64; ++k){
      float rv = row[k];
      float4 w = *(const float4*)&Ws[k][c0];
      o.x = fmaf(rv, w.x, o.x); o.y = fmaf(rv, w.y, o.y);
      o.z = fmaf(rv, w.z, o.z); o.w = fmaf(rv, w.w, o.w);
    }
    o.x *= dv; o.y *= dv; o.z *= dv; o.w *= dv;
    Y16[(size_t)node*16 + fq] = f4_to_h4(o);
  }
}

// f32 version (single tier)
__global__ __launch_bounds__(256) void k_gathergemm(const int* __restrict__ rowptr, const int* __restrict__ col,
                                                    const float* __restrict__ h, const float* __restrict__ dinv,
                                                    const float* __restrict__ b1, const float* __restrict__ W2,
                                                    float* __restrict__ Y){
  __shared__ float Ws[64][64];
  __shared__ float rows[16][68];
  int t = threadIdx.x;
  {
    const float4* W4 = (const float4*)W2;
    float4* S4 = (float4*)&Ws[0][0];
    #pragma unroll
    for (int i = 0; i < 4; ++i) S4[t + 256*i] = W4[t + 256*i];
  }
  __syncthreads();
  int fq = t & 15, grp = t >> 4;
  int node = blockIdx.x*16 + grp;
  bool alive = node < NN;
  float dv = 0.f;
  if (alive){
    const float4* __restrict__ h4 = (const float4*)h;
    float4 acc = h4[(size_t)node*16 + fq];
    acc = gather_rows4(col, rowptr[node], rowptr[node+1], h4, fq, acc);
    dv = dinv[node];
    float4 bb = ((const float4*)b1)[fq];
    float4 r;
    r.x = fmaxf(fmaf(acc.x, dv, bb.x), 0.f);
    r.y = fmaxf(fmaf(acc.y, dv, bb.y), 0.f);
    r.z = fmaxf(fmaf(acc.z, dv, bb.z), 0.f);
    r.w = fmaxf(fmaf(acc.w, dv, bb.w), 0.f);
    *(float4*)&rows[grp][fq*4] = r;
  }
  __syncthreads();
  if (alive){
    const float* __restrict__ row = &rows[grp][0];
    float4 o = make_float4(0.f,0.f,0.f,0.f);
    int c0 = fq*4;
    #pragma unroll 8
    for (int k = 0; k < 64; ++k){
      float rv = row[k];
      float4 w = *(const float4*)&Ws[k][c0];
      o.x = fmaf(rv, w.x, o.x); o.y = fmaf(rv, w.y, o.y);
      o.z = fmaf(rv, w.z, o.z); o.w = fmaf(rv, w.w, o.w);
    }
    o.x *= dv; o.y *= dv; o.z *= dv; o.w *= dv;
    *(float4*)(Y + (size_t)node*64 + fq*4) = o;
  }
}

// ---------------- FUSED: lf-gather (fp16, CSR-A) + cross-layer agg (f32 last, CSR-B) + scale (+dropout) ----------------
template<bool DROP>
__global__ __launch_bounds__(256) void k_gatherlfaggh(const int* __restrict__ rpA, const int* __restrict__ colA,
                                                      const uint2* __restrict__ h16, const float* __restrict__ dinv,
                                                      const float* __restrict__ b,
                                                      const int* __restrict__ rpB, const int* __restrict__ colB,
                                                      const float* __restrict__ last,
                                                      const float* __restrict__ ds, int dsidx,
                                                      float* __restrict__ out){
  int gt = blockIdx.x*256 + threadIdx.x;
  int fq = gt & 15;
  int node = gt >> 4;
  if (node >= NN) return;
  float4 acc = h4_to_f4(h16[(size_t)node*16 + fq]);
  acc = gather_rows4_h16(colA, rpA[node], rpA[node+1], h16, fq, acc);
  float dv = dinv[node];
  float4 bb = ((const float4*)b)[fq];
  float4 lf;
  lf.x = fmaf(acc.x, dv, bb.x); lf.y = fmaf(acc.y, dv, bb.y);
  lf.z = fmaf(acc.z, dv, bb.z); lf.w = fmaf(acc.w, dv, bb.w);
  float4 agg = gather_rows4(colB, rpB[node], rpB[node+1], (const float4*)last, fq,
                            make_float4(0.f,0.f,0.f,0.f));
  float inv = 1.0f / ds[dsidx];
  float4 r;
  r.x = (lf.x + agg.x) * inv; r.y = (lf.y + agg.y) * inv;
  r.z = (lf.z + agg.z) * inv; r.w = (lf.w + agg.w) * inv;
  if (DROP){
    unsigned base_i = (unsigned)node*64u + (unsigned)fq*4u;
    r.x = dropout_val(r.x, base_i + 0);
    r.y = dropout_val(r.y, base_i + 1);
    r.z = dropout_val(r.z, base_i + 2);
    r.w = dropout_val(r.w, base_i + 3);
  }
  *(float4*)(out + (size_t)node*64 + fq*4) = r;
}

// ---------------- CSR gather cross-layer agg f32 (single tier) ----------------
template<bool DROP>
__global__ __launch_bounds__(256) void k_agggather(const int* __restrict__ rowptr, const int* __restrict__ col,
                                                    const float* __restrict__ lf, const float* __restrict__ last,
                                                    const float* __restrict__ ds, int dsidx, float* __restrict__ out){
  int gt = blockIdx.x*256 + threadIdx.x;
  int fq = gt & 15;
  int node = gt >> 4;
  if (node >= NN) return;
  float4 acc = ((const float4*)lf)[(size_t)node*16 + fq];
  acc = gather_rows4(col, rowptr[node], rowptr[node+1], (const float4*)last, fq, acc);
  float inv = 1.0f / ds[dsidx];
  float4 r;
  r.x = acc.x * inv; r.y = acc.y * inv; r.z = acc.z * inv; r.w = acc.w * inv;
  if (DROP){
    unsigned base_i = (unsigned)node*64u + (unsigned)fq*4u;
    r.x = dropout_val(r.x, base_i + 0);
    r.y = dropout_val(r.y, base_i + 1);
    r.z = dropout_val(r.z, base_i + 2);
    r.w = dropout_val(r.w, base_i + 3);
  }
  *(float4*)(out + (size_t)node*64 + fq*4) = r;
}

// ---------------- CSR gather final conv (D_out=2) ----------------
__global__ void k_gather2(const int* __restrict__ rowptr, const int* __restrict__ col,
                          const float* __restrict__ h2, const float* __restrict__ dinv,
                          const float* __restrict__ b, float* __restrict__ out){
  int d = blockIdx.x*256 + threadIdx.x;
  if (d >= NN) return;
  int beg = rowptr[d], end = rowptr[d+1];
  float a0 = h2[(size_t)d*2];
  float a1 = h2[(size_t)d*2+1];
  for (int j = beg; j < end; ++j){
    int s = col[j];
    a0 += h2[(size_t)s*2];
    a1 += h2[(size_t)s*2+1];
  }
  float dv = dinv[d];
  out[(size_t)d*2]   = fmaf(a0, dv, b[0]);
  out[(size_t)d*2+1] = fmaf(a1, dv, b[1]);
}

// ---------------- standalone dropout (fallback path only) ----------------
__global__ void k_dropout(const float* __restrict__ last, float* __restrict__ xemb){
  unsigned i = blockIdx.x*256 + threadIdx.x;
  if (i >= NF) return;
  xemb[i] = dropout_val(last[i], i);
}

// ======== fallback (atomic scatter) kernels ========
__global__ void k_convinit(const float* __restrict__ h, const float* __restrict__ dinv,
                           const float* __restrict__ b, float* __restrict__ out){
  int i = blockIdx.x*256 + threadIdx.x;
  if (i >= NF) return;
  int v = i >> 6, c = i & 63;
  float dv = dinv[v];
  out[i] = h[i]*dv*dv + b[c];
}
__global__ void k_scatter64(const int* __restrict__ src, const int* __restrict__ dst, int ne,
                            const float* __restrict__ h, const float* __restrict__ dinv,
                            float* __restrict__ out){
  int lane = threadIdx.x & 63;
  int wid  = (blockIdx.x*256 + threadIdx.x) >> 6;
  int nw   = (gridDim.x*256) >> 6;
  for (int e = wid; e < ne; e += nw){
    int s = src[e], d = dst[e];
    float coef = dinv[s]*dinv[d];
    atomicAdd(&out[d*64 + lane], h[s*64 + lane]*coef);
  }
}
__global__ void k_layeragg(const int* __restrict__ recv, const int* __restrict__ srcn, int ne,
                           const float* __restrict__ last, float* __restrict__ acc){
  int lane = threadIdx.x & 63;
  int wid  = (blockIdx.x*256 + threadIdx.x) >> 6;
  int nw   = (gridDim.x*256) >> 6;
  for (int e = wid; e < ne; e += nw){
    int r = recv[e], s = srcn[e];
    atomicAdd(&acc[r*64 + lane], last[s*64 + lane]);
  }
}
__global__ void k_scale(const float* __restrict__ in, const float* __restrict__ ds, int dsidx,
                        float* __restrict__ out){
  int i = blockIdx.x*256 + threadIdx.x;
  if (i < NF) out[i] = in[i] / ds[dsidx];
}
__global__ void k_convinit2(const float* __restrict__ h2, const float* __restrict__ dinv,
                            const float* __restrict__ b, float* __restrict__ out){
  int i = blockIdx.x*256 + threadIdx.x;
  if (i >= NN*2) return;
  int v = i >> 1, c = i & 1;
  float dv = dinv[v];
  out[i] = h2[i]*dv*dv + b[c];
}
__global__ void k_scatter2(const int* __restrict__ src, const int* __restrict__ dst, int ne,
                           const float* __restrict__ h2, const float* __restrict__ dinv,
                           float* __restrict__ out){
  int e = blockIdx.x*256 + threadIdx.x;
  if (e >= ne) return;
  int s = src[e], d = dst[e];
  float coef = dinv[s]*dinv[d];
  atomicAdd(&out[d*2 + 0], h2[s*2 + 0]*coef);
  atomicAdd(&out[d*2 + 1], h2[s*2 + 1]*coef);
}

extern "C" void kernel_launch(void* const* d_in, const int* in_sizes, int n_in,
                              void* d_out, int out_size, void* d_ws, size_t ws_size,
                              hipStream_t stream) {
  const float* x    = (const float*)d_in[0];
  const int*   ei   = (const int*)  d_in[1];
  const int*   lei  = (const int*)  d_in[2];
  const float* degs = (const float*)d_in[3];
  const float* lW1  = (const float*)d_in[4];
  const float* lb1  = (const float*)d_in[5];
  const float* lW2  = (const float*)d_in[6];
  const float* lb2  = (const float*)d_in[7];
  const float* pW1  = (const float*)d_in[8];
  const float* pb1  = (const float*)d_in[9];
  const float* pW2  = (const float*)d_in[10];
  const float* pb2  = (const float*)d_in[11];
  float* out = (float*)d_out;

  const int gN  = (NN + 255)/256;
  const int gE  = (EE + 255)/256;
  const int gEL = (ELL + 255)/256;
  const int gNF = (NF + 255)/256;
  const int gG16 = (NN*16 + 255)/256;   // 6250

  const bool dual   = ws_size >= (size_t)WS_DUAL * 4;
  const bool single = ws_size >= (size_t)WS_SINGLE * 4;

  if (dual) {
    float* base   = (float*)d_ws;
    float* dinv   = base;
    int*   cnt    = (int*)(base + OFF_CNT);
    int*   bsum   = (int*)(base + OFF_BSUM);
    int*   flag   = bsum + 120;
    int*   rpA    = (int*)(base + OFF_RPA);
    int*   colA   = (int*)(base + OFF_COLA);
    int*   rpB    = (int*)(base + OFF_RPB);
    int*   colB   = (int*)(base + OFF_COLB);
    float* F0     = base + OFF_COLB + 1000000;
    float* F1     = F0 + NF;
    float* F2     = F1 + NF;
    uint2* H0     = (uint2*)(F2 + NF);               // NF/2 floats
    uint2* H1     = H0 + (size_t)NN*16;              // NF/2 floats

    auto build_csr = [&](const int* srcp, const int* dstp, int ne, int gEdges, int computeDinv,
                         int* rowptr, int* col, int* rank){
      k_degrank<<<gEdges, 256, 0, stream>>>(dstp, ne, cnt, rank);
      k_scanfused<<<NB_SCAN, 1024, 0, stream>>>(cnt, bsum, flag, rowptr, dinv, computeDinv, NN);
      k_fillrz<<<gEdges, 256, 0, stream>>>(srcp, dstp, ne, rowptr, rank, col, cnt, flag);
    };

    const int* s0 = ei;                  const int* d0 = s0 + EE;
    const int* s1 = ei + 2*(size_t)EE;   const int* d1 = s1 + EE;
    const int* s2 = ei + 4*(size_t)EE;   const int* d2 = s2 + EE;
    const int* r0 = lei;                 const int* ls0 = r0 + ELL;
    const int* r1 = lei + 2*(size_t)ELL; const int* ls1 = r1 + ELL;

    k_zerof<<<gN, 256, 0, stream>>>(cnt, NN, flag);

    // ---- surface 0 ----  (rank in F0: free)
    build_csr(s0, d0, EE, gE, 1, rpA, colA, (int*)F0);
    k_gemm64h<false><<<6250, 256, 0, stream>>>(x, lW1, dinv, NN, H0);
    k_gathergemmh<<<6250, 256, 0, stream>>>(rpA, colA, H0, dinv, lb1, lW2, H1);
    k_gather64h<<<gG16, 256, 0, stream>>>(rpA, colA, H1, dinv, lb2, F2);             // last = F2 (f32)
    // ---- surface 1 ----  (rank in F0: free)
    build_csr(s1, d1, EE, gE, 1, rpA, colA, (int*)F0);
    build_csr(ls0, r0, ELL, gEL, 0, rpB, colB, (int*)F0);
    k_gemm64h<false><<<6250, 256, 0, stream>>>(x + (size_t)NF, lW1 + 4096, dinv, NN, H0);
    k_gathergemmh<<<6250, 256, 0, stream>>>(rpA, colA, H0, dinv, lb1 + 64, lW2 + 4096, H1);
    k_gatherlfaggh<false><<<gG16, 256, 0, stream>>>(rpA, colA, H1, dinv, lb2 + 64,
                                                    rpB, colB, F2, degs, 0, F0);     // last = F0
    // ---- surface 2 ----  (rank in F1: free)
    build_csr(s2, d2, EE, gE, 1, rpA, colA, (int*)F1);
    build_csr(ls1, r1, ELL, gEL, 0, rpB, colB, (int*)F1);
    k_gemm64h<false><<<6250, 256, 0, stream>>>(x + 2*(size_t)NF, lW1 + 8192, dinv, NN, H0);
    k_gathergemmh<<<6250, 256, 0, stream>>>(rpA, colA, H0, dinv, lb1 + 128, lW2 + 8192, H1);
    k_gatherlfaggh<true><<<gG16, 256, 0, stream>>>(rpA, colA, H1, dinv, lb2 + 128,
                                                   rpB, colB, F0, degs, 1, F1);      // F1 = x_emb (f32)
    // ---- predictor (CSR-A = surface-2 edges; dinv = surface-2 degrees) ----
    k_gemm64h<false><<<6250, 256, 0, stream>>>(F1, pW1, dinv, NN, H0);
    k_gather64h<<<gG16, 256, 0, stream>>>(rpA, colA, H0, dinv, pb1, F2);
    k_gemm2<true,true><<<gN, 256, 0, stream>>>(F2, pW2, dinv, NN, F1);
    k_gather2<<<gN, 256, 0, stream>>>(rpA, colA, F1, dinv, pb2, out);
    k_probe<<<1, 64, 0, stream>>>(ei, 0u, out);
    return;
  }

  if (single) {
    // ======= R14-proven single-slot f32 path =======
    float* base   = (float*)d_ws;
    float* dinv   = base;
    int*   cnt    = (int*)(base + OFF_CNT);
    int*   bsum   = (int*)(base + OFF_BSUM);
    int*   flag   = bsum + 120;
    int*   rpA    = (int*)(base + OFF_RPA);
    int*   colA   = (int*)(base + OFF_COLA);
    float* F0     = base + OFF_RPB;
    float* F1     = F0 + NF;
    float* F2     = F1 + NF;

    auto build_csr = [&](const int* srcp, const int* dstp, int ne, int gEdges, int computeDinv,
                         int* rowptr, int* col, int* rank){
      k_zerof<<<gN, 256, 0, stream>>>(cnt, NN, flag);
      k_degrank<<<gEdges, 256, 0, stream>>>(dstp, ne, cnt, rank);
      k_scanfused<<<NB_SCAN, 1024, 0, stream>>>(cnt, bsum, flag, rowptr, dinv, computeDinv, NN);
      k_fillr<<<gEdges, 256, 0, stream>>>(srcp, dstp, ne, rowptr, rank, col);
    };

    const int* s0 = ei;                  const int* d0 = s0 + EE;
    const int* s1 = ei + 2*(size_t)EE;   const int* d1 = s1 + EE;
    const int* s2 = ei + 4*(size_t)EE;   const int* d2 = s2 + EE;
    const int* r0 = lei;                 const int* ls0 = r0 + ELL;
    const int* r1 = lei + 2*(size_t)ELL; const int* ls1 = r1 + ELL;

    build_csr(s0, d0, EE, gE, 1, rpA, colA, (int*)F0);
    k_gemm64<false,true><<<6250, 256, 0, stream>>>(x, lW1, dinv, NN, F0);
    k_gathergemm<<<6250, 256, 0, stream>>>(rpA, colA, F0, dinv, lb1, lW2, F1);
    k_gather64<<<gG16, 256, 0, stream>>>(rpA, colA, F1, dinv, lb2, F2);
    build_csr(s1, d1, EE, gE, 1, rpA, colA, (int*)F0);
    k_gemm64<false,true><<<6250, 256, 0, stream>>>(x + (size_t)NF, lW1 + 4096, dinv, NN, F0);
    k_gathergemm<<<6250, 256, 0, stream>>>(rpA, colA, F0, dinv, lb1 + 64, lW2 + 4096, F1);
    build_csr(ls0, r0, ELL, gEL, 0, rpA, colA, (int*)F0);
    k_agggather<false><<<gG16, 256, 0, stream>>>(rpA, colA, F1, F2, degs, 0, F0);
    build_csr(s2, d2, EE, gE, 1, rpA, colA, (int*)F1);
    k_gemm64<false,true><<<6250, 256, 0, stream>>>(x + 2*(size_t)NF, lW1 + 8192, dinv, NN, F1);
    k_gathergemm<<<6250, 256, 0, stream>>>(rpA, colA, F1, dinv, lb1 + 128, lW2 + 8192, F2);
    build_csr(ls1, r1, ELL, gEL, 0, rpA, colA, (int*)F1);
    k_agggather<true><<<gG16, 256, 0, stream>>>(rpA, colA, F2, F0, degs, 1, F1);
    build_csr(s2, d2, EE, gE, 0, rpA, colA, (int*)F0);
    k_gemm64<false,true><<<6250, 256, 0, stream>>>(F1, pW1, dinv, NN, F0);
    k_gather64<<<gG16, 256, 0, stream>>>(rpA, colA, F0, dinv, pb1, F2);
    k_gemm2<true,true><<<gN, 256, 0, stream>>>(F2, pW2, dinv, NN, F1);
    k_gather2<<<gN, 256, 0, stream>>>(rpA, colA, F1, dinv, pb2, out);
    k_probe<<<1, 64, 0, stream>>>(ei, 0u, out);
    return;
  }

  // ================= fallback: verified atomic-scatter path =================
  float* base = (float*)d_ws;
  float* dinv = base;
  int*   cnt  = (int*)(base + 100352);
  float* A    = base + 262144;
  float* B    = A + NF;
  float* C    = B + NF;

  for (int i = 0; i < 3; ++i){
    const int* srcp = ei + (size_t)i*2*EE;
    const int* dstp = srcp + EE;
    k_zero_int<<<gN, 256, 0, stream>>>(cnt, NN);
    k_deg<<<gE, 256, 0, stream>>>(dstp, EE, cnt);
    k_dinv<<<gN, 256, 0, stream>>>(cnt, dinv, NN);
    k_gemm64<false,false><<<6250, 256, 0, stream>>>(x + (size_t)i*NF, lW1 + (size_t)i*64*64, dinv, NN, A);
    k_convinit<<<gNF, 256, 0, stream>>>(A, dinv, lb1 + (size_t)i*64, B);
    k_scatter64<<<8192, 256, 0, stream>>>(srcp, dstp, EE, A, dinv, B);
    k_gemm64<true,false><<<6250, 256, 0, stream>>>(B, lW2 + (size_t)i*64*64, dinv, NN, A);
    float* T = (i == 0) ? C : B;
    k_convinit<<<gNF, 256, 0, stream>>>(A, dinv, lb2 + (size_t)i*64, T);
    k_scatter64<<<8192, 256, 0, stream>>>(srcp, dstp, EE, A, dinv, T);
    if (i > 0){
      const int* recvp = lei + (size_t)(i-1)*2*ELL;
      const int* lsrcp = recvp + ELL;
      k_layeragg<<<4096, 256, 0, stream>>>(recvp, lsrcp, ELL, C, B);
      k_scale<<<gNF, 256, 0, stream>>>(B, degs, i-1, C);
    }
  }
  k_dropout<<<gNF, 256, 0, stream>>>(C, B);
  const int* srcp = ei + (size_t)2*2*EE;
  const int* dstp = srcp + EE;
  k_gemm64<false,false><<<6250, 256, 0, stream>>>(B, pW1, dinv, NN, A);
  k_convinit<<<gNF, 256, 0, stream>>>(A, dinv, pb1, C);
  k_scatter64<<<8192, 256, 0, stream>>>(srcp, dstp, EE, A, dinv, C);
  k_gemm2<true,false><<<gN, 256, 0, stream>>>(C, pW2, dinv, NN, B);
  k_convinit2<<<(NN*2 + 255)/256, 256, 0, stream>>>(B, dinv, pb2, out);
  k_scatter2<<<gE, 256, 0, stream>>>(srcp, dstp, EE, B, dinv, out);
  k_probe<<<1, 64, 0, stream>>>(ei, 0u, out);
}

// Round 17
// 630.481 us; speedup vs baseline: 1.7114x; 1.0242x over previous
//
#include <hip/hip_runtime.h>
#include <hip/hip_fp16.h>

#define NN 100000
#define EE 1000000
#define ELL 500000
#define NF (NN*64)
#define NB_SCAN ((NN + 1023) / 1024)   // 98

// ws layouts (floats)
#define OFF_CNT    100352
#define OFF_BSUM   200704
#define OFF_RPA    200832
#define OFF_COLA   301184
#define OFF_RPB    1301184
#define OFF_COLB   1401536
#define WS_SINGLE  (1301184 + 3*NF)              // 82.0 MB
#define WS_DUAL    (2401536 + 5*NF)              // dual + F0..F2 + 4 fp16 tables  (137.6 MB)

// ---------------- Threefry-2x32 ----------------
__device__ __forceinline__ void threefry2x32(unsigned k0, unsigned k1, unsigned &x0, unsigned &x1){
  unsigned ks2 = k0 ^ k1 ^ 0x1BD11BDAu;
#define TF_R(R) { x0 += x1; x1 = (x1<<(R))|(x1>>(32-(R))); x1 ^= x0; }
  x0 += k0; x1 += k1;
  TF_R(13) TF_R(15) TF_R(26) TF_R(6)
  x0 += k1;  x1 += ks2 + 1u;
  TF_R(17) TF_R(29) TF_R(16) TF_R(24)
  x0 += ks2; x1 += k0 + 2u;
  TF_R(13) TF_R(15) TF_R(26) TF_R(6)
  x0 += k0;  x1 += k1 + 3u;
  TF_R(17) TF_R(29) TF_R(16) TF_R(24)
  x0 += k1;  x1 += ks2 + 4u;
  TF_R(13) TF_R(15) TF_R(26) TF_R(6)
  x0 += ks2; x1 += k0 + 5u;
#undef TF_R
}

__device__ __forceinline__ float dropout_val(float v, unsigned i){
  unsigned x0 = 0u, x1 = i;
  threefry2x32(0u, 42u, x0, x1);
  unsigned bits = x0 ^ x1;
  float u = __uint_as_float((bits >> 9) | 0x3f800000u) - 1.0f;
  return (u < 0.6f) ? v * (1.0f/0.6f) : 0.0f;
}

__global__ void k_probe(const int* __restrict__ ei, unsigned hostbits, float* __restrict__ out){
  if (threadIdx.x != 0 || blockIdx.x != 0) return;
  unsigned bits = hostbits;
  { unsigned a=0u, b=0u; threefry2x32(0u, 0u, a, b);
    if (a != 0x6b200159u || b != 0x99ba4efeu) bits |= 1u; }
  if (bits) out[0] = 1.0e4f * (float)bits;
}

// ---------------- fp16 pack/unpack ----------------
__device__ __forceinline__ uint2 f4_to_h4(float4 v){
  __half2 lo = __floats2half2_rn(v.x, v.y);
  __half2 hi = __floats2half2_rn(v.z, v.w);
  uint2 r; r.x = *(unsigned*)&lo; r.y = *(unsigned*)&hi; return r;
}
__device__ __forceinline__ float4 h4_to_f4(uint2 u){
  __half2 lo = *(__half2*)&u.x;
  __half2 hi = *(__half2*)&u.y;
  float2 a = __half22float2(lo), b = __half22float2(hi);
  return make_float4(a.x, a.y, b.x, b.y);
}

// ---------------- utility ----------------
__global__ void k_zero_int(int* __restrict__ p, int n){
  int i = blockIdx.x*256 + threadIdx.x;
  if (i < n) p[i] = 0;
}

__global__ void k_zerof(int* __restrict__ cnt, int n, int* __restrict__ flag){
  int i = blockIdx.x*256 + threadIdx.x;
  if (i < n) cnt[i] = 0;
  if (i == 0) *flag = 0;
}

__global__ void k_deg(const int* __restrict__ dst, int ne, int* __restrict__ cnt){
  int i = blockIdx.x*256 + threadIdx.x;
  if (i < ne) atomicAdd(&cnt[dst[i]], 1);
}

__global__ void k_degrank(const int* __restrict__ dst, int ne, int* __restrict__ cnt,
                          int* __restrict__ rank){
  int i = blockIdx.x*256 + threadIdx.x;
  if (i >= ne) return;
  rank[i] = atomicAdd(&cnt[dst[i]], 1);
}

__global__ void k_dinv(const int* __restrict__ cnt, float* __restrict__ dinv, int n){
  int i = blockIdx.x*256 + threadIdx.x;
  if (i < n) dinv[i] = 1.0f / sqrtf((float)(cnt[i] + 1));
}

// ---------------- fused single-launch scan (98 blocks, device spin barrier) + dinv ----------------
__global__ __launch_bounds__(1024) void k_scanfused(const int* __restrict__ cnt, int* __restrict__ bsum,
                                                    int* __restrict__ flag, int* __restrict__ rowptr,
                                                    float* __restrict__ dinv, int computeDinv, int n){
  __shared__ int lds[1024];
  __shared__ int ps[128];
  int t = threadIdx.x;
  int i = blockIdx.x*1024 + t;
  int v = (i < n) ? cnt[i] : 0;
  if (computeDinv && i < n) dinv[i] = 1.0f / sqrtf((float)(v + 1));
  lds[t] = v;
  __syncthreads();
  for (int off = 1; off < 1024; off <<= 1){
    int x = (t >= off) ? lds[t - off] : 0;
    __syncthreads();
    lds[t] += x;
    __syncthreads();
  }
  int incl = lds[t];
  if (t == 1023){
    bsum[blockIdx.x] = lds[1023];
    __threadfence();
    atomicAdd(flag, 1);
  }
  if (t == 0){
    while (atomicAdd(flag, 0) < NB_SCAN) { }
  }
  __syncthreads();
  if (t < 128) ps[t] = (t < blockIdx.x) ? bsum[t] : 0;
  __syncthreads();
  if (t < 64) ps[t] += ps[t + 64];
  __syncthreads();
  if (t < 32) ps[t] += ps[t + 32];
  __syncthreads();
  if (t < 16) ps[t] += ps[t + 16];
  __syncthreads();
  if (t < 8)  ps[t] += ps[t + 8];
  __syncthreads();
  if (t < 4)  ps[t] += ps[t + 4];
  __syncthreads();
  if (t < 2)  ps[t] += ps[t + 2];
  __syncthreads();
  if (t < 1)  ps[t] += ps[t + 1];
  __syncthreads();
  int excl = incl - v + ps[0];
  if (i < n)  rowptr[i] = excl;
  if (i == n-1) rowptr[n] = excl + v;
}

// ---------------- CSR fill, atomic-free; also re-zeroes cnt+flag for the NEXT build ----------------
__global__ void k_fillrz(const int* __restrict__ src, const int* __restrict__ dst, int ne,
                         const int* __restrict__ rowptr, const int* __restrict__ rank,
                         int* __restrict__ col, int* __restrict__ cnt, int* __restrict__ flag){
  int e = blockIdx.x*256 + threadIdx.x;
  if (e < NN) cnt[e] = 0;
  if (e == 0) *flag = 0;
  if (e >= ne) return;
  col[rowptr[dst[e]] + rank[e]] = src[e];
}

__global__ void k_fillr(const int* __restrict__ src, const int* __restrict__ dst, int ne,
                        const int* __restrict__ rowptr, const int* __restrict__ rank,
                        int* __restrict__ col){
  int e = blockIdx.x*256 + threadIdx.x;
  if (e >= ne) return;
  col[rowptr[dst[e]] + rank[e]] = src[e];
}

// ---------------- GEMM [nrows,64] @ [64,64]; RELU on input; SCALE: row *= dinv[row]; f32 out ----------------
template<bool RELU, bool SCALE>
__global__ __launch_bounds__(256) void k_gemm64(const float* __restrict__ X, const float* __restrict__ W,
                                                const float* __restrict__ dinv,
                                                int nrows, float* __restrict__ Y){
  __shared__ float Ws[64][64];
  int t = threadIdx.x;
  {
    const float4* W4 = (const float4*)W;
    float4* S4 = (float4*)&Ws[0][0];
    #pragma unroll
    for (int i = 0; i < 4; ++i) S4[t + 256*i] = W4[t + 256*i];
  }
  __syncthreads();
  int row = blockIdx.x*16 + (t>>4);
  if (row >= nrows) return;
  int c0 = (t & 15) * 4;
  const float4* Xr = (const float4*)(X + (size_t)row*64);
  float4 acc = make_float4(0.f,0.f,0.f,0.f);
  #pragma unroll
  for (int kk = 0; kk < 16; ++kk){
    float4 xv = Xr[kk];
    if (RELU){
      xv.x = fmaxf(xv.x, 0.f); xv.y = fmaxf(xv.y, 0.f);
      xv.z = fmaxf(xv.z, 0.f); xv.w = fmaxf(xv.w, 0.f);
    }
    int k = kk*4;
    float4 w0 = *(const float4*)&Ws[k+0][c0];
    float4 w1 = *(const float4*)&Ws[k+1][c0];
    float4 w2 = *(const float4*)&Ws[k+2][c0];
    float4 w3 = *(const float4*)&Ws[k+3][c0];
    acc.x = fmaf(xv.x, w0.x, acc.x); acc.y = fmaf(xv.x, w0.y, acc.y);
    acc.z = fmaf(xv.x, w0.z, acc.z); acc.w = fmaf(xv.x, w0.w, acc.w);
    acc.x = fmaf(xv.y, w1.x, acc.x); acc.y = fmaf(xv.y, w1.y, acc.y);
    acc.z = fmaf(xv.y, w1.z, acc.z); acc.w = fmaf(xv.y, w1.w, acc.w);
    acc.x = fmaf(xv.z, w2.x, acc.x); acc.y = fmaf(xv.z, w2.y, acc.y);
    acc.z = fmaf(xv.z, w2.z, acc.z); acc.w = fmaf(xv.z, w2.w, acc.w);
    acc.x = fmaf(xv.w, w3.x, acc.x); acc.y = fmaf(xv.w, w3.y, acc.y);
    acc.z = fmaf(xv.w, w3.z, acc.z); acc.w = fmaf(xv.w, w3.w, acc.w);
  }
  if (SCALE){
    float dv = dinv[row];
    acc.x *= dv; acc.y *= dv; acc.z *= dv; acc.w *= dv;
  }
  *(float4*)(Y + (size_t)row*64 + c0) = acc;
}

// ---------------- GEMM f32-in -> fp16 table out (row = 16 x uint2) ----------------
template<bool RELU>
__global__ __launch_bounds__(256) void k_gemm64h(const float* __restrict__ X, const float* __restrict__ W,
                                                 const float* __restrict__ dinv,
                                                 int nrows, uint2* __restrict__ Y16){
  __shared__ float Ws[64][64];
  int t = threadIdx.x;
  {
    const float4* W4 = (const float4*)W;
    float4* S4 = (float4*)&Ws[0][0];
    #pragma unroll
    for (int i = 0; i < 4; ++i) S4[t + 256*i] = W4[t + 256*i];
  }
  __syncthreads();
  int row = blockIdx.x*16 + (t>>4);
  if (row >= nrows) return;
  int c0 = (t & 15) * 4;
  const float4* Xr = (const float4*)(X + (size_t)row*64);
  float4 acc = make_float4(0.f,0.f,0.f,0.f);
  #pragma unroll
  for (int kk = 0; kk < 16; ++kk){
    float4 xv = Xr[kk];
    if (RELU){
      xv.x = fmaxf(xv.x, 0.f); xv.y = fmaxf(xv.y, 0.f);
      xv.z = fmaxf(xv.z, 0.f); xv.w = fmaxf(xv.w, 0.f);
    }
    int k = kk*4;
    float4 w0 = *(const float4*)&Ws[k+0][c0];
    float4 w1 = *(const float4*)&Ws[k+1][c0];
    float4 w2 = *(const float4*)&Ws[k+2][c0];
    float4 w3 = *(const float4*)&Ws[k+3][c0];
    acc.x = fmaf(xv.x, w0.x, acc.x); acc.y = fmaf(xv.x, w0.y, acc.y);
    acc.z = fmaf(xv.x, w0.z, acc.z); acc.w = fmaf(xv.x, w0.w, acc.w);
    acc.x = fmaf(xv.y, w1.x, acc.x); acc.y = fmaf(xv.y, w1.y, acc.y);
    acc.z = fmaf(xv.y, w1.z, acc.z); acc.w = fmaf(xv.y, w1.w, acc.w);
    acc.x = fmaf(xv.z, w2.x, acc.x); acc.y = fmaf(xv.z, w2.y, acc.y);
    acc.z = fmaf(xv.z, w2.z, acc.z); acc.w = fmaf(xv.z, w2.w, acc.w);
    acc.x = fmaf(xv.w, w3.x, acc.x); acc.y = fmaf(xv.w, w3.y, acc.y);
    acc.z = fmaf(xv.w, w3.z, acc.z); acc.w = fmaf(xv.w, w3.w, acc.w);
  }
  float dv = dinv[row];
  acc.x *= dv; acc.y *= dv; acc.z *= dv; acc.w *= dv;
  Y16[(size_t)row*16 + (t & 15)] = f4_to_h4(acc);
}

// ---------------- GEMM [nrows,64] @ [64,2] ----------------
template<bool RELU, bool SCALE>
__global__ __launch_bounds__(256) void k_gemm2(const float* __restrict__ X, const float* __restrict__ W,
                                               const float* __restrict__ dinv,
                                               int nrows, float* __restrict__ Y){
  __shared__ float Ws[128];
  int t = threadIdx.x;
  if (t < 128) Ws[t] = W[t];
  __syncthreads();
  int row = blockIdx.x*256 + t;
  if (row >= nrows) return;
  const float4* Xr = (const float4*)(X + (size_t)row*64);
  float a0 = 0.f, a1 = 0.f;
  #pragma unroll
  for (int kk = 0; kk < 16; ++kk){
    float4 xv = Xr[kk];
    if (RELU){ xv.x=fmaxf(xv.x,0.f); xv.y=fmaxf(xv.y,0.f); xv.z=fmaxf(xv.z,0.f); xv.w=fmaxf(xv.w,0.f); }
    int k = kk*4;
    a0 = fmaf(xv.x, Ws[2*k+0], a0); a1 = fmaf(xv.x, Ws[2*k+1], a1);
    a0 = fmaf(xv.y, Ws[2*k+2], a0); a1 = fmaf(xv.y, Ws[2*k+3], a1);
    a0 = fmaf(xv.z, Ws[2*k+4], a0); a1 = fmaf(xv.z, Ws[2*k+5], a1);
    a0 = fmaf(xv.w, Ws[2*k+6], a0); a1 = fmaf(xv.w, Ws[2*k+7], a1);
  }
  if (SCALE){ float dv = dinv[row]; a0 *= dv; a1 *= dv; }
  Y[(size_t)row*2]   = a0;
  Y[(size_t)row*2+1] = a1;
}

// ---------------- pipelined row-gather helpers ----------------
__device__ __forceinline__ float4 gather_rows4(const int* __restrict__ col, int beg, int end,
                                               const float4* __restrict__ h4, int fq, float4 acc){
  int j = beg;
  bool p0 = j   < end; int c0 = p0 ? col[j]   : 0;
  bool p1 = j+1 < end; int c1 = p1 ? col[j+1] : 0;
  bool p2 = j+2 < end; int c2 = p2 ? col[j+2] : 0;
  bool p3 = j+3 < end; int c3 = p3 ? col[j+3] : 0;
  while (p0){
    float4 v0 = h4[(size_t)c0*16 + fq];
    float4 v1 = p1 ? h4[(size_t)c1*16 + fq] : make_float4(0.f,0.f,0.f,0.f);
    float4 v2 = p2 ? h4[(size_t)c2*16 + fq] : make_float4(0.f,0.f,0.f,0.f);
    float4 v3 = p3 ? h4[(size_t)c3*16 + fq] : make_float4(0.f,0.f,0.f,0.f);
    j += 4;
    bool q0 = j < end, q1 = j+1 < end, q2 = j+2 < end, q3 = j+3 < end;
    int n0 = q0 ? col[j]   : 0;
    int n1 = q1 ? col[j+1] : 0;
    int n2 = q2 ? col[j+2] : 0;
    int n3 = q3 ? col[j+3] : 0;
    acc.x += v0.x + v1.x + v2.x + v3.x;
    acc.y += v0.y + v1.y + v2.y + v3.y;
    acc.z += v0.z + v1.z + v2.z + v3.z;
    acc.w += v0.w + v1.w + v2.w + v3.w;
    p0=q0; p1=q1; p2=q2; p3=q3; c0=n0; c1=n1; c2=n2; c3=n3;
  }
  return acc;
}

__device__ __forceinline__ float4 gather_rows4_h16(const int* __restrict__ col, int beg, int end,
                                                   const uint2* __restrict__ h16, int fq, float4 acc){
  int j = beg;
  bool p0 = j   < end; int c0 = p0 ? col[j]   : 0;
  bool p1 = j+1 < end; int c1 = p1 ? col[j+1] : 0;
  bool p2 = j+2 < end; int c2 = p2 ? col[j+2] : 0;
  bool p3 = j+3 < end; int c3 = p3 ? col[j+3] : 0;
  const uint2 z = make_uint2(0u, 0u);
  while (p0){
    uint2 u0 = h16[(size_t)c0*16 + fq];
    uint2 u1 = p1 ? h16[(size_t)c1*16 + fq] : z;
    uint2 u2 = p2 ? h16[(size_t)c2*16 + fq] : z;
    uint2 u3 = p3 ? h16[(size_t)c3*16 + fq] : z;
    j += 4;
    bool q0 = j < end, q1 = j+1 < end, q2 = j+2 < end, q3 = j+3 < end;
    int n0 = q0 ? col[j]   : 0;
    int n1 = q1 ? col[j+1] : 0;
    int n2 = q2 ? col[j+2] : 0;
    int n3 = q3 ? col[j+3] : 0;
    float4 v0 = h4_to_f4(u0), v1 = h4_to_f4(u1), v2 = h4_to_f4(u2), v3 = h4_to_f4(u3);
    acc.x += v0.x + v1.x + v2.x + v3.x;
    acc.y += v0.y + v1.y + v2.y + v3.y;
    acc.z += v0.z + v1.z + v2.z + v3.z;
    acc.w += v0.w + v1.w + v2.w + v3.w;
    p0=q0; p1=q1; p2=q2; p3=q3; c0=n0; c1=n1; c2=n2; c3=n3;
  }
  return acc;
}

// ---------------- CSR gather conv, f32 (single tier) ----------------
__global__ __launch_bounds__(256) void k_gather64(const int* __restrict__ rowptr, const int* __restrict__ col,
                                                  const float* __restrict__ h, const float* __restrict__ dinv,
                                                  const float* __restrict__ b, float* __restrict__ out){
  int gt = blockIdx.x*256 + threadIdx.x;
  int fq = gt & 15;
  int node = gt >> 4;
  if (node >= NN) return;
  const float4* __restrict__ h4 = (const float4*)h;
  float4 acc = h4[(size_t)node*16 + fq];
  acc = gather_rows4(col, rowptr[node], rowptr[node+1], h4, fq, acc);
  float dv = dinv[node];
  float4 bb = ((const float4*)b)[fq];
  float4 r;
  r.x = fmaf(acc.x, dv, bb.x); r.y = fmaf(acc.y, dv, bb.y);
  r.z = fmaf(acc.z, dv, bb.z); r.w = fmaf(acc.w, dv, bb.w);
  *(float4*)(out + (size_t)node*64 + fq*4) = r;
}

// ---------------- CSR gather conv, fp16 in -> fp16 out ----------------
__global__ __launch_bounds__(256) void k_gather64hh(const int* __restrict__ rowptr, const int* __restrict__ col,
                                                    const uint2* __restrict__ h16, const float* __restrict__ dinv,
                                                    const float* __restrict__ b, uint2* __restrict__ out16){
  int gt = blockIdx.x*256 + threadIdx.x;
  int fq = gt & 15;
  int node = gt >> 4;
  if (node >= NN) return;
  float4 acc = h4_to_f4(h16[(size_t)node*16 + fq]);
  acc = gather_rows4_h16(col, rowptr[node], rowptr[node+1], h16, fq, acc);
  float dv = dinv[node];
  float4 bb = ((const float4*)b)[fq];
  float4 r;
  r.x = fmaf(acc.x, dv, bb.x); r.y = fmaf(acc.y, dv, bb.y);
  r.z = fmaf(acc.z, dv, bb.z); r.w = fmaf(acc.w, dv, bb.w);
  out16[(size_t)node*16 + fq] = f4_to_h4(r);
}

// ---------------- FUSED: gather conv1(fp16) + ReLU + @W2 + scale -> fp16 table ----------------
__global__ __launch_bounds__(256) void k_gathergemmh(const int* __restrict__ rowptr, const int* __restrict__ col,
                                                     const uint2* __restrict__ h16, const float* __restrict__ dinv,
                                                     const float* __restrict__ b1, const float* __restrict__ W2,
                                                     uint2* __restrict__ Y16){
  __shared__ float Ws[64][64];
  __shared__ float rows[16][68];
  int t = threadIdx.x;
  {
    const float4* W4 = (const float4*)W2;
    float4* S4 = (float4*)&Ws[0][0];
    #pragma unroll
    for (int i = 0; i < 4; ++i) S4[t + 256*i] = W4[t + 256*i];
  }
  __syncthreads();
  int fq = t & 15, grp = t >> 4;
  int node = blockIdx.x*16 + grp;
  bool alive = node < NN;
  float dv = 0.f;
  if (alive){
    float4 acc = h4_to_f4(h16[(size_t)node*16 + fq]);
    acc = gather_rows4_h16(col, rowptr[node], rowptr[node+1], h16, fq, acc);
    dv = dinv[node];
    float4 bb = ((const float4*)b1)[fq];
    float4 r;
    r.x = fmaxf(fmaf(acc.x, dv, bb.x), 0.f);
    r.y = fmaxf(fmaf(acc.y, dv, bb.y), 0.f);
    r.z = fmaxf(fmaf(acc.z, dv, bb.z), 0.f);
    r.w = fmaxf(fmaf(acc.w, dv, bb.w), 0.f);
    *(float4*)&rows[grp][fq*4] = r;
  }
  __syncthreads();
  if (alive){
    const float* __restrict__ row = &rows[grp][0];
    float4 o = make_float4(0.f,0.f,0.f,0.f);
    int c0 = fq*4;
    #pragma unroll 8
    for (int k = 0; k < 64; ++k){
      float rv = row[k];
      float4 w = *(const float4*)&Ws[k][c0];
      o.x = fmaf(rv, w.x, o.x); o.y = fmaf(rv, w.y, o.y);
      o.z = fmaf(rv, w.z, o.z); o.w = fmaf(rv, w.w, o.w);
    }
    o.x *= dv; o.y *= dv; o.z *= dv; o.w *= dv;
    Y16[(size_t)node*16 + fq] = f4_to_h4(o);
  }
}

// f32 version (single tier)
__global__ __launch_bounds__(256) void k_gathergemm(const int* __restrict__ rowptr, const int* __restrict__ col,
                                                    const float* __restrict__ h, const float* __restrict__ dinv,
                                                    const float* __restrict__ b1, const float* __restrict__ W2,
                                                    float* __restrict__ Y){
  __shared__ float Ws[64][64];
  __shared__ float rows[16][68];
  int t = threadIdx.x;
  {
    const float4* W4 = (const float4*)W2;
    float4* S4 = (float4*)&Ws[0][0];
    #pragma unroll
    for (int i = 0; i < 4; ++i) S4[t + 256*i] = W4[t + 256*i];
  }
  __syncthreads();
  int fq = t & 15, grp = t >> 4;
  int node = blockIdx.x*16 + grp;
  bool alive = node < NN;
  float dv = 0.f;
  if (alive){
    const float4* __restrict__ h4 = (const float4*)h;
    float4 acc = h4[(size_t)node*16 + fq];
    acc = gather_rows4(col, rowptr[node], rowptr[node+1], h4, fq, acc);
    dv = dinv[node];
    float4 bb = ((const float4*)b1)[fq];
    float4 r;
    r.x = fmaxf(fmaf(acc.x, dv, bb.x), 0.f);
    r.y = fmaxf(fmaf(acc.y, dv, bb.y), 0.f);
    r.z = fmaxf(fmaf(acc.z, dv, bb.z), 0.f);
    r.w = fmaxf(fmaf(acc.w, dv, bb.w), 0.f);
    *(float4*)&rows[grp][fq*4] = r;
  }
  __syncthreads();
  if (alive){
    const float* __restrict__ row = &rows[grp][0];
    float4 o = make_float4(0.f,0.f,0.f,0.f);
    int c0 = fq*4;
    #pragma unroll 8
    for (int k = 0; k < 64; ++k){
      float rv = row[k];
      float4 w = *(const float4*)&Ws[k][c0];
      o.x = fmaf(rv, w.x, o.x); o.y = fmaf(rv, w.y, o.y);
      o.z = fmaf(rv, w.z, o.z); o.w = fmaf(rv, w.w, o.w);
    }
    o.x *= dv; o.y *= dv; o.z *= dv; o.w *= dv;
    *(float4*)(Y + (size_t)node*64 + fq*4) = o;
  }
}

// ---------------- FUSED: lf-gather (fp16, CSR-A) + cross-layer agg (fp16 last, CSR-B) + scale (+drop) ----------------
// OUT16: write fp16 table (next `last`); else f32 (x_emb)
template<bool DROP, bool OUT16>
__global__ __launch_bounds__(256) void k_gatherlfagg2h(const int* __restrict__ rpA, const int* __restrict__ colA,
                                                       const uint2* __restrict__ h16, const float* __restrict__ dinv,
                                                       const float* __restrict__ b,
                                                       const int* __restrict__ rpB, const int* __restrict__ colB,
                                                       const uint2* __restrict__ last16,
                                                       const float* __restrict__ ds, int dsidx,
                                                       void* __restrict__ outv){
  int gt = blockIdx.x*256 + threadIdx.x;
  int fq = gt & 15;
  int node = gt >> 4;
  if (node >= NN) return;
  float4 acc = h4_to_f4(h16[(size_t)node*16 + fq]);
  acc = gather_rows4_h16(colA, rpA[node], rpA[node+1], h16, fq, acc);
  float dv = dinv[node];
  float4 bb = ((const float4*)b)[fq];
  float4 lf;
  lf.x = fmaf(acc.x, dv, bb.x); lf.y = fmaf(acc.y, dv, bb.y);
  lf.z = fmaf(acc.z, dv, bb.z); lf.w = fmaf(acc.w, dv, bb.w);
  float4 agg = gather_rows4_h16(colB, rpB[node], rpB[node+1], last16, fq,
                                make_float4(0.f,0.f,0.f,0.f));
  float inv = 1.0f / ds[dsidx];
  float4 r;
  r.x = (lf.x + agg.x) * inv; r.y = (lf.y + agg.y) * inv;
  r.z = (lf.z + agg.z) * inv; r.w = (lf.w + agg.w) * inv;
  if (DROP){
    unsigned base_i = (unsigned)node*64u + (unsigned)fq*4u;
    r.x = dropout_val(r.x, base_i + 0);
    r.y = dropout_val(r.y, base_i + 1);
    r.z = dropout_val(r.z, base_i + 2);
    r.w = dropout_val(r.w, base_i + 3);
  }
  if (OUT16) ((uint2*)outv)[(size_t)node*16 + fq] = f4_to_h4(r);
  else       *(float4*)((float*)outv + (size_t)node*64 + fq*4) = r;
}

// ---------------- CSR gather cross-layer agg f32 (single tier) ----------------
template<bool DROP>
__global__ __launch_bounds__(256) void k_agggather(const int* __restrict__ rowptr, const int* __restrict__ col,
                                                    const float* __restrict__ lf, const float* __restrict__ last,
                                                    const float* __restrict__ ds, int dsidx, float* __restrict__ out){
  int gt = blockIdx.x*256 + threadIdx.x;
  int fq = gt & 15;
  int node = gt >> 4;
  if (node >= NN) return;
  float4 acc = ((const float4*)lf)[(size_t)node*16 + fq];
  acc = gather_rows4(col, rowptr[node], rowptr[node+1], (const float4*)last, fq, acc);
  float inv = 1.0f / ds[dsidx];
  float4 r;
  r.x = acc.x * inv; r.y = acc.y * inv; r.z = acc.z * inv; r.w = acc.w * inv;
  if (DROP){
    unsigned base_i = (unsigned)node*64u + (unsigned)fq*4u;
    r.x = dropout_val(r.x, base_i + 0);
    r.y = dropout_val(r.y, base_i + 1);
    r.z = dropout_val(r.z, base_i + 2);
    r.w = dropout_val(r.w, base_i + 3);
  }
  *(float4*)(out + (size_t)node*64 + fq*4) = r;
}

// ---------------- FUSED predictor tail: gather(H0) + pb1 + relu + @pW2 + dv -> [N,2] ----------------
__global__ __launch_bounds__(256) void k_predgather2h(const int* __restrict__ rowptr, const int* __restrict__ col,
                                                      const uint2* __restrict__ h16, const float* __restrict__ dinv,
                                                      const float* __restrict__ b1, const float* __restrict__ W2,
                                                      float* __restrict__ Y){
  int gt = blockIdx.x*256 + threadIdx.x;
  int fq = gt & 15;
  int node = gt >> 4;
  if (node >= NN) return;
  float4 acc = h4_to_f4(h16[(size_t)node*16 + fq]);
  acc = gather_rows4_h16(col, rowptr[node], rowptr[node+1], h16, fq, acc);
  float dv = dinv[node];
  float4 bb = ((const float4*)b1)[fq];
  float4 r;
  r.x = fmaxf(fmaf(acc.x, dv, bb.x), 0.f);
  r.y = fmaxf(fmaf(acc.y, dv, bb.y), 0.f);
  r.z = fmaxf(fmaf(acc.z, dv, bb.z), 0.f);
  r.w = fmaxf(fmaf(acc.w, dv, bb.w), 0.f);
  // weights for this thread's k-quad: pW2[64][2] row-major; float4 idx fq*2, fq*2+1
  const float4* w4 = (const float4*)W2;
  float4 wa = w4[fq*2], wb = w4[fq*2 + 1];
  float o0 = r.x*wa.x + r.y*wa.z + r.z*wb.x + r.w*wb.z;
  float o1 = r.x*wa.y + r.y*wa.w + r.z*wb.y + r.w*wb.w;
  // reduce across the 16-lane group (groups are 16-aligned within the wave)
  o0 += __shfl_xor(o0, 1); o1 += __shfl_xor(o1, 1);
  o0 += __shfl_xor(o0, 2); o1 += __shfl_xor(o1, 2);
  o0 += __shfl_xor(o0, 4); o1 += __shfl_xor(o1, 4);
  o0 += __shfl_xor(o0, 8); o1 += __shfl_xor(o1, 8);
  if (fq == 0){
    Y[(size_t)node*2]   = o0 * dv;
    Y[(size_t)node*2+1] = o1 * dv;
  }
}

// ---------------- CSR gather final conv (D_out=2) ----------------
__global__ void k_gather2(const int* __restrict__ rowptr, const int* __restrict__ col,
                          const float* __restrict__ h2, const float* __restrict__ dinv,
                          const float* __restrict__ b, float* __restrict__ out){
  int d = blockIdx.x*256 + threadIdx.x;
  if (d >= NN) return;
  int beg = rowptr[d], end = rowptr[d+1];
  float a0 = h2[(size_t)d*2];
  float a1 = h2[(size_t)d*2+1];
  for (int j = beg; j < end; ++j){
    int s = col[j];
    a0 += h2[(size_t)s*2];
    a1 += h2[(size_t)s*2+1];
  }
  float dv = dinv[d];
  out[(size_t)d*2]   = fmaf(a0, dv, b[0]);
  out[(size_t)d*2+1] = fmaf(a1, dv, b[1]);
}

// ---------------- standalone dropout (fallback path only) ----------------
__global__ void k_dropout(const float* __restrict__ last, float* __restrict__ xemb){
  unsigned i = blockIdx.x*256 + threadIdx.x;
  if (i >= NF) return;
  xemb[i] = dropout_val(last[i], i);
}

// ======== fallback (atomic scatter) kernels ========
__global__ void k_convinit(const float* __restrict__ h, const float* __restrict__ dinv,
                           const float* __restrict__ b, float* __restrict__ out){
  int i = blockIdx.x*256 + threadIdx.x;
  if (i >= NF) return;
  int v = i >> 6, c = i & 63;
  float dv = dinv[v];
  out[i] = h[i]*dv*dv + b[c];
}
__global__ void k_scatter64(const int* __restrict__ src, const int* __restrict__ dst, int ne,
                            const float* __restrict__ h, const float* __restrict__ dinv,
                            float* __restrict__ out){
  int lane = threadIdx.x & 63;
  int wid  = (blockIdx.x*256 + threadIdx.x) >> 6;
  int nw   = (gridDim.x*256) >> 6;
  for (int e = wid; e < ne; e += nw){
    int s = src[e], d = dst[e];
    float coef = dinv[s]*dinv[d];
    atomicAdd(&out[d*64 + lane], h[s*64 + lane]*coef);
  }
}
__global__ void k_layeragg(const int* __restrict__ recv, const int* __restrict__ srcn, int ne,
                           const float* __restrict__ last, float* __restrict__ acc){
  int lane = threadIdx.x & 63;
  int wid  = (blockIdx.x*256 + threadIdx.x) >> 6;
  int nw   = (gridDim.x*256) >> 6;
  for (int e = wid; e < ne; e += nw){
    int r = recv[e], s = srcn[e];
    atomicAdd(&acc[r*64 + lane], last[s*64 + lane]);
  }
}
__global__ void k_scale(const float* __restrict__ in, const float* __restrict__ ds, int dsidx,
                        float* __restrict__ out){
  int i = blockIdx.x*256 + threadIdx.x;
  if (i < NF) out[i] = in[i] / ds[dsidx];
}
__global__ void k_convinit2(const float* __restrict__ h2, const float* __restrict__ dinv,
                            const float* __restrict__ b, float* __restrict__ out){
  int i = blockIdx.x*256 + threadIdx.x;
  if (i >= NN*2) return;
  int v = i >> 1, c = i & 1;
  float dv = dinv[v];
  out[i] = h2[i]*dv*dv + b[c];
}
__global__ void k_scatter2(const int* __restrict__ src, const int* __restrict__ dst, int ne,
                           const float* __restrict__ h2, const float* __restrict__ dinv,
                           float* __restrict__ out){
  int e = blockIdx.x*256 + threadIdx.x;
  if (e >= ne) return;
  int s = src[e], d = dst[e];
  float coef = dinv[s]*dinv[d];
  atomicAdd(&out[d*2 + 0], h2[s*2 + 0]*coef);
  atomicAdd(&out[d*2 + 1], h2[s*2 + 1]*coef);
}

extern "C" void kernel_launch(void* const* d_in, const int* in_sizes, int n_in,
                              void* d_out, int out_size, void* d_ws, size_t ws_size,
                              hipStream_t stream) {
  const float* x    = (const float*)d_in[0];
  const int*   ei   = (const int*)  d_in[1];
  const int*   lei  = (const int*)  d_in[2];
  const float* degs = (const float*)d_in[3];
  const float* lW1  = (const float*)d_in[4];
  const float* lb1  = (const float*)d_in[5];
  const float* lW2  = (const float*)d_in[6];
  const float* lb2  = (const float*)d_in[7];
  const float* pW1  = (const float*)d_in[8];
  const float* pb1  = (const float*)d_in[9];
  const float* pW2  = (const float*)d_in[10];
  const float* pb2  = (const float*)d_in[11];
  float* out = (float*)d_out;

  const int gN  = (NN + 255)/256;
  const int gE  = (EE + 255)/256;
  const int gEL = (ELL + 255)/256;
  const int gNF = (NF + 255)/256;
  const int gG16 = (NN*16 + 255)/256;   // 6250

  const bool dual   = ws_size >= (size_t)WS_DUAL * 4;
  const bool single = ws_size >= (size_t)WS_SINGLE * 4;

  if (dual) {
    float* base   = (float*)d_ws;
    float* dinv   = base;
    int*   cnt    = (int*)(base + OFF_CNT);
    int*   bsum   = (int*)(base + OFF_BSUM);
    int*   flag   = bsum + 120;
    int*   rpA    = (int*)(base + OFF_RPA);
    int*   colA   = (int*)(base + OFF_COLA);
    int*   rpB    = (int*)(base + OFF_RPB);
    int*   colB   = (int*)(base + OFF_COLB);
    float* F0     = base + OFF_COLB + 1000000;
    float* F1     = F0 + NF;
    float* F2     = F1 + NF;
    uint2* H0     = (uint2*)(F2 + NF);
    uint2* H1     = H0 + (size_t)NN*16;
    uint2* H2     = H1 + (size_t)NN*16;
    uint2* H3     = H2 + (size_t)NN*16;

    auto build_csr = [&](const int* srcp, const int* dstp, int ne, int gEdges, int computeDinv,
                         int* rowptr, int* col, int* rank){
      k_degrank<<<gEdges, 256, 0, stream>>>(dstp, ne, cnt, rank);
      k_scanfused<<<NB_SCAN, 1024, 0, stream>>>(cnt, bsum, flag, rowptr, dinv, computeDinv, NN);
      k_fillrz<<<gEdges, 256, 0, stream>>>(srcp, dstp, ne, rowptr, rank, col, cnt, flag);
    };

    const int* s0 = ei;                  const int* d0 = s0 + EE;
    const int* s1 = ei + 2*(size_t)EE;   const int* d1 = s1 + EE;
    const int* s2 = ei + 4*(size_t)EE;   const int* d2 = s2 + EE;
    const int* r0 = lei;                 const int* ls0 = r0 + ELL;
    const int* r1 = lei + 2*(size_t)ELL; const int* ls1 = r1 + ELL;

    k_zerof<<<gN, 256, 0, stream>>>(cnt, NN, flag);

    // ---- surface 0 ----
    build_csr(s0, d0, EE, gE, 1, rpA, colA, (int*)F0);
    k_gemm64h<false><<<6250, 256, 0, stream>>>(x, lW1, dinv, NN, H0);
    k_gathergemmh<<<6250, 256, 0, stream>>>(rpA, colA, H0, dinv, lb1, lW2, H1);
    k_gather64hh<<<gG16, 256, 0, stream>>>(rpA, colA, H1, dinv, lb2, H2);            // last16 = H2
    // ---- surface 1 ----
    build_csr(s1, d1, EE, gE, 1, rpA, colA, (int*)F0);
    build_csr(ls0, r0, ELL, gEL, 0, rpB, colB, (int*)F0);
    k_gemm64h<false><<<6250, 256, 0, stream>>>(x + (size_t)NF, lW1 + 4096, dinv, NN, H0);
    k_gathergemmh<<<6250, 256, 0, stream>>>(rpA, colA, H0, dinv, lb1 + 64, lW2 + 4096, H1);
    k_gatherlfagg2h<false,true><<<gG16, 256, 0, stream>>>(rpA, colA, H1, dinv, lb2 + 64,
                                                          rpB, colB, H2, degs, 0, (void*)H3);  // last16 = H3
    // ---- surface 2 ----
    build_csr(s2, d2, EE, gE, 1, rpA, colA, (int*)F0);
    build_csr(ls1, r1, ELL, gEL, 0, rpB, colB, (int*)F0);
    k_gemm64h<false><<<6250, 256, 0, stream>>>(x + 2*(size_t)NF, lW1 + 8192, dinv, NN, H0);
    k_gathergemmh<<<6250, 256, 0, stream>>>(rpA, colA, H0, dinv, lb1 + 128, lW2 + 8192, H1);
    k_gatherlfagg2h<true,false><<<gG16, 256, 0, stream>>>(rpA, colA, H1, dinv, lb2 + 128,
                                                          rpB, colB, H3, degs, 1, (void*)F1); // F1 = x_emb f32
    // ---- predictor (CSR-A = surface-2 edges; dinv = surface-2 degrees) ----
    k_gemm64h<false><<<6250, 256, 0, stream>>>(F1, pW1, dinv, NN, H0);
    k_predgather2h<<<gG16, 256, 0, stream>>>(rpA, colA, H0, dinv, pb1, pW2, F2);     // F2 = h2' [N,2]
    k_gather2<<<gN, 256, 0, stream>>>(rpA, colA, F2, dinv, pb2, out);
    k_probe<<<1, 64, 0, stream>>>(ei, 0u, out);
    return;
  }

  if (single) {
    // ======= proven single-slot f32 path =======
    float* base   = (float*)d_ws;
    float* dinv   = base;
    int*   cnt    = (int*)(base + OFF_CNT);
    int*   bsum   = (int*)(base + OFF_BSUM);
    int*   flag   = bsum + 120;
    int*   rpA    = (int*)(base + OFF_RPA);
    int*   colA   = (int*)(base + OFF_COLA);
    float* F0     = base + OFF_RPB;
    float* F1     = F0 + NF;
    float* F2     = F1 + NF;

    auto build_csr = [&](const int* srcp, const int* dstp, int ne, int gEdges, int computeDinv,
                         int* rowptr, int* col, int* rank){
      k_zerof<<<gN, 256, 0, stream>>>(cnt, NN, flag);
      k_degrank<<<gEdges, 256, 0, stream>>>(dstp, ne, cnt, rank);
      k_scanfused<<<NB_SCAN, 1024, 0, stream>>>(cnt, bsum, flag, rowptr, dinv, computeDinv, NN);
      k_fillr<<<gEdges, 256, 0, stream>>>(srcp, dstp, ne, rowptr, rank, col);
    };

    const int* s0 = ei;                  const int* d0 = s0 + EE;
    const int* s1 = ei + 2*(size_t)EE;   const int* d1 = s1 + EE;
    const int* s2 = ei + 4*(size_t)EE;   const int* d2 = s2 + EE;
    const int* r0 = lei;                 const int* ls0 = r0 + ELL;
    const int* r1 = lei + 2*(size_t)ELL; const int* ls1 = r1 + ELL;

    build_csr(s0, d0, EE, gE, 1, rpA, colA, (int*)F0);
    k_gemm64<false,true><<<6250, 256, 0, stream>>>(x, lW1, dinv, NN, F0);
    k_gathergemm<<<6250, 256, 0, stream>>>(rpA, colA, F0, dinv, lb1, lW2, F1);
    k_gather64<<<gG16, 256, 0, stream>>>(rpA, colA, F1, dinv, lb2, F2);
    build_csr(s1, d1, EE, gE, 1, rpA, colA, (int*)F0);
    k_gemm64<false,true><<<6250, 256, 0, stream>>>(x + (size_t)NF, lW1 + 4096, dinv, NN, F0);
    k_gathergemm<<<6250, 256, 0, stream>>>(rpA, colA, F0, dinv, lb1 + 64, lW2 + 4096, F1);
    build_csr(ls0, r0, ELL, gEL, 0, rpA, colA, (int*)F0);
    k_agggather<false><<<gG16, 256, 0, stream>>>(rpA, colA, F1, F2, degs, 0, F0);
    build_csr(s2, d2, EE, gE, 1, rpA, colA, (int*)F1);
    k_gemm64<false,true><<<6250, 256, 0, stream>>>(x + 2*(size_t)NF, lW1 + 8192, dinv, NN, F1);
    k_gathergemm<<<6250, 256, 0, stream>>>(rpA, colA, F1, dinv, lb1 + 128, lW2 + 8192, F2);
    build_csr(ls1, r1, ELL, gEL, 0, rpA, colA, (int*)F1);
    k_agggather<true><<<gG16, 256, 0, stream>>>(rpA, colA, F2, F0, degs, 1, F1);
    build_csr(s2, d2, EE, gE, 0, rpA, colA, (int*)F0);
    k_gemm64<false,true><<<6250, 256, 0, stream>>>(F1, pW1, dinv, NN, F0);
    k_gather64<<<gG16, 256, 0, stream>>>(rpA, colA, F0, dinv, pb1, F2);
    k_gemm2<true,true><<<gN, 256, 0, stream>>>(F2, pW2, dinv, NN, F1);
    k_gather2<<<gN, 256, 0, stream>>>(rpA, colA, F1, dinv, pb2, out);
    k_probe<<<1, 64, 0, stream>>>(ei, 0u, out);
    return;
  }

  // ================= fallback: verified atomic-scatter path =================
  float* base = (float*)d_ws;
  float* dinv = base;
  int*   cnt  = (int*)(base + 100352);
  float* A    = base + 262144;
  float* B    = A + NF;
  float* C    = B + NF;

  for (int i = 0; i < 3; ++i){
    const int* srcp = ei + (size_t)i*2*EE;
    const int* dstp = srcp + EE;
    k_zero_int<<<gN, 256, 0, stream>>>(cnt, NN);
    k_deg<<<gE, 256, 0, stream>>>(dstp, EE, cnt);
    k_dinv<<<gN, 256, 0, stream>>>(cnt, dinv, NN);
    k_gemm64<false,false><<<6250, 256, 0, stream>>>(x + (size_t)i*NF, lW1 + (size_t)i*64*64, dinv, NN, A);
    k_convinit<<<gNF, 256, 0, stream>>>(A, dinv, lb1 + (size_t)i*64, B);
    k_scatter64<<<8192, 256, 0, stream>>>(srcp, dstp, EE, A, dinv, B);
    k_gemm64<true,false><<<6250, 256, 0, stream>>>(B, lW2 + (size_t)i*64*64, dinv, NN, A);
    float* T = (i == 0) ? C : B;
    k_convinit<<<gNF, 256, 0, stream>>>(A, dinv, lb2 + (size_t)i*64, T);
    k_scatter64<<<8192, 256, 0, stream>>>(srcp, dstp, EE, A, dinv, T);
    if (i > 0){
      const int* recvp = lei + (size_t)(i-1)*2*ELL;
      const int* lsrcp = recvp + ELL;
      k_layeragg<<<4096, 256, 0, stream>>>(recvp, lsrcp, ELL, C, B);
      k_scale<<<gNF, 256, 0, stream>>>(B, degs, i-1, C);
    }
  }
  k_dropout<<<gNF, 256, 0, stream>>>(C, B);
  const int* srcp = ei + (size_t)2*2*EE;
  const int* dstp = srcp + EE;
  k_gemm64<false,false><<<6250, 256, 0, stream>>>(B, pW1, dinv, NN, A);
  k_convinit<<<gNF, 256, 0, stream>>>(A, dinv, pb1, C);
  k_scatter64<<<8192, 256, 0, stream>>>(srcp, dstp, EE, A, dinv, C);
  k_gemm2<true,false><<<gN, 256, 0, stream>>>(C, pW2, dinv, NN, B);
  k_convinit2<<<(NN*2 + 255)/256, 256, 0, stream>>>(B, dinv, pb2, out);
  k_scatter2<<<gE, 256, 0, stream>>>(srcp, dstp, EE, B, dinv, out);
  k_probe<<<1, 64, 0, stream>>>(ei, 0u, out);
}